// Round 1
// baseline (1504.764 us; speedup 1.0000x reference)
//
#include <hip/hip_runtime.h>
#include <math.h>

// ---------------------------------------------------------------------------
// GatedCrossAttention: B=2, NQ=NK=1024, QD=KVD=OD=1024, H=8, DH=64, INNER=512
// Round 0: pure-f32 correctness baseline. All GEMMs are C[M,N]=A[M,K]*W[N,K]^T
// with M=2048. Attention is fused flash-style (no SxS materialization).
// ---------------------------------------------------------------------------

#define M_ROWS 2048   // B*NQ
#define SEQ    1024

// ----------------------------- LayerNorm ----------------------------------
// One block per row. D in {512, 1024}. 256 threads, one float4 per thread.
__global__ __launch_bounds__(256)
void ln_kernel(const float* __restrict__ x, const float* __restrict__ w,
               const float* __restrict__ bias, float* __restrict__ out, int D)
{
    const size_t row = blockIdx.x;
    const float* xr = x + row * (size_t)D;
    float* orow = out + row * (size_t)D;
    const int c = threadIdx.x * 4;
    float4 v = make_float4(0.f, 0.f, 0.f, 0.f);
    if (c < D) v = *reinterpret_cast<const float4*>(&xr[c]);
    float sum = v.x + v.y + v.z + v.w;
    float sq  = v.x*v.x + v.y*v.y + v.z*v.z + v.w*v.w;
    #pragma unroll
    for (int off = 32; off > 0; off >>= 1) {
        sum += __shfl_down(sum, off);
        sq  += __shfl_down(sq,  off);
    }
    __shared__ float s1[4], s2[4];
    const int wid = threadIdx.x >> 6;
    if ((threadIdx.x & 63) == 0) { s1[wid] = sum; s2[wid] = sq; }
    __syncthreads();
    const float tsum = s1[0] + s1[1] + s1[2] + s1[3];
    const float tsq  = s2[0] + s2[1] + s2[2] + s2[3];
    const float mean = tsum / (float)D;
    const float var  = tsq / (float)D - mean * mean;
    const float rstd = rsqrtf(var + 1e-5f);
    if (c < D) {
        float4 o;
        o.x = (v.x - mean) * rstd * w[c+0] + bias[c+0];
        o.y = (v.y - mean) * rstd * w[c+1] + bias[c+1];
        o.z = (v.z - mean) * rstd * w[c+2] + bias[c+2];
        o.w = (v.w - mean) * rstd * w[c+3] + bias[c+3];
        *reinterpret_cast<float4*>(&orow[c]) = o;
    }
}

// ------------------------------- GEMM --------------------------------------
// C[M,N] = A[M,K] * W[N,K]^T. 64x64 tile, BK=32, 256 threads, 4x4 micro-tile.
// LDS tiles stored K-major transposed (As[k][m]) so fragment reads are
// contiguous b128 across lanes. EPI: 0=none, 1=exact GELU, 2=C = C + gate*acc.
template<int EPI>
__global__ __launch_bounds__(256)
void gemm_bt(const float* __restrict__ A, const float* __restrict__ W,
             float* __restrict__ C, int N, int K,
             const float* __restrict__ gatep)
{
    __shared__ float As[32][68];
    __shared__ float Ws[32][68];
    const int tid = threadIdx.x;
    const int ty = tid >> 4, tx = tid & 15;
    const int m0 = blockIdx.y * 64;
    const int n0 = blockIdx.x * 64;
    const int kc = (tid & 7) * 4;   // k-chunk within BK for staging
    const int r0 = tid >> 3;        // 0..31 row for staging
    float acc[4][4] = {};

    for (int k0 = 0; k0 < K; k0 += 32) {
        #pragma unroll
        for (int p = 0; p < 2; ++p) {
            const int mr = p * 32 + r0;
            const float4 a4 = *reinterpret_cast<const float4*>(
                &A[(size_t)(m0 + mr) * K + k0 + kc]);
            As[kc+0][mr] = a4.x; As[kc+1][mr] = a4.y;
            As[kc+2][mr] = a4.z; As[kc+3][mr] = a4.w;
            const float4 w4 = *reinterpret_cast<const float4*>(
                &W[(size_t)(n0 + mr) * K + k0 + kc]);
            Ws[kc+0][mr] = w4.x; Ws[kc+1][mr] = w4.y;
            Ws[kc+2][mr] = w4.z; Ws[kc+3][mr] = w4.w;
        }
        __syncthreads();
        #pragma unroll
        for (int kk = 0; kk < 32; ++kk) {
            const float4 av = *reinterpret_cast<const float4*>(&As[kk][ty * 4]);
            const float4 wv = *reinterpret_cast<const float4*>(&Ws[kk][tx * 4]);
            const float a[4] = {av.x, av.y, av.z, av.w};
            const float w[4] = {wv.x, wv.y, wv.z, wv.w};
            #pragma unroll
            for (int i = 0; i < 4; ++i)
                #pragma unroll
                for (int j = 0; j < 4; ++j)
                    acc[i][j] = fmaf(a[i], w[j], acc[i][j]);
        }
        __syncthreads();
    }

    const float gate = (EPI == 2) ? gatep[0] : 0.f;
    #pragma unroll
    for (int i = 0; i < 4; ++i) {
        const size_t row = (size_t)(m0 + ty * 4 + i);
        float* cp = &C[row * N + n0 + tx * 4];
        float vals[4] = {acc[i][0], acc[i][1], acc[i][2], acc[i][3]};
        if (EPI == 1) {
            #pragma unroll
            for (int j = 0; j < 4; ++j) {
                const float xv = vals[j];
                vals[j] = 0.5f * xv * (1.f + erff(xv * 0.70710678118654752f));
            }
        }
        if (EPI == 2) {
            const float4 b4 = *reinterpret_cast<const float4*>(cp);
            vals[0] = b4.x + gate * vals[0];
            vals[1] = b4.y + gate * vals[1];
            vals[2] = b4.z + gate * vals[2];
            vals[3] = b4.w + gate * vals[3];
        }
        float4 o; o.x = vals[0]; o.y = vals[1]; o.z = vals[2]; o.w = vals[3];
        *reinterpret_cast<float4*>(cp) = o;
    }
}

// --------------------------- Fused attention -------------------------------
// grid = (NQ/64, B*H). One block handles a 64-row Q tile of one (b,h).
// Q/K/V are [B*SEQ, stride] buffers; head h occupies cols h*64..h*64+63.
// Online softmax, P re-staged through LDS (Ks reused) for the PV product.
__global__ __launch_bounds__(256)
void attn64(const float* __restrict__ Q, const float* __restrict__ K,
            const float* __restrict__ V, float* __restrict__ O,
            int qs, int ks, int vs, int os)
{
    __shared__ float Qs[64][65];
    __shared__ float Ks[64][65];   // reused to hold P after S is computed
    __shared__ float Vs[64][65];
    const int tid = threadIdx.x;
    const int ty = tid >> 4, tx = tid & 15;
    const int b  = blockIdx.y >> 3;
    const int hc = (blockIdx.y & 7) * 64;
    const size_t qrow0 = (size_t)b * SEQ + (size_t)blockIdx.x * 64;
    const size_t krow0 = (size_t)b * SEQ;
    const int lr = tid >> 4;          // staging row 0..15
    const int lc = (tid & 15) * 4;    // staging col

    #pragma unroll
    for (int p = 0; p < 4; ++p) {
        const int r = p * 16 + lr;
        const float4 q4 = *reinterpret_cast<const float4*>(
            &Q[(qrow0 + r) * qs + hc + lc]);
        Qs[r][lc+0] = q4.x * 0.125f;   // scale = DH^-0.5 applied to Q (as ref)
        Qs[r][lc+1] = q4.y * 0.125f;
        Qs[r][lc+2] = q4.z * 0.125f;
        Qs[r][lc+3] = q4.w * 0.125f;
    }

    float m[4], l[4], acc[4][4];
    #pragma unroll
    for (int i = 0; i < 4; ++i) {
        m[i] = -1e30f; l[i] = 0.f;
        #pragma unroll
        for (int j = 0; j < 4; ++j) acc[i][j] = 0.f;
    }

    for (int kt = 0; kt < SEQ / 64; ++kt) {
        __syncthreads();   // previous iteration done reading Ks/Vs
        #pragma unroll
        for (int p = 0; p < 4; ++p) {
            const int r = p * 16 + lr;
            const size_t gr = krow0 + kt * 64 + r;
            const float4 k4 = *reinterpret_cast<const float4*>(&K[gr * ks + hc + lc]);
            Ks[r][lc+0] = k4.x; Ks[r][lc+1] = k4.y;
            Ks[r][lc+2] = k4.z; Ks[r][lc+3] = k4.w;
            const float4 v4 = *reinterpret_cast<const float4*>(&V[gr * vs + hc + lc]);
            Vs[r][lc+0] = v4.x; Vs[r][lc+1] = v4.y;
            Vs[r][lc+2] = v4.z; Vs[r][lc+3] = v4.w;
        }
        __syncthreads();

        // S tile: s[i][j] = sum_d Qs[ty*4+i][d] * Ks[tx*4+j][d]
        float s[4][4] = {};
        #pragma unroll 8
        for (int d = 0; d < 64; ++d) {
            float qv[4], kv[4];
            #pragma unroll
            for (int i = 0; i < 4; ++i) qv[i] = Qs[ty * 4 + i][d];
            #pragma unroll
            for (int j = 0; j < 4; ++j) kv[j] = Ks[tx * 4 + j][d];
            #pragma unroll
            for (int i = 0; i < 4; ++i)
                #pragma unroll
                for (int j = 0; j < 4; ++j)
                    s[i][j] = fmaf(qv[i], kv[j], s[i][j]);
        }

        // online softmax per row (row owned by the 16 lanes sharing ty)
        float corr[4];
        #pragma unroll
        for (int i = 0; i < 4; ++i) {
            float mx = fmaxf(fmaxf(s[i][0], s[i][1]), fmaxf(s[i][2], s[i][3]));
            #pragma unroll
            for (int off = 1; off < 16; off <<= 1)
                mx = fmaxf(mx, __shfl_xor(mx, off, 16));
            const float mnew = fmaxf(m[i], mx);
            corr[i] = __expf(m[i] - mnew);
            m[i] = mnew;
            float sm = 0.f;
            #pragma unroll
            for (int j = 0; j < 4; ++j) {
                s[i][j] = __expf(s[i][j] - mnew);
                sm += s[i][j];
            }
            #pragma unroll
            for (int off = 1; off < 16; off <<= 1)
                sm += __shfl_xor(sm, off, 16);
            l[i] = l[i] * corr[i] + sm;
            #pragma unroll
            for (int j = 0; j < 4; ++j) acc[i][j] *= corr[i];
        }

        __syncthreads();   // everyone done reading Ks as K
        #pragma unroll
        for (int i = 0; i < 4; ++i)
            #pragma unroll
            for (int j = 0; j < 4; ++j)
                Ks[ty * 4 + i][tx * 4 + j] = s[i][j];
        __syncthreads();

        // PV: acc[i][j] += sum_jj P[ty*4+i][jj] * Vs[jj][tx*4+j]
        #pragma unroll 8
        for (int jj = 0; jj < 64; ++jj) {
            float pv[4], vv[4];
            #pragma unroll
            for (int i = 0; i < 4; ++i) pv[i] = Ks[ty * 4 + i][jj];
            #pragma unroll
            for (int j = 0; j < 4; ++j) vv[j] = Vs[jj][tx * 4 + j];
            #pragma unroll
            for (int i = 0; i < 4; ++i)
                #pragma unroll
                for (int j = 0; j < 4; ++j)
                    acc[i][j] = fmaf(pv[i], vv[j], acc[i][j]);
        }
    }

    #pragma unroll
    for (int i = 0; i < 4; ++i) {
        const float inv = 1.f / l[i];
        float4 o;
        o.x = acc[i][0] * inv; o.y = acc[i][1] * inv;
        o.z = acc[i][2] * inv; o.w = acc[i][3] * inv;
        *reinterpret_cast<float4*>(&O[(qrow0 + ty * 4 + i) * os + hc + tx * 4]) = o;
    }
}

// -------------------- gate mix (dot, softmax-2, blend) ---------------------
// One block per row: mix = softmax(gate_ctx @ mix_w^T + mix_b) over 2 logits,
// then mixed = mix0*self_out + mix1*cross_out.
__global__ __launch_bounds__(256)
void mix_kernel(const float* __restrict__ gctx, const float* __restrict__ mixw,
                const float* __restrict__ mixb, const float* __restrict__ so,
                const float* __restrict__ co, float* __restrict__ mixed)
{
    const size_t row = blockIdx.x;
    const float* g = gctx + row * 512;
    float d0 = 0.f, d1 = 0.f;
    for (int c = threadIdx.x; c < 512; c += 256) {
        const float gv = g[c];
        d0 = fmaf(gv, mixw[c], d0);
        d1 = fmaf(gv, mixw[512 + c], d1);
    }
    #pragma unroll
    for (int off = 32; off > 0; off >>= 1) {
        d0 += __shfl_down(d0, off);
        d1 += __shfl_down(d1, off);
    }
    __shared__ float sA[4], sB[4];
    const int wid = threadIdx.x >> 6;
    if ((threadIdx.x & 63) == 0) { sA[wid] = d0; sB[wid] = d1; }
    __syncthreads();
    const float t0 = sA[0] + sA[1] + sA[2] + sA[3] + mixb[0];
    const float t1 = sB[0] + sB[1] + sB[2] + sB[3] + mixb[1];
    const float mx = fmaxf(t0, t1);
    const float e0 = __expf(t0 - mx), e1 = __expf(t1 - mx);
    const float inv = 1.f / (e0 + e1);
    const float w0 = e0 * inv, w1 = e1 * inv;
    for (int c = threadIdx.x; c < 512; c += 256)
        mixed[row * 512 + c] = w0 * so[row * 512 + c] + w1 * co[row * 512 + c];
}

// ---------------------------------------------------------------------------
extern "C" void kernel_launch(void* const* d_in, const int* in_sizes, int n_in,
                              void* d_out, int out_size, void* d_ws, size_t ws_size,
                              hipStream_t stream)
{
    const float* query     = (const float*)d_in[0];
    const float* kvwt      = (const float*)d_in[1];
    const float* nq_w      = (const float*)d_in[2];
    const float* nq_b      = (const float*)d_in[3];
    const float* nkv_w     = (const float*)d_in[4];
    const float* nkv_b     = (const float*)d_in[5];
    const float* wq_cross  = (const float*)d_in[6];
    const float* wkv_cross = (const float*)d_in[7];
    const float* wqkv_self = (const float*)d_in[8];
    const float* gn_w      = (const float*)d_in[9];
    const float* gn_b      = (const float*)d_in[10];
    const float* mha_in_w  = (const float*)d_in[11];
    const float* mha_out_w = (const float*)d_in[12];
    const float* mix_w     = (const float*)d_in[13];
    const float* mix_b     = (const float*)d_in[14];
    const float* w_out     = (const float*)d_in[15];
    const float* ff_ln_w   = (const float*)d_in[16];
    const float* ff_ln_b   = (const float*)d_in[17];
    const float* ff_fc1    = (const float*)d_in[18];
    const float* ff_fc2    = (const float*)d_in[19];
    const float* ff_gate   = (const float*)d_in[20];

    float* out       = (float*)d_out;
    float* delta_out = out;                              // stack[0]
    float* wt_out    = out + (size_t)M_ROWS * 1024;      // stack[1]

    // Workspace layout (floats). region0 is reused for the FFN hidden (bufM).
    float* ws      = (float*)d_ws;
    float* bufQKV  = ws;                       // 2048*1536 = 3,145,728
    float* bufKVN  = bufQKV + 3145728;         // 2048*1024 = 2,097,152
    float* bufKVC  = bufKVN + 2097152;         // 2,097,152
    float* bufE    = bufKVC + 2097152;         // 8 x 1,048,576 below
    float* bufF    = bufE  + 1048576;
    float* bufG    = bufF  + 1048576;
    float* bufH    = bufG  + 1048576;
    float* bufI    = bufH  + 1048576;
    float* bufJ    = bufI  + 1048576;
    float* bufK_   = bufJ  + 1048576;
    float* bufL    = bufK_ + 1048576;
    float* bufM    = ws;                       // FFN hidden 2048*4096, aliases
                                               // region0 (all dead by then)
    float* bufQN   = bufL + 1048576;           // 2,097,152 (qn, later ln_delta)
    // total: 17,825,792 floats = 68 MiB

    const dim3 blk(256);
    const dim3 attn_grid(SEQ / 64, 16);

    // 1. kvn = LN(kv_feats_wt)
    ln_kernel<<<M_ROWS, blk, 0, stream>>>(kvwt, nkv_w, nkv_b, bufKVN, 1024);
    // 2. qkv_wt = kvn @ wqkv_self^T
    gemm_bt<0><<<dim3(1536/64, M_ROWS/64), blk, 0, stream>>>(bufKVN, wqkv_self, bufQKV, 1536, 1024, nullptr);
    // 3. wt_attn
    attn64<<<attn_grid, blk, 0, stream>>>(bufQKV, bufQKV + 512, bufQKV + 1024, bufE, 1536, 1536, 1536, 512);
    // 4. wt_out = wt_attn @ w_out^T  -> output stack[1]
    gemm_bt<0><<<dim3(1024/64, M_ROWS/64), blk, 0, stream>>>(bufE, w_out, wt_out, 1024, 512, nullptr);
    // 5. qn = LN(query_feats)
    ln_kernel<<<M_ROWS, blk, 0, stream>>>(query, nq_w, nq_b, bufQN, 1024);
    // 6. q_c = qn @ wq_cross^T
    gemm_bt<0><<<dim3(512/64, M_ROWS/64), blk, 0, stream>>>(bufQN, wq_cross, bufH, 512, 1024, nullptr);
    // 7. kv_c = kvn @ wkv_cross^T
    gemm_bt<0><<<dim3(1024/64, M_ROWS/64), blk, 0, stream>>>(bufKVN, wkv_cross, bufKVC, 1024, 1024, nullptr);
    // 8. cross_out
    attn64<<<attn_grid, blk, 0, stream>>>(bufH, bufKVC, bufKVC + 512, bufF, 512, 1024, 1024, 512);
    // 9. qkv_s = qn @ wqkv_self^T (reuse bufQKV)
    gemm_bt<0><<<dim3(1536/64, M_ROWS/64), blk, 0, stream>>>(bufQN, wqkv_self, bufQKV, 1536, 1024, nullptr);
    // 10. self_out
    attn64<<<attn_grid, blk, 0, stream>>>(bufQKV, bufQKV + 512, bufQKV + 1024, bufG, 1536, 1536, 1536, 512);
    // 11. son = LN(self_out; gn), con = LN(cross_out; gn)
    ln_kernel<<<M_ROWS, blk, 0, stream>>>(bufG, gn_w, gn_b, bufI, 512);
    ln_kernel<<<M_ROWS, blk, 0, stream>>>(bufF, gn_w, gn_b, bufJ, 512);
    // 12. gq/gk/gv
    gemm_bt<0><<<dim3(512/64, M_ROWS/64), blk, 0, stream>>>(bufI, mha_in_w,              bufH,  512, 512, nullptr);
    gemm_bt<0><<<dim3(512/64, M_ROWS/64), blk, 0, stream>>>(bufJ, mha_in_w + 512*512,    bufK_, 512, 512, nullptr);
    gemm_bt<0><<<dim3(512/64, M_ROWS/64), blk, 0, stream>>>(bufJ, mha_in_w + 1024*512,   bufL,  512, 512, nullptr);
    // 13. gate attention (reuse bufE)
    attn64<<<attn_grid, blk, 0, stream>>>(bufH, bufK_, bufL, bufE, 512, 512, 512, 512);
    // 14. gate_ctx = gate_attn @ mha_out_w^T (reuse bufI)
    gemm_bt<0><<<dim3(512/64, M_ROWS/64), blk, 0, stream>>>(bufE, mha_out_w, bufI, 512, 512, nullptr);
    // 15. mixed = softmax-gate blend of self_out/cross_out (reuse bufJ)
    mix_kernel<<<M_ROWS, blk, 0, stream>>>(bufI, mix_w, mix_b, bufG, bufF, bufJ);
    // 16. delta = mixed @ w_out^T -> output stack[0]
    gemm_bt<0><<<dim3(1024/64, M_ROWS/64), blk, 0, stream>>>(bufJ, w_out, delta_out, 1024, 512, nullptr);
    // 17. ln_delta = LN(delta; ff_ln) (reuse bufQN)
    ln_kernel<<<M_ROWS, blk, 0, stream>>>(delta_out, ff_ln_w, ff_ln_b, bufQN, 1024);
    // 18. ffh = gelu(ln_delta @ ff_fc1^T)  (bufM aliases dead region0)
    gemm_bt<1><<<dim3(4096/64, M_ROWS/64), blk, 0, stream>>>(bufQN, ff_fc1, bufM, 4096, 1024, nullptr);
    // 19. delta += ff_gate * (ffh @ ff_fc2^T)  (read-modify-write epilogue)
    gemm_bt<2><<<dim3(1024/64, M_ROWS/64), blk, 0, stream>>>(bufM, ff_fc2, delta_out, 1024, 4096, ff_gate);
}

// Round 2
// 850.779 us; speedup vs baseline: 1.7687x; 1.7687x over previous
//
#include <hip/hip_runtime.h>
#include <math.h>

// ---------------------------------------------------------------------------
// GatedCrossAttention: B=2, NQ=NK=1024, QD=KVD=OD=1024, H=8, DH=64, INNER=512
// Round 2: bf16 MFMA GEMMs (m97 structure: 128x128x32, global_load_lds w=16,
// mfma_f32_16x16x32_bf16). Attention remains f32 internally, bf16 I/O.
// ---------------------------------------------------------------------------

#define M_ROWS 2048   // B*NQ
#define SEQ    1024

typedef unsigned short u16;
typedef __attribute__((ext_vector_type(8))) short short8;
typedef __attribute__((ext_vector_type(4))) float f32x4;

__device__ inline u16 f2b(float f) {
    unsigned u = __builtin_bit_cast(unsigned, f);
    u += 0x7FFFu + ((u >> 16) & 1u);   // round-to-nearest-even
    return (u16)(u >> 16);
}
__device__ inline float b2f(u16 h) {
    return __builtin_bit_cast(float, (unsigned)h << 16);
}

__device__ inline void gload16(const u16* g, u16* l) {
    __builtin_amdgcn_global_load_lds(
        (const __attribute__((address_space(1))) void*)g,
        (__attribute__((address_space(3))) void*)l, 16, 0, 0);
}

// ------------------------- f32 -> bf16 convert -----------------------------
__global__ __launch_bounds__(256)
void f2b_kernel(const float* __restrict__ in, u16* __restrict__ out, int n)
{
    const int i = (blockIdx.x * 256 + threadIdx.x) * 4;
    if (i < n) {
        const float4 v = *reinterpret_cast<const float4*>(&in[i]);
        ushort4 o;
        o.x = f2b(v.x); o.y = f2b(v.y); o.z = f2b(v.z); o.w = f2b(v.w);
        *reinterpret_cast<ushort4*>(&out[i]) = o;
    }
}

// ----------------------------- LayerNorm -----------------------------------
// One block per row, f32 in, bf16 out. D in {512, 1024}.
__global__ __launch_bounds__(256)
void ln_bf16(const float* __restrict__ x, const float* __restrict__ w,
             const float* __restrict__ bias, u16* __restrict__ out, int D)
{
    const size_t row = blockIdx.x;
    const float* xr = x + row * (size_t)D;
    const int c = threadIdx.x * 4;
    float4 v = make_float4(0.f, 0.f, 0.f, 0.f);
    if (c < D) v = *reinterpret_cast<const float4*>(&xr[c]);
    float sum = v.x + v.y + v.z + v.w;
    float sq  = v.x*v.x + v.y*v.y + v.z*v.z + v.w*v.w;
    #pragma unroll
    for (int off = 32; off > 0; off >>= 1) {
        sum += __shfl_down(sum, off);
        sq  += __shfl_down(sq,  off);
    }
    __shared__ float s1[4], s2[4];
    const int wid = threadIdx.x >> 6;
    if ((threadIdx.x & 63) == 0) { s1[wid] = sum; s2[wid] = sq; }
    __syncthreads();
    const float tsum = s1[0] + s1[1] + s1[2] + s1[3];
    const float tsq  = s2[0] + s2[1] + s2[2] + s2[3];
    const float mean = tsum / (float)D;
    const float var  = tsq / (float)D - mean * mean;
    const float rstd = rsqrtf(var + 1e-5f);
    if (c < D) {
        ushort4 o;
        o.x = f2b((v.x - mean) * rstd * w[c+0] + bias[c+0]);
        o.y = f2b((v.y - mean) * rstd * w[c+1] + bias[c+1]);
        o.z = f2b((v.z - mean) * rstd * w[c+2] + bias[c+2]);
        o.w = f2b((v.w - mean) * rstd * w[c+3] + bias[c+3]);
        *reinterpret_cast<ushort4*>(&out[row * (size_t)D + c]) = o;
    }
}

// ------------------------------ MFMA GEMM ----------------------------------
// C[M,N] = A[M,K] * W[N,K]^T, A/W bf16, acc f32. 128x128 tile, BK=32,
// 4 waves (2x2), 4x4 16x16 fragments per wave. m97 staging: 2x
// global_load_lds(16B) per matrix per K-step, linear LDS [128][32].
// EPI: 0=none, 1=exact GELU, 2=C += gate*acc (f32 RMW). OB: bf16 output.
template<int EPI, int OB>
__global__ __launch_bounds__(256)
void gemm_mfma(const u16* __restrict__ A, const u16* __restrict__ W,
               void* __restrict__ Cv, int N, int K, const float* __restrict__ gatep)
{
    __shared__ __align__(16) u16 As[128 * 32];
    __shared__ __align__(16) u16 Ws[128 * 32];
    const int tid  = threadIdx.x;
    const int lane = tid & 63;
    const int wave = tid >> 6;
    const int wr = wave >> 1, wc = wave & 1;
    const int m0 = blockIdx.y * 128, n0 = blockIdx.x * 128;

    // staging: element e = (inst*256 + tid)*8 -> row = e/32, col = e%32
    const int srow = tid >> 2;
    const int scol = (tid & 3) * 8;
    const u16* Ag = A + (size_t)(m0 + srow) * K + scol;
    const u16* Wg = W + (size_t)(n0 + srow) * K + scol;
    u16* AsL = &As[tid * 8];
    u16* WsL = &Ws[tid * 8];

    const int fr = lane & 15;      // A/B fragment row (m or n within 16)
    const int fq = lane >> 4;      // k-group (8 elems each)
    const int arow0 = wr * 64 + fr;
    const int brow0 = wc * 64 + fr;

    f32x4 acc[4][4] = {};

    for (int k0 = 0; k0 < K; k0 += 32) {
        gload16(Ag + k0,                  AsL);
        gload16(Ag + k0 + (size_t)64 * K, AsL + 2048);
        gload16(Wg + k0,                  WsL);
        gload16(Wg + k0 + (size_t)64 * K, WsL + 2048);
        __syncthreads();   // drains vmcnt before barrier (compiler-inserted)

        short8 a[4], b[4];
        #pragma unroll
        for (int m = 0; m < 4; ++m)
            a[m] = *reinterpret_cast<const short8*>(&As[(arow0 + m * 16) * 32 + fq * 8]);
        #pragma unroll
        for (int n = 0; n < 4; ++n)
            b[n] = *reinterpret_cast<const short8*>(&Ws[(brow0 + n * 16) * 32 + fq * 8]);
        #pragma unroll
        for (int m = 0; m < 4; ++m)
            #pragma unroll
            for (int n = 0; n < 4; ++n)
                acc[m][n] = __builtin_amdgcn_mfma_f32_16x16x32_bf16(
                    a[m], b[n], acc[m][n], 0, 0, 0);
        __syncthreads();   // all LDS reads done before next stage
    }

    // C/D layout: col = lane&15, row = (lane>>4)*4 + reg  [m89/m91 verified]
    const float gate = (EPI == 2) ? gatep[0] : 0.f;
    #pragma unroll
    for (int m = 0; m < 4; ++m) {
        #pragma unroll
        for (int j = 0; j < 4; ++j) {
            const size_t row = (size_t)(m0 + wr * 64 + m * 16 + fq * 4 + j);
            #pragma unroll
            for (int n = 0; n < 4; ++n) {
                float v = acc[m][n][j];
                const size_t idx = row * (size_t)N + (size_t)(n0 + wc * 64 + n * 16 + fr);
                if (EPI == 1) v = 0.5f * v * (1.f + erff(v * 0.70710678118654752f));
                if (OB) {
                    ((u16*)Cv)[idx] = f2b(v);
                } else {
                    float* C = (float*)Cv;
                    if (EPI == 2) C[idx] = C[idx] + gate * v;
                    else          C[idx] = v;
                }
            }
        }
    }
}

// --------------------------- Fused attention -------------------------------
// bf16 Q/K/V in, f32 math, f32 or bf16 out. grid = (NQ/64, B*H).
template<int OB>
__global__ __launch_bounds__(256)
void attn64(const u16* __restrict__ Q, const u16* __restrict__ K,
            const u16* __restrict__ V, void* __restrict__ Ov,
            int qs, int ks, int vs, int os)
{
    __shared__ float Qs[64][65];
    __shared__ float Ks[64][65];   // reused to hold P after S is computed
    __shared__ float Vs[64][65];
    const int tid = threadIdx.x;
    const int ty = tid >> 4, tx = tid & 15;
    const int b  = blockIdx.y >> 3;
    const int hc = (blockIdx.y & 7) * 64;
    const size_t qrow0 = (size_t)b * SEQ + (size_t)blockIdx.x * 64;
    const size_t krow0 = (size_t)b * SEQ;
    const int lr = tid >> 4;
    const int lc = (tid & 15) * 4;

    #pragma unroll
    for (int p = 0; p < 4; ++p) {
        const int r = p * 16 + lr;
        const ushort4 q4 = *reinterpret_cast<const ushort4*>(&Q[(qrow0 + r) * qs + hc + lc]);
        Qs[r][lc+0] = b2f(q4.x) * 0.125f;
        Qs[r][lc+1] = b2f(q4.y) * 0.125f;
        Qs[r][lc+2] = b2f(q4.z) * 0.125f;
        Qs[r][lc+3] = b2f(q4.w) * 0.125f;
    }

    float m[4], l[4], acc[4][4];
    #pragma unroll
    for (int i = 0; i < 4; ++i) {
        m[i] = -1e30f; l[i] = 0.f;
        #pragma unroll
        for (int j = 0; j < 4; ++j) acc[i][j] = 0.f;
    }

    for (int kt = 0; kt < SEQ / 64; ++kt) {
        __syncthreads();
        #pragma unroll
        for (int p = 0; p < 4; ++p) {
            const int r = p * 16 + lr;
            const size_t gr = krow0 + kt * 64 + r;
            const ushort4 k4 = *reinterpret_cast<const ushort4*>(&K[gr * ks + hc + lc]);
            Ks[r][lc+0] = b2f(k4.x); Ks[r][lc+1] = b2f(k4.y);
            Ks[r][lc+2] = b2f(k4.z); Ks[r][lc+3] = b2f(k4.w);
            const ushort4 v4 = *reinterpret_cast<const ushort4*>(&V[gr * vs + hc + lc]);
            Vs[r][lc+0] = b2f(v4.x); Vs[r][lc+1] = b2f(v4.y);
            Vs[r][lc+2] = b2f(v4.z); Vs[r][lc+3] = b2f(v4.w);
        }
        __syncthreads();

        float s[4][4] = {};
        #pragma unroll 8
        for (int d = 0; d < 64; ++d) {
            float qv[4], kv[4];
            #pragma unroll
            for (int i = 0; i < 4; ++i) qv[i] = Qs[ty * 4 + i][d];
            #pragma unroll
            for (int j = 0; j < 4; ++j) kv[j] = Ks[tx * 4 + j][d];
            #pragma unroll
            for (int i = 0; i < 4; ++i)
                #pragma unroll
                for (int j = 0; j < 4; ++j)
                    s[i][j] = fmaf(qv[i], kv[j], s[i][j]);
        }

        float corr[4];
        #pragma unroll
        for (int i = 0; i < 4; ++i) {
            float mx = fmaxf(fmaxf(s[i][0], s[i][1]), fmaxf(s[i][2], s[i][3]));
            #pragma unroll
            for (int off = 1; off < 16; off <<= 1)
                mx = fmaxf(mx, __shfl_xor(mx, off, 16));
            const float mnew = fmaxf(m[i], mx);
            corr[i] = __expf(m[i] - mnew);
            m[i] = mnew;
            float sm = 0.f;
            #pragma unroll
            for (int j = 0; j < 4; ++j) {
                s[i][j] = __expf(s[i][j] - mnew);
                sm += s[i][j];
            }
            #pragma unroll
            for (int off = 1; off < 16; off <<= 1)
                sm += __shfl_xor(sm, off, 16);
            l[i] = l[i] * corr[i] + sm;
            #pragma unroll
            for (int j = 0; j < 4; ++j) acc[i][j] *= corr[i];
        }

        __syncthreads();
        #pragma unroll
        for (int i = 0; i < 4; ++i)
            #pragma unroll
            for (int j = 0; j < 4; ++j)
                Ks[ty * 4 + i][tx * 4 + j] = s[i][j];
        __syncthreads();

        #pragma unroll 8
        for (int jj = 0; jj < 64; ++jj) {
            float pv[4], vv[4];
            #pragma unroll
            for (int i = 0; i < 4; ++i) pv[i] = Ks[ty * 4 + i][jj];
            #pragma unroll
            for (int j = 0; j < 4; ++j) vv[j] = Vs[jj][tx * 4 + j];
            #pragma unroll
            for (int i = 0; i < 4; ++i)
                #pragma unroll
                for (int j = 0; j < 4; ++j)
                    acc[i][j] = fmaf(pv[i], vv[j], acc[i][j]);
        }
    }

    #pragma unroll
    for (int i = 0; i < 4; ++i) {
        const float inv = 1.f / l[i];
        const size_t orow = (qrow0 + ty * 4 + i) * os + hc + tx * 4;
        if (OB) {
            ushort4 o;
            o.x = f2b(acc[i][0] * inv); o.y = f2b(acc[i][1] * inv);
            o.z = f2b(acc[i][2] * inv); o.w = f2b(acc[i][3] * inv);
            *reinterpret_cast<ushort4*>(&((u16*)Ov)[orow]) = o;
        } else {
            float4 o;
            o.x = acc[i][0] * inv; o.y = acc[i][1] * inv;
            o.z = acc[i][2] * inv; o.w = acc[i][3] * inv;
            *reinterpret_cast<float4*>(&((float*)Ov)[orow]) = o;
        }
    }
}

// -------------------- gate mix (dot, softmax-2, blend) ---------------------
__global__ __launch_bounds__(256)
void mix_kernel(const float* __restrict__ gctx, const float* __restrict__ mixw,
                const float* __restrict__ mixb, const float* __restrict__ so,
                const float* __restrict__ co, u16* __restrict__ mixed)
{
    const size_t row = blockIdx.x;
    const float* g = gctx + row * 512;
    float d0 = 0.f, d1 = 0.f;
    for (int c = threadIdx.x; c < 512; c += 256) {
        const float gv = g[c];
        d0 = fmaf(gv, mixw[c], d0);
        d1 = fmaf(gv, mixw[512 + c], d1);
    }
    #pragma unroll
    for (int off = 32; off > 0; off >>= 1) {
        d0 += __shfl_down(d0, off);
        d1 += __shfl_down(d1, off);
    }
    __shared__ float sA[4], sB[4];
    const int wid = threadIdx.x >> 6;
    if ((threadIdx.x & 63) == 0) { sA[wid] = d0; sB[wid] = d1; }
    __syncthreads();
    const float t0 = sA[0] + sA[1] + sA[2] + sA[3] + mixb[0];
    const float t1 = sB[0] + sB[1] + sB[2] + sB[3] + mixb[1];
    const float mx = fmaxf(t0, t1);
    const float e0 = __expf(t0 - mx), e1 = __expf(t1 - mx);
    const float inv = 1.f / (e0 + e1);
    const float w0 = e0 * inv, w1 = e1 * inv;
    for (int c = threadIdx.x; c < 512; c += 256)
        mixed[row * 512 + c] = f2b(w0 * so[row * 512 + c] + w1 * co[row * 512 + c]);
}

// ---------------------------------------------------------------------------
extern "C" void kernel_launch(void* const* d_in, const int* in_sizes, int n_in,
                              void* d_out, int out_size, void* d_ws, size_t ws_size,
                              hipStream_t stream)
{
    const float* query     = (const float*)d_in[0];
    const float* kvwt      = (const float*)d_in[1];
    const float* nq_w      = (const float*)d_in[2];
    const float* nq_b      = (const float*)d_in[3];
    const float* nkv_w     = (const float*)d_in[4];
    const float* nkv_b     = (const float*)d_in[5];
    const float* wq_cross  = (const float*)d_in[6];
    const float* wkv_cross = (const float*)d_in[7];
    const float* wqkv_self = (const float*)d_in[8];
    const float* gn_w      = (const float*)d_in[9];
    const float* gn_b      = (const float*)d_in[10];
    const float* mha_in_w  = (const float*)d_in[11];
    const float* mha_out_w = (const float*)d_in[12];
    const float* mix_w     = (const float*)d_in[13];
    const float* mix_b     = (const float*)d_in[14];
    const float* w_out     = (const float*)d_in[15];
    const float* ff_ln_w   = (const float*)d_in[16];
    const float* ff_ln_b   = (const float*)d_in[17];
    const float* ff_fc1    = (const float*)d_in[18];
    const float* ff_fc2    = (const float*)d_in[19];
    const float* ff_gate   = (const float*)d_in[20];

    float* delta_out = (float*)d_out;                          // stack[0]
    float* wt_out    = (float*)d_out + (size_t)M_ROWS * 1024;  // stack[1]

    // ---- workspace layout (byte offsets; total 59,768,832 B = 57 MB) ----
    char* wsb = (char*)d_ws;
    u16*   qkv_b   = (u16*)  (wsb + 0);          // 6,291,456 B bf16 [2048,1536]; gq/gk/gv; ffh alias
    u16*   kv_c_b  = (u16*)  (wsb + 6291456);    // 4,194,304 B bf16 [2048,1024]; gctx_f alias
    u16*   q_c_b   = (u16*)  (wsb + 10485760);   // 2,097,152 B bf16 [2048,512]
    float* cross_f = (float*)(wsb + 12582912);   // 4,194,304 B f32  [2048,512]
    float* self_f  = (float*)(wsb + 16777216);   // 4,194,304 B f32  [2048,512]
    u16*   kvn_b   = (u16*)  (wsb + 20971520);   // 4,194,304 B bf16 [2048,1024]
    u16*   qn_b    = (u16*)  (wsb + 25165824);   // 4,194,304 B bf16 [2048,1024]; lnd alias
    u16*   wta_b   = (u16*)  (wsb + 29360128);   // 2,097,152 B bf16 [2048,512]; son alias
    u16*   con_b   = (u16*)  (wsb + 31457280);   // 2,097,152 B bf16 [2048,512]
    // aliases (liveness audited):
    u16*   gq_b    = qkv_b;                      // live 12-13 (qkv dead after 10)
    u16*   gk_b    = qkv_b + 1048576;
    u16*   gv_b    = qkv_b + 2097152;
    float* gctx_f  = (float*)kv_c_b;             // live 14-15 (kv_c dead after 8)
    u16*   gattn_b = kvn_b;                      // live 13-14 (kvn dead after 7)
    u16*   mixed_b = kvn_b + 1048576;            // live 15-16
    u16*   lnd_b   = qn_b;                       // live 17-18 (qn dead after 9)
    u16*   son_b   = wta_b;                      // live 11-12 (wta dead after 4)
    u16*   ffh_b   = qkv_b;                      // 16,777,216 B, live 18-19
                                                 // (spans qkv+kv_c+q_c+cross, all dead by 18)
    // bf16 weights:
    u16* wqkv_self_b = (u16*)(wsb + 33554432);   // 3,145,728
    u16* wq_cross_b  = (u16*)(wsb + 36700160);   // 1,048,576
    u16* wkv_cross_b = (u16*)(wsb + 37748736);   // 2,097,152
    u16* mha_in_b    = (u16*)(wsb + 39845888);   // 1,572,864
    u16* mha_out_b   = (u16*)(wsb + 41418752);   //   524,288
    u16* w_out_b     = (u16*)(wsb + 41943040);   // 1,048,576
    u16* ff_fc1_b    = (u16*)(wsb + 42991616);   // 8,388,608
    u16* ff_fc2_b    = (u16*)(wsb + 51380224);   // 8,388,608

    const dim3 blk(256);
    const dim3 attn_grid(SEQ / 64, 16);
    auto cvt = [&](const float* src, u16* dst, int n) {
        f2b_kernel<<<dim3(n / 1024), blk, 0, stream>>>(src, dst, n);
    };
    auto gemm_grid = [](int N) { return dim3(N / 128, M_ROWS / 128); };

    // 0. weight conversions
    cvt(wqkv_self, wqkv_self_b, 1536 * 1024);
    cvt(wq_cross,  wq_cross_b,   512 * 1024);
    cvt(wkv_cross, wkv_cross_b, 1024 * 1024);
    cvt(mha_in_w,  mha_in_b,    1536 * 512);
    cvt(mha_out_w, mha_out_b,    512 * 512);
    cvt(w_out,     w_out_b,     1024 * 512);
    cvt(ff_fc1,    ff_fc1_b,    4096 * 1024);
    cvt(ff_fc2,    ff_fc2_b,    1024 * 4096);

    // 1. kvn = LN(kv_feats_wt)
    ln_bf16<<<M_ROWS, blk, 0, stream>>>(kvwt, nkv_w, nkv_b, kvn_b, 1024);
    // 2. qkv_wt = kvn @ wqkv_self^T
    gemm_mfma<0,1><<<gemm_grid(1536), blk, 0, stream>>>(kvn_b, wqkv_self_b, qkv_b, 1536, 1024, nullptr);
    // 3. wt_attn (bf16 out)
    attn64<1><<<attn_grid, blk, 0, stream>>>(qkv_b, qkv_b + 512, qkv_b + 1024, wta_b, 1536, 1536, 1536, 512);
    // 4. wt_out = wt_attn @ w_out^T -> output stack[1]
    gemm_mfma<0,0><<<gemm_grid(1024), blk, 0, stream>>>(wta_b, w_out_b, wt_out, 1024, 512, nullptr);
    // 5. qn = LN(query_feats)
    ln_bf16<<<M_ROWS, blk, 0, stream>>>(query, nq_w, nq_b, qn_b, 1024);
    // 6. q_c = qn @ wq_cross^T
    gemm_mfma<0,1><<<gemm_grid(512), blk, 0, stream>>>(qn_b, wq_cross_b, q_c_b, 512, 1024, nullptr);
    // 7. kv_c = kvn @ wkv_cross^T
    gemm_mfma<0,1><<<gemm_grid(1024), blk, 0, stream>>>(kvn_b, wkv_cross_b, kv_c_b, 1024, 1024, nullptr);
    // 8. cross_out (f32 out)
    attn64<0><<<attn_grid, blk, 0, stream>>>(q_c_b, kv_c_b, kv_c_b + 512, cross_f, 512, 1024, 1024, 512);
    // 9. qkv_s = qn @ wqkv_self^T
    gemm_mfma<0,1><<<gemm_grid(1536), blk, 0, stream>>>(qn_b, wqkv_self_b, qkv_b, 1536, 1024, nullptr);
    // 10. self_out (f32 out)
    attn64<0><<<attn_grid, blk, 0, stream>>>(qkv_b, qkv_b + 512, qkv_b + 1024, self_f, 1536, 1536, 1536, 512);
    // 11. son = LN(self_out; gn), con = LN(cross_out; gn)
    ln_bf16<<<M_ROWS, blk, 0, stream>>>(self_f,  gn_w, gn_b, son_b, 512);
    ln_bf16<<<M_ROWS, blk, 0, stream>>>(cross_f, gn_w, gn_b, con_b, 512);
    // 12. gq/gk/gv
    gemm_mfma<0,1><<<gemm_grid(512), blk, 0, stream>>>(son_b, mha_in_b,              gq_b, 512, 512, nullptr);
    gemm_mfma<0,1><<<gemm_grid(512), blk, 0, stream>>>(con_b, mha_in_b + 512*512,    gk_b, 512, 512, nullptr);
    gemm_mfma<0,1><<<gemm_grid(512), blk, 0, stream>>>(con_b, mha_in_b + 1024*512,   gv_b, 512, 512, nullptr);
    // 13. gate attention (bf16 out)
    attn64<1><<<attn_grid, blk, 0, stream>>>(gq_b, gk_b, gv_b, gattn_b, 512, 512, 512, 512);
    // 14. gate_ctx = gate_attn @ mha_out_w^T (f32 out)
    gemm_mfma<0,0><<<gemm_grid(512), blk, 0, stream>>>(gattn_b, mha_out_b, gctx_f, 512, 512, nullptr);
    // 15. mixed = softmax-gate blend (bf16 out)
    mix_kernel<<<M_ROWS, blk, 0, stream>>>(gctx_f, mix_w, mix_b, self_f, cross_f, mixed_b);
    // 16. delta = mixed @ w_out^T -> output stack[0] (f32)
    gemm_mfma<0,0><<<gemm_grid(1024), blk, 0, stream>>>(mixed_b, w_out_b, delta_out, 1024, 512, nullptr);
    // 17. ln_delta = LN(delta; ff_ln)
    ln_bf16<<<M_ROWS, blk, 0, stream>>>(delta_out, ff_ln_w, ff_ln_b, lnd_b, 1024);
    // 18. ffh = gelu(ln_delta @ ff_fc1^T) (bf16 out, GELU epilogue)
    gemm_mfma<1,1><<<gemm_grid(4096), blk, 0, stream>>>(lnd_b, ff_fc1_b, ffh_b, 4096, 1024, nullptr);
    // 19. delta += ff_gate * (ffh @ ff_fc2^T) (f32 RMW epilogue)
    gemm_mfma<2,0><<<gemm_grid(1024), blk, 0, stream>>>(ffh_b, ff_fc2_b, delta_out, 1024, 4096, ff_gate);
}

// Round 3
// 482.167 us; speedup vs baseline: 3.1208x; 1.7645x over previous
//
#include <hip/hip_runtime.h>
#include <math.h>

// ---------------------------------------------------------------------------
// GatedCrossAttention: B=2, NQ=NK=1024, QD=KVD=OD=1024, H=8, DH=64, INNER=512
// Round 3: bf16 MFMA attention (swapped-QK^T, wave-private P round-trip,
// transposed-V staging). GEMMs unchanged (m97-structure 128x128x32 bf16).
// ---------------------------------------------------------------------------

#define M_ROWS 2048   // B*NQ
#define SEQ    1024

typedef unsigned short u16;
typedef __attribute__((ext_vector_type(8))) short short8;
typedef __attribute__((ext_vector_type(4))) float f32x4;

__device__ inline u16 f2b(float f) {
    unsigned u = __builtin_bit_cast(unsigned, f);
    u += 0x7FFFu + ((u >> 16) & 1u);   // round-to-nearest-even
    return (u16)(u >> 16);
}
__device__ inline float b2f(u16 h) {
    return __builtin_bit_cast(float, (unsigned)h << 16);
}

__device__ inline void gload16(const u16* g, u16* l) {
    __builtin_amdgcn_global_load_lds(
        (const __attribute__((address_space(1))) void*)g,
        (__attribute__((address_space(3))) void*)l, 16, 0, 0);
}

// ------------------------- f32 -> bf16 convert -----------------------------
__global__ __launch_bounds__(256)
void f2b_kernel(const float* __restrict__ in, u16* __restrict__ out, int n)
{
    const int i = (blockIdx.x * 256 + threadIdx.x) * 4;
    if (i < n) {
        const float4 v = *reinterpret_cast<const float4*>(&in[i]);
        ushort4 o;
        o.x = f2b(v.x); o.y = f2b(v.y); o.z = f2b(v.z); o.w = f2b(v.w);
        *reinterpret_cast<ushort4*>(&out[i]) = o;
    }
}

// ----------------------------- LayerNorm -----------------------------------
__global__ __launch_bounds__(256)
void ln_bf16(const float* __restrict__ x, const float* __restrict__ w,
             const float* __restrict__ bias, u16* __restrict__ out, int D)
{
    const size_t row = blockIdx.x;
    const float* xr = x + row * (size_t)D;
    const int c = threadIdx.x * 4;
    float4 v = make_float4(0.f, 0.f, 0.f, 0.f);
    if (c < D) v = *reinterpret_cast<const float4*>(&xr[c]);
    float sum = v.x + v.y + v.z + v.w;
    float sq  = v.x*v.x + v.y*v.y + v.z*v.z + v.w*v.w;
    #pragma unroll
    for (int off = 32; off > 0; off >>= 1) {
        sum += __shfl_down(sum, off);
        sq  += __shfl_down(sq,  off);
    }
    __shared__ float s1[4], s2[4];
    const int wid = threadIdx.x >> 6;
    if ((threadIdx.x & 63) == 0) { s1[wid] = sum; s2[wid] = sq; }
    __syncthreads();
    const float tsum = s1[0] + s1[1] + s1[2] + s1[3];
    const float tsq  = s2[0] + s2[1] + s2[2] + s2[3];
    const float mean = tsum / (float)D;
    const float var  = tsq / (float)D - mean * mean;
    const float rstd = rsqrtf(var + 1e-5f);
    if (c < D) {
        ushort4 o;
        o.x = f2b((v.x - mean) * rstd * w[c+0] + bias[c+0]);
        o.y = f2b((v.y - mean) * rstd * w[c+1] + bias[c+1]);
        o.z = f2b((v.z - mean) * rstd * w[c+2] + bias[c+2]);
        o.w = f2b((v.w - mean) * rstd * w[c+3] + bias[c+3]);
        *reinterpret_cast<ushort4*>(&out[row * (size_t)D + c]) = o;
    }
}

// ------------------------------ MFMA GEMM ----------------------------------
// C[M,N] = A[M,K]*W[N,K]^T, bf16 in, f32 acc. 128x128x32, 4 waves, m97-style.
template<int EPI, int OB>
__global__ __launch_bounds__(256)
void gemm_mfma(const u16* __restrict__ A, const u16* __restrict__ W,
               void* __restrict__ Cv, int N, int K, const float* __restrict__ gatep)
{
    __shared__ __align__(16) u16 As[128 * 32];
    __shared__ __align__(16) u16 Ws[128 * 32];
    const int tid  = threadIdx.x;
    const int lane = tid & 63;
    const int wave = tid >> 6;
    const int wr = wave >> 1, wc = wave & 1;
    const int m0 = blockIdx.y * 128, n0 = blockIdx.x * 128;

    const int srow = tid >> 2;
    const int scol = (tid & 3) * 8;
    const u16* Ag = A + (size_t)(m0 + srow) * K + scol;
    const u16* Wg = W + (size_t)(n0 + srow) * K + scol;
    u16* AsL = &As[tid * 8];
    u16* WsL = &Ws[tid * 8];

    const int fr = lane & 15;
    const int fq = lane >> 4;
    const int arow0 = wr * 64 + fr;
    const int brow0 = wc * 64 + fr;

    f32x4 acc[4][4] = {};

    for (int k0 = 0; k0 < K; k0 += 32) {
        gload16(Ag + k0,                  AsL);
        gload16(Ag + k0 + (size_t)64 * K, AsL + 2048);
        gload16(Wg + k0,                  WsL);
        gload16(Wg + k0 + (size_t)64 * K, WsL + 2048);
        __syncthreads();

        short8 a[4], b[4];
        #pragma unroll
        for (int m = 0; m < 4; ++m)
            a[m] = *reinterpret_cast<const short8*>(&As[(arow0 + m * 16) * 32 + fq * 8]);
        #pragma unroll
        for (int n = 0; n < 4; ++n)
            b[n] = *reinterpret_cast<const short8*>(&Ws[(brow0 + n * 16) * 32 + fq * 8]);
        #pragma unroll
        for (int m = 0; m < 4; ++m)
            #pragma unroll
            for (int n = 0; n < 4; ++n)
                acc[m][n] = __builtin_amdgcn_mfma_f32_16x16x32_bf16(
                    a[m], b[n], acc[m][n], 0, 0, 0);
        __syncthreads();
    }

    const float gate = (EPI == 2) ? gatep[0] : 0.f;
    #pragma unroll
    for (int m = 0; m < 4; ++m) {
        #pragma unroll
        for (int j = 0; j < 4; ++j) {
            const size_t row = (size_t)(m0 + wr * 64 + m * 16 + fq * 4 + j);
            #pragma unroll
            for (int n = 0; n < 4; ++n) {
                float v = acc[m][n][j];
                const size_t idx = row * (size_t)N + (size_t)(n0 + wc * 64 + n * 16 + fr);
                if (EPI == 1) v = 0.5f * v * (1.f + erff(v * 0.70710678118654752f));
                if (OB) {
                    ((u16*)Cv)[idx] = f2b(v);
                } else {
                    float* C = (float*)Cv;
                    if (EPI == 2) C[idx] = C[idx] + gate * v;
                    else          C[idx] = v;
                }
            }
        }
    }
}

// ------------------------- MFMA fused attention ----------------------------
// grid = (NQ/64, B*H), 256 threads = 4 waves x 16 q-rows. bf16 QKV.
// Swapped QK^T: ST = mfma(K_rows, Q_rows) -> lane owns q-col (lane&15),
// softmax = in-lane 16-max + 2 shfl_xor. P packed bf16 into wave-private LDS
// (no barrier), re-read as PV A-frag. V staged transposed Vt[d][kv].
template<int OB>
__global__ __launch_bounds__(256)
void attn_mfma(const u16* __restrict__ Q, const u16* __restrict__ K,
               const u16* __restrict__ V, void* __restrict__ Ov,
               int qs, int ks, int vs, int os)
{
    __shared__ __align__(16) u16 Ks[64 * 72];      // [kv][d], pad 72
    __shared__ __align__(16) u16 Vt[64 * 72];      // [d][kv], pad 72
    __shared__ __align__(16) u16 Ps[4][16 * 72];   // per-wave P [q][kv]
    const int tid  = threadIdx.x;
    const int lane = tid & 63;
    const int wave = tid >> 6;
    const int fr = lane & 15;
    const int fq = lane >> 4;
    const int b  = blockIdx.y >> 3;
    const int hc = (blockIdx.y & 7) * 64;
    const size_t qrow0 = (size_t)b * SEQ + (size_t)blockIdx.x * 64;
    const size_t krow0 = (size_t)b * SEQ;

    // Q B-frags (rows of Q): lane holds q-row = fr, d-chunk fq*8 within 32.
    short8 qf[2];
    {
        const u16* qp = Q + (qrow0 + wave * 16 + fr) * qs + hc + fq * 8;
        qf[0] = *reinterpret_cast<const short8*>(qp);
        qf[1] = *reinterpret_cast<const short8*>(qp + 32);
    }

    // staging maps
    const int skr = tid >> 2;            // K row 0..63
    const int skc = (tid & 3) * 16;      // K col base {0,16,32,48}
    const int svk = (tid >> 4) * 4;      // V kv0 0..60
    const int svd = (tid & 15) * 4;      // V d0  0..60

    float m_run = -1e30f, l_run = 0.f;
    f32x4 acc[4] = {};                   // [nd]; d = nd*16+fr, q = fq*4+reg

    for (int kt = 0; kt < SEQ / 64; ++kt) {
        __syncthreads();                 // prev-tile LDS reads complete
        {   // stage K [kv][d]
            const u16* kp = K + (krow0 + kt * 64 + skr) * ks + hc + skc;
            *reinterpret_cast<short8*>(&Ks[skr * 72 + skc]) =
                *reinterpret_cast<const short8*>(kp);
            *reinterpret_cast<short8*>(&Ks[skr * 72 + skc + 8]) =
                *reinterpret_cast<const short8*>(kp + 8);
        }
        {   // stage V transposed: Vt[d][kv]
            const u16* vp = V + (krow0 + kt * 64 + svk) * vs + hc + svd;
            const ushort4 l0 = *reinterpret_cast<const ushort4*>(vp);
            const ushort4 l1 = *reinterpret_cast<const ushort4*>(vp + vs);
            const ushort4 l2 = *reinterpret_cast<const ushort4*>(vp + 2 * (size_t)vs);
            const ushort4 l3 = *reinterpret_cast<const ushort4*>(vp + 3 * (size_t)vs);
            uint2 w;
            w.x = (unsigned)l0.x | ((unsigned)l1.x << 16);
            w.y = (unsigned)l2.x | ((unsigned)l3.x << 16);
            *reinterpret_cast<uint2*>(&Vt[(svd + 0) * 72 + svk]) = w;
            w.x = (unsigned)l0.y | ((unsigned)l1.y << 16);
            w.y = (unsigned)l2.y | ((unsigned)l3.y << 16);
            *reinterpret_cast<uint2*>(&Vt[(svd + 1) * 72 + svk]) = w;
            w.x = (unsigned)l0.z | ((unsigned)l1.z << 16);
            w.y = (unsigned)l2.z | ((unsigned)l3.z << 16);
            *reinterpret_cast<uint2*>(&Vt[(svd + 2) * 72 + svk]) = w;
            w.x = (unsigned)l0.w | ((unsigned)l1.w << 16);
            w.y = (unsigned)l2.w | ((unsigned)l3.w << 16);
            *reinterpret_cast<uint2*>(&Vt[(svd + 3) * 72 + svk]) = w;
        }
        __syncthreads();

        // ST = K·Q^T: st[kn] holds S[kv=kn*16+fq*4+reg][q=fr]
        f32x4 st[4] = {};
        #pragma unroll
        for (int kn = 0; kn < 4; ++kn) {
            const short8 ka0 = *reinterpret_cast<const short8*>(
                &Ks[(kn * 16 + fr) * 72 + fq * 8]);
            const short8 ka1 = *reinterpret_cast<const short8*>(
                &Ks[(kn * 16 + fr) * 72 + 32 + fq * 8]);
            st[kn] = __builtin_amdgcn_mfma_f32_16x16x32_bf16(ka0, qf[0], st[kn], 0, 0, 0);
            st[kn] = __builtin_amdgcn_mfma_f32_16x16x32_bf16(ka1, qf[1], st[kn], 0, 0, 0);
        }

        // online softmax for q-row = fr (16 kv values in-lane, x4 lanes-groups)
        float mx = -1e30f;
        #pragma unroll
        for (int kn = 0; kn < 4; ++kn)
            #pragma unroll
            for (int r = 0; r < 4; ++r) {
                st[kn][r] *= 0.125f;
                mx = fmaxf(mx, st[kn][r]);
            }
        mx = fmaxf(mx, __shfl_xor(mx, 16, 64));
        mx = fmaxf(mx, __shfl_xor(mx, 32, 64));
        const float mnew = fmaxf(m_run, mx);
        const float corr = __expf(m_run - mnew);
        m_run = mnew;
        float psum = 0.f;
        #pragma unroll
        for (int kn = 0; kn < 4; ++kn) {
            const float p0 = __expf(st[kn][0] - mnew);
            const float p1 = __expf(st[kn][1] - mnew);
            const float p2 = __expf(st[kn][2] - mnew);
            const float p3 = __expf(st[kn][3] - mnew);
            psum += (p0 + p1) + (p2 + p3);
            uint2 w;
            w.x = (unsigned)f2b(p0) | ((unsigned)f2b(p1) << 16);
            w.y = (unsigned)f2b(p2) | ((unsigned)f2b(p3) << 16);
            *reinterpret_cast<uint2*>(&Ps[wave][fr * 72 + kn * 16 + fq * 4]) = w;
        }
        psum += __shfl_xor(psum, 16, 64);
        psum += __shfl_xor(psum, 32, 64);
        l_run = l_run * corr + psum;

        // rescale O by corr of the q-rows this lane accumulates (q = fq*4+j)
        float cq[4];
        #pragma unroll
        for (int j = 0; j < 4; ++j) cq[j] = __shfl(corr, fq * 4 + j, 64);
        #pragma unroll
        for (int nd = 0; nd < 4; ++nd)
            #pragma unroll
            for (int j = 0; j < 4; ++j)
                acc[nd][j] *= cq[j];

        // PV: A-frag = P rows (wave-private LDS round-trip, lgkm-ordered)
        short8 pa0 = *reinterpret_cast<const short8*>(&Ps[wave][fr * 72 + fq * 8]);
        short8 pa1 = *reinterpret_cast<const short8*>(&Ps[wave][fr * 72 + 32 + fq * 8]);
        #pragma unroll
        for (int nd = 0; nd < 4; ++nd) {
            const short8 vb0 = *reinterpret_cast<const short8*>(
                &Vt[(nd * 16 + fr) * 72 + fq * 8]);
            const short8 vb1 = *reinterpret_cast<const short8*>(
                &Vt[(nd * 16 + fr) * 72 + 32 + fq * 8]);
            acc[nd] = __builtin_amdgcn_mfma_f32_16x16x32_bf16(pa0, vb0, acc[nd], 0, 0, 0);
            acc[nd] = __builtin_amdgcn_mfma_f32_16x16x32_bf16(pa1, vb1, acc[nd], 0, 0, 0);
        }
    }

    // epilogue: normalize rows (q = fq*4+j) and store
    float iq[4];
    #pragma unroll
    for (int j = 0; j < 4; ++j) iq[j] = 1.f / __shfl(l_run, fq * 4 + j, 64);
    #pragma unroll
    for (int j = 0; j < 4; ++j) {
        const size_t orow = (qrow0 + wave * 16 + fq * 4 + j) * os + hc;
        #pragma unroll
        for (int nd = 0; nd < 4; ++nd) {
            const float v = acc[nd][j] * iq[j];
            if (OB) ((u16*)Ov)[orow + nd * 16 + fr] = f2b(v);
            else    ((float*)Ov)[orow + nd * 16 + fr] = v;
        }
    }
}

// -------------------- gate mix (dot, softmax-2, blend) ---------------------
__global__ __launch_bounds__(256)
void mix_kernel(const float* __restrict__ gctx, const float* __restrict__ mixw,
                const float* __restrict__ mixb, const float* __restrict__ so,
                const float* __restrict__ co, u16* __restrict__ mixed)
{
    const size_t row = blockIdx.x;
    const float* g = gctx + row * 512;
    float d0 = 0.f, d1 = 0.f;
    for (int c = threadIdx.x; c < 512; c += 256) {
        const float gv = g[c];
        d0 = fmaf(gv, mixw[c], d0);
        d1 = fmaf(gv, mixw[512 + c], d1);
    }
    #pragma unroll
    for (int off = 32; off > 0; off >>= 1) {
        d0 += __shfl_down(d0, off);
        d1 += __shfl_down(d1, off);
    }
    __shared__ float sA[4], sB[4];
    const int wid = threadIdx.x >> 6;
    if ((threadIdx.x & 63) == 0) { sA[wid] = d0; sB[wid] = d1; }
    __syncthreads();
    const float t0 = sA[0] + sA[1] + sA[2] + sA[3] + mixb[0];
    const float t1 = sB[0] + sB[1] + sB[2] + sB[3] + mixb[1];
    const float mx = fmaxf(t0, t1);
    const float e0 = __expf(t0 - mx), e1 = __expf(t1 - mx);
    const float inv = 1.f / (e0 + e1);
    const float w0 = e0 * inv, w1 = e1 * inv;
    for (int c = threadIdx.x; c < 512; c += 256)
        mixed[row * 512 + c] = f2b(w0 * so[row * 512 + c] + w1 * co[row * 512 + c]);
}

// ---------------------------------------------------------------------------
extern "C" void kernel_launch(void* const* d_in, const int* in_sizes, int n_in,
                              void* d_out, int out_size, void* d_ws, size_t ws_size,
                              hipStream_t stream)
{
    const float* query     = (const float*)d_in[0];
    const float* kvwt      = (const float*)d_in[1];
    const float* nq_w      = (const float*)d_in[2];
    const float* nq_b      = (const float*)d_in[3];
    const float* nkv_w     = (const float*)d_in[4];
    const float* nkv_b     = (const float*)d_in[5];
    const float* wq_cross  = (const float*)d_in[6];
    const float* wkv_cross = (const float*)d_in[7];
    const float* wqkv_self = (const float*)d_in[8];
    const float* gn_w      = (const float*)d_in[9];
    const float* gn_b      = (const float*)d_in[10];
    const float* mha_in_w  = (const float*)d_in[11];
    const float* mha_out_w = (const float*)d_in[12];
    const float* mix_w     = (const float*)d_in[13];
    const float* mix_b     = (const float*)d_in[14];
    const float* w_out     = (const float*)d_in[15];
    const float* ff_ln_w   = (const float*)d_in[16];
    const float* ff_ln_b   = (const float*)d_in[17];
    const float* ff_fc1    = (const float*)d_in[18];
    const float* ff_fc2    = (const float*)d_in[19];
    const float* ff_gate   = (const float*)d_in[20];

    float* delta_out = (float*)d_out;                          // stack[0]
    float* wt_out    = (float*)d_out + (size_t)M_ROWS * 1024;  // stack[1]

    // ---- workspace layout (byte offsets; total 59,768,832 B = 57 MB) ----
    char* wsb = (char*)d_ws;
    u16*   qkv_b   = (u16*)  (wsb + 0);          // bf16 [2048,1536]
    u16*   kv_c_b  = (u16*)  (wsb + 6291456);    // bf16 [2048,1024]
    u16*   q_c_b   = (u16*)  (wsb + 10485760);   // bf16 [2048,512]
    float* cross_f = (float*)(wsb + 12582912);   // f32  [2048,512]
    float* self_f  = (float*)(wsb + 16777216);   // f32  [2048,512]
    u16*   kvn_b   = (u16*)  (wsb + 20971520);   // bf16 [2048,1024]
    u16*   qn_b    = (u16*)  (wsb + 25165824);   // bf16 [2048,1024]
    u16*   wta_b   = (u16*)  (wsb + 29360128);   // bf16 [2048,512]
    u16*   con_b   = (u16*)  (wsb + 31457280);   // bf16 [2048,512]
    // aliases (liveness audited):
    u16*   gq_b    = qkv_b;
    u16*   gk_b    = qkv_b + 1048576;
    u16*   gv_b    = qkv_b + 2097152;
    float* gctx_f  = (float*)kv_c_b;
    u16*   gattn_b = kvn_b;
    u16*   mixed_b = kvn_b + 1048576;
    u16*   lnd_b   = qn_b;
    u16*   son_b   = wta_b;
    u16*   ffh_b   = qkv_b;
    // bf16 weights:
    u16* wqkv_self_b = (u16*)(wsb + 33554432);
    u16* wq_cross_b  = (u16*)(wsb + 36700160);
    u16* wkv_cross_b = (u16*)(wsb + 37748736);
    u16* mha_in_b    = (u16*)(wsb + 39845888);
    u16* mha_out_b   = (u16*)(wsb + 41418752);
    u16* w_out_b     = (u16*)(wsb + 41943040);
    u16* ff_fc1_b    = (u16*)(wsb + 42991616);
    u16* ff_fc2_b    = (u16*)(wsb + 51380224);

    const dim3 blk(256);
    const dim3 attn_grid(SEQ / 64, 16);
    auto cvt = [&](const float* src, u16* dst, int n) {
        f2b_kernel<<<dim3(n / 1024), blk, 0, stream>>>(src, dst, n);
    };
    auto gemm_grid = [](int N) { return dim3(N / 128, M_ROWS / 128); };

    // 0. weight conversions
    cvt(wqkv_self, wqkv_self_b, 1536 * 1024);
    cvt(wq_cross,  wq_cross_b,   512 * 1024);
    cvt(wkv_cross, wkv_cross_b, 1024 * 1024);
    cvt(mha_in_w,  mha_in_b,    1536 * 512);
    cvt(mha_out_w, mha_out_b,    512 * 512);
    cvt(w_out,     w_out_b,     1024 * 512);
    cvt(ff_fc1,    ff_fc1_b,    4096 * 1024);
    cvt(ff_fc2,    ff_fc2_b,    1024 * 4096);

    // 1. kvn = LN(kv_feats_wt)
    ln_bf16<<<M_ROWS, blk, 0, stream>>>(kvwt, nkv_w, nkv_b, kvn_b, 1024);
    // 2. qkv_wt = kvn @ wqkv_self^T
    gemm_mfma<0,1><<<gemm_grid(1536), blk, 0, stream>>>(kvn_b, wqkv_self_b, qkv_b, 1536, 1024, nullptr);
    // 3. wt_attn (bf16 out)
    attn_mfma<1><<<attn_grid, blk, 0, stream>>>(qkv_b, qkv_b + 512, qkv_b + 1024, wta_b, 1536, 1536, 1536, 512);
    // 4. wt_out = wt_attn @ w_out^T -> output stack[1]
    gemm_mfma<0,0><<<gemm_grid(1024), blk, 0, stream>>>(wta_b, w_out_b, wt_out, 1024, 512, nullptr);
    // 5. qn = LN(query_feats)
    ln_bf16<<<M_ROWS, blk, 0, stream>>>(query, nq_w, nq_b, qn_b, 1024);
    // 6. q_c = qn @ wq_cross^T
    gemm_mfma<0,1><<<gemm_grid(512), blk, 0, stream>>>(qn_b, wq_cross_b, q_c_b, 512, 1024, nullptr);
    // 7. kv_c = kvn @ wkv_cross^T
    gemm_mfma<0,1><<<gemm_grid(1024), blk, 0, stream>>>(kvn_b, wkv_cross_b, kv_c_b, 1024, 1024, nullptr);
    // 8. cross_out (f32 out)
    attn_mfma<0><<<attn_grid, blk, 0, stream>>>(q_c_b, kv_c_b, kv_c_b + 512, cross_f, 512, 1024, 1024, 512);
    // 9. qkv_s = qn @ wqkv_self^T
    gemm_mfma<0,1><<<gemm_grid(1536), blk, 0, stream>>>(qn_b, wqkv_self_b, qkv_b, 1536, 1024, nullptr);
    // 10. self_out (f32 out)
    attn_mfma<0><<<attn_grid, blk, 0, stream>>>(qkv_b, qkv_b + 512, qkv_b + 1024, self_f, 1536, 1536, 1536, 512);
    // 11. son = LN(self_out; gn), con = LN(cross_out; gn)
    ln_bf16<<<M_ROWS, blk, 0, stream>>>(self_f,  gn_w, gn_b, son_b, 512);
    ln_bf16<<<M_ROWS, blk, 0, stream>>>(cross_f, gn_w, gn_b, con_b, 512);
    // 12. gq/gk/gv
    gemm_mfma<0,1><<<gemm_grid(512), blk, 0, stream>>>(son_b, mha_in_b,            gq_b, 512, 512, nullptr);
    gemm_mfma<0,1><<<gemm_grid(512), blk, 0, stream>>>(con_b, mha_in_b + 512*512,  gk_b, 512, 512, nullptr);
    gemm_mfma<0,1><<<gemm_grid(512), blk, 0, stream>>>(con_b, mha_in_b + 1024*512, gv_b, 512, 512, nullptr);
    // 13. gate attention (bf16 out)
    attn_mfma<1><<<attn_grid, blk, 0, stream>>>(gq_b, gk_b, gv_b, gattn_b, 512, 512, 512, 512);
    // 14. gate_ctx = gate_attn @ mha_out_w^T (f32 out)
    gemm_mfma<0,0><<<gemm_grid(512), blk, 0, stream>>>(gattn_b, mha_out_b, gctx_f, 512, 512, nullptr);
    // 15. mixed = softmax-gate blend (bf16 out)
    mix_kernel<<<M_ROWS, blk, 0, stream>>>(gctx_f, mix_w, mix_b, self_f, cross_f, mixed_b);
    // 16. delta = mixed @ w_out^T -> output stack[0] (f32)
    gemm_mfma<0,0><<<gemm_grid(1024), blk, 0, stream>>>(mixed_b, w_out_b, delta_out, 1024, 512, nullptr);
    // 17. ln_delta = LN(delta; ff_ln)
    ln_bf16<<<M_ROWS, blk, 0, stream>>>(delta_out, ff_ln_w, ff_ln_b, lnd_b, 1024);
    // 18. ffh = gelu(ln_delta @ ff_fc1^T) (bf16 out, GELU epilogue)
    gemm_mfma<1,1><<<gemm_grid(4096), blk, 0, stream>>>(lnd_b, ff_fc1_b, ffh_b, 4096, 1024, nullptr);
    // 19. delta += ff_gate * (ffh @ ff_fc2^T) (f32 RMW epilogue)
    gemm_mfma<2,0><<<gemm_grid(1024), blk, 0, stream>>>(ffh_b, ff_fc2_b, delta_out, 1024, 4096, ff_gate);
}

// Round 4
// 398.260 us; speedup vs baseline: 3.7783x; 1.2107x over previous
//
#include <hip/hip_runtime.h>
#include <math.h>

// ---------------------------------------------------------------------------
// GatedCrossAttention: B=2, NQ=NK=1024, QD=KVD=OD=1024, H=8, DH=64, INNER=512
// Round 4: GEMM latency fix — 2-phase double-buffered global_load_lds pipeline
// + per-shape tiles (64x64 / 64x128 / 128x128) so every grid >= 256 blocks.
// Attention unchanged (bf16 MFMA swapped-QK^T from round 3).
// ---------------------------------------------------------------------------

#define M_ROWS 2048   // B*NQ
#define SEQ    1024

typedef unsigned short u16;
typedef __attribute__((ext_vector_type(8))) short short8;
typedef __attribute__((ext_vector_type(4))) float f32x4;

__device__ inline u16 f2b(float f) {
    unsigned u = __builtin_bit_cast(unsigned, f);
    u += 0x7FFFu + ((u >> 16) & 1u);   // round-to-nearest-even
    return (u16)(u >> 16);
}
__device__ inline float b2f(u16 h) {
    return __builtin_bit_cast(float, (unsigned)h << 16);
}

__device__ inline void gload16(const u16* g, u16* l) {
    __builtin_amdgcn_global_load_lds(
        (const __attribute__((address_space(1))) void*)g,
        (__attribute__((address_space(3))) void*)l, 16, 0, 0);
}

// ------------------------- f32 -> bf16 convert -----------------------------
__global__ __launch_bounds__(256)
void f2b_kernel(const float* __restrict__ in, u16* __restrict__ out, int n)
{
    const int i = (blockIdx.x * 256 + threadIdx.x) * 4;
    if (i < n) {
        const float4 v = *reinterpret_cast<const float4*>(&in[i]);
        ushort4 o;
        o.x = f2b(v.x); o.y = f2b(v.y); o.z = f2b(v.z); o.w = f2b(v.w);
        *reinterpret_cast<ushort4*>(&out[i]) = o;
    }
}

// ----------------------------- LayerNorm -----------------------------------
__global__ __launch_bounds__(256)
void ln_bf16(const float* __restrict__ x, const float* __restrict__ w,
             const float* __restrict__ bias, u16* __restrict__ out, int D)
{
    const size_t row = blockIdx.x;
    const float* xr = x + row * (size_t)D;
    const int c = threadIdx.x * 4;
    float4 v = make_float4(0.f, 0.f, 0.f, 0.f);
    if (c < D) v = *reinterpret_cast<const float4*>(&xr[c]);
    float sum = v.x + v.y + v.z + v.w;
    float sq  = v.x*v.x + v.y*v.y + v.z*v.z + v.w*v.w;
    #pragma unroll
    for (int off = 32; off > 0; off >>= 1) {
        sum += __shfl_down(sum, off);
        sq  += __shfl_down(sq,  off);
    }
    __shared__ float s1[4], s2[4];
    const int wid = threadIdx.x >> 6;
    if ((threadIdx.x & 63) == 0) { s1[wid] = sum; s2[wid] = sq; }
    __syncthreads();
    const float tsum = s1[0] + s1[1] + s1[2] + s1[3];
    const float tsq  = s2[0] + s2[1] + s2[2] + s2[3];
    const float mean = tsum / (float)D;
    const float var  = tsq / (float)D - mean * mean;
    const float rstd = rsqrtf(var + 1e-5f);
    if (c < D) {
        ushort4 o;
        o.x = f2b((v.x - mean) * rstd * w[c+0] + bias[c+0]);
        o.y = f2b((v.y - mean) * rstd * w[c+1] + bias[c+1]);
        o.z = f2b((v.z - mean) * rstd * w[c+2] + bias[c+2]);
        o.w = f2b((v.w - mean) * rstd * w[c+3] + bias[c+3]);
        *reinterpret_cast<ushort4*>(&out[row * (size_t)D + c]) = o;
    }
}

// ------------------------------ MFMA GEMM ----------------------------------
// C[M,N] = A[M,K]*W[N,K]^T, bf16 in, f32 acc. Templated tile BM x BN (64/128),
// BK=32, 4 waves (2x2). 2-phase double-buffered global_load_lds pipeline:
// issue next tile's loads BEFORE computing the current tile so HBM/L2 latency
// hides under ds_read+MFMA (grids here are small -> latency-bound otherwise).
// EPI: 0=none, 1=exact GELU, 2=C += gate*acc (f32 RMW). OB: bf16 output.
template<int BM, int BN, int EPI, int OB>
__global__ __launch_bounds__(256)
void gemm_mfma(const u16* __restrict__ A, const u16* __restrict__ W,
               void* __restrict__ Cv, int N, int K, const float* __restrict__ gatep)
{
    constexpr int MF = BM / 32;   // 16x16 frags per wave (M)
    constexpr int NF = BN / 32;   // 16x16 frags per wave (N)
    __shared__ __align__(16) u16 As[2][BM * 32];
    __shared__ __align__(16) u16 Ws[2][BN * 32];
    const int tid  = threadIdx.x;
    const int lane = tid & 63;
    const int wave = tid >> 6;
    const int wr = wave >> 1, wc = wave & 1;
    const int m0 = blockIdx.y * BM, n0 = blockIdx.x * BN;

    // staging: thread tid covers 8 elems at row tid>>2, col (tid&3)*8
    const int srow = tid >> 2;
    const int scol = (tid & 3) * 8;
    const u16* Ag = A + (size_t)(m0 + srow) * K + scol;
    const u16* Wg = W + (size_t)(n0 + srow) * K + scol;

    const int fr = lane & 15;
    const int fq = lane >> 4;

    f32x4 acc[MF][NF] = {};

    auto stage = [&](int buf, int k0) {
        #pragma unroll
        for (int i = 0; i < BM / 64; ++i)
            gload16(Ag + k0 + (size_t)(i * 64) * K, &As[buf][tid * 8 + i * 2048]);
        #pragma unroll
        for (int i = 0; i < BN / 64; ++i)
            gload16(Wg + k0 + (size_t)(i * 64) * K, &Ws[buf][tid * 8 + i * 2048]);
    };
    auto compute = [&](int buf) {
        short8 a[MF], b[NF];
        #pragma unroll
        for (int m = 0; m < MF; ++m)
            a[m] = *reinterpret_cast<const short8*>(
                &As[buf][(wr * (BM / 2) + m * 16 + fr) * 32 + fq * 8]);
        #pragma unroll
        for (int n = 0; n < NF; ++n)
            b[n] = *reinterpret_cast<const short8*>(
                &Ws[buf][(wc * (BN / 2) + n * 16 + fr) * 32 + fq * 8]);
        #pragma unroll
        for (int m = 0; m < MF; ++m)
            #pragma unroll
            for (int n = 0; n < NF; ++n)
                acc[m][n] = __builtin_amdgcn_mfma_f32_16x16x32_bf16(
                    a[m], b[n], acc[m][n], 0, 0, 0);
    };

    // 2-phase pipeline
    stage(0, 0);
    __syncthreads();                    // vmcnt(0): tile 0 resident
    int cur = 0;
    for (int k0 = 32; k0 < K; k0 += 32) {
        stage(cur ^ 1, k0);             // prefetch next tile (in flight)
        compute(cur);                   // MFMA on current tile
        __syncthreads();                // drain prefetch + LDS reads
        cur ^= 1;
    }
    compute(cur);                       // last tile

    // C/D layout: col = lane&15, row = (lane>>4)*4 + reg  [m89/m91 verified]
    const float gate = (EPI == 2) ? gatep[0] : 0.f;
    #pragma unroll
    for (int m = 0; m < MF; ++m) {
        #pragma unroll
        for (int j = 0; j < 4; ++j) {
            const size_t row = (size_t)(m0 + wr * (BM / 2) + m * 16 + fq * 4 + j);
            #pragma unroll
            for (int n = 0; n < NF; ++n) {
                float v = acc[m][n][j];
                const size_t idx = row * (size_t)N + (size_t)(n0 + wc * (BN / 2) + n * 16 + fr);
                if (EPI == 1) v = 0.5f * v * (1.f + erff(v * 0.70710678118654752f));
                if (OB) {
                    ((u16*)Cv)[idx] = f2b(v);
                } else {
                    float* C = (float*)Cv;
                    if (EPI == 2) C[idx] = C[idx] + gate * v;
                    else          C[idx] = v;
                }
            }
        }
    }
}

// ------------------------- MFMA fused attention ----------------------------
// grid = (NQ/64, B*H), 256 threads = 4 waves x 16 q-rows. bf16 QKV.
// Swapped QK^T: ST = mfma(K_rows, Q_rows) -> lane owns q-col (lane&15),
// softmax = in-lane 16-max + 2 shfl_xor. P packed bf16 into wave-private LDS
// (no barrier), re-read as PV A-frag. V staged transposed Vt[d][kv].
template<int OB>
__global__ __launch_bounds__(256)
void attn_mfma(const u16* __restrict__ Q, const u16* __restrict__ K,
               const u16* __restrict__ V, void* __restrict__ Ov,
               int qs, int ks, int vs, int os)
{
    __shared__ __align__(16) u16 Ks[64 * 72];      // [kv][d], pad 72
    __shared__ __align__(16) u16 Vt[64 * 72];      // [d][kv], pad 72
    __shared__ __align__(16) u16 Ps[4][16 * 72];   // per-wave P [q][kv]
    const int tid  = threadIdx.x;
    const int lane = tid & 63;
    const int wave = tid >> 6;
    const int fr = lane & 15;
    const int fq = lane >> 4;
    const int b  = blockIdx.y >> 3;
    const int hc = (blockIdx.y & 7) * 64;
    const size_t qrow0 = (size_t)b * SEQ + (size_t)blockIdx.x * 64;
    const size_t krow0 = (size_t)b * SEQ;

    short8 qf[2];
    {
        const u16* qp = Q + (qrow0 + wave * 16 + fr) * qs + hc + fq * 8;
        qf[0] = *reinterpret_cast<const short8*>(qp);
        qf[1] = *reinterpret_cast<const short8*>(qp + 32);
    }

    const int skr = tid >> 2;
    const int skc = (tid & 3) * 16;
    const int svk = (tid >> 4) * 4;
    const int svd = (tid & 15) * 4;

    float m_run = -1e30f, l_run = 0.f;
    f32x4 acc[4] = {};

    for (int kt = 0; kt < SEQ / 64; ++kt) {
        __syncthreads();
        {   // stage K [kv][d]
            const u16* kp = K + (krow0 + kt * 64 + skr) * ks + hc + skc;
            *reinterpret_cast<short8*>(&Ks[skr * 72 + skc]) =
                *reinterpret_cast<const short8*>(kp);
            *reinterpret_cast<short8*>(&Ks[skr * 72 + skc + 8]) =
                *reinterpret_cast<const short8*>(kp + 8);
        }
        {   // stage V transposed: Vt[d][kv]
            const u16* vp = V + (krow0 + kt * 64 + svk) * vs + hc + svd;
            const ushort4 l0 = *reinterpret_cast<const ushort4*>(vp);
            const ushort4 l1 = *reinterpret_cast<const ushort4*>(vp + vs);
            const ushort4 l2 = *reinterpret_cast<const ushort4*>(vp + 2 * (size_t)vs);
            const ushort4 l3 = *reinterpret_cast<const ushort4*>(vp + 3 * (size_t)vs);
            uint2 w;
            w.x = (unsigned)l0.x | ((unsigned)l1.x << 16);
            w.y = (unsigned)l2.x | ((unsigned)l3.x << 16);
            *reinterpret_cast<uint2*>(&Vt[(svd + 0) * 72 + svk]) = w;
            w.x = (unsigned)l0.y | ((unsigned)l1.y << 16);
            w.y = (unsigned)l2.y | ((unsigned)l3.y << 16);
            *reinterpret_cast<uint2*>(&Vt[(svd + 1) * 72 + svk]) = w;
            w.x = (unsigned)l0.z | ((unsigned)l1.z << 16);
            w.y = (unsigned)l2.z | ((unsigned)l3.z << 16);
            *reinterpret_cast<uint2*>(&Vt[(svd + 2) * 72 + svk]) = w;
            w.x = (unsigned)l0.w | ((unsigned)l1.w << 16);
            w.y = (unsigned)l2.w | ((unsigned)l3.w << 16);
            *reinterpret_cast<uint2*>(&Vt[(svd + 3) * 72 + svk]) = w;
        }
        __syncthreads();

        f32x4 st[4] = {};
        #pragma unroll
        for (int kn = 0; kn < 4; ++kn) {
            const short8 ka0 = *reinterpret_cast<const short8*>(
                &Ks[(kn * 16 + fr) * 72 + fq * 8]);
            const short8 ka1 = *reinterpret_cast<const short8*>(
                &Ks[(kn * 16 + fr) * 72 + 32 + fq * 8]);
            st[kn] = __builtin_amdgcn_mfma_f32_16x16x32_bf16(ka0, qf[0], st[kn], 0, 0, 0);
            st[kn] = __builtin_amdgcn_mfma_f32_16x16x32_bf16(ka1, qf[1], st[kn], 0, 0, 0);
        }

        float mx = -1e30f;
        #pragma unroll
        for (int kn = 0; kn < 4; ++kn)
            #pragma unroll
            for (int r = 0; r < 4; ++r) {
                st[kn][r] *= 0.125f;
                mx = fmaxf(mx, st[kn][r]);
            }
        mx = fmaxf(mx, __shfl_xor(mx, 16, 64));
        mx = fmaxf(mx, __shfl_xor(mx, 32, 64));
        const float mnew = fmaxf(m_run, mx);
        const float corr = __expf(m_run - mnew);
        m_run = mnew;
        float psum = 0.f;
        #pragma unroll
        for (int kn = 0; kn < 4; ++kn) {
            const float p0 = __expf(st[kn][0] - mnew);
            const float p1 = __expf(st[kn][1] - mnew);
            const float p2 = __expf(st[kn][2] - mnew);
            const float p3 = __expf(st[kn][3] - mnew);
            psum += (p0 + p1) + (p2 + p3);
            uint2 w;
            w.x = (unsigned)f2b(p0) | ((unsigned)f2b(p1) << 16);
            w.y = (unsigned)f2b(p2) | ((unsigned)f2b(p3) << 16);
            *reinterpret_cast<uint2*>(&Ps[wave][fr * 72 + kn * 16 + fq * 4]) = w;
        }
        psum += __shfl_xor(psum, 16, 64);
        psum += __shfl_xor(psum, 32, 64);
        l_run = l_run * corr + psum;

        float cq[4];
        #pragma unroll
        for (int j = 0; j < 4; ++j) cq[j] = __shfl(corr, fq * 4 + j, 64);
        #pragma unroll
        for (int nd = 0; nd < 4; ++nd)
            #pragma unroll
            for (int j = 0; j < 4; ++j)
                acc[nd][j] *= cq[j];

        short8 pa0 = *reinterpret_cast<const short8*>(&Ps[wave][fr * 72 + fq * 8]);
        short8 pa1 = *reinterpret_cast<const short8*>(&Ps[wave][fr * 72 + 32 + fq * 8]);
        #pragma unroll
        for (int nd = 0; nd < 4; ++nd) {
            const short8 vb0 = *reinterpret_cast<const short8*>(
                &Vt[(nd * 16 + fr) * 72 + fq * 8]);
            const short8 vb1 = *reinterpret_cast<const short8*>(
                &Vt[(nd * 16 + fr) * 72 + 32 + fq * 8]);
            acc[nd] = __builtin_amdgcn_mfma_f32_16x16x32_bf16(pa0, vb0, acc[nd], 0, 0, 0);
            acc[nd] = __builtin_amdgcn_mfma_f32_16x16x32_bf16(pa1, vb1, acc[nd], 0, 0, 0);
        }
    }

    float iq[4];
    #pragma unroll
    for (int j = 0; j < 4; ++j) iq[j] = 1.f / __shfl(l_run, fq * 4 + j, 64);
    #pragma unroll
    for (int j = 0; j < 4; ++j) {
        const size_t orow = (qrow0 + wave * 16 + fq * 4 + j) * os + hc;
        #pragma unroll
        for (int nd = 0; nd < 4; ++nd) {
            const float v = acc[nd][j] * iq[j];
            if (OB) ((u16*)Ov)[orow + nd * 16 + fr] = f2b(v);
            else    ((float*)Ov)[orow + nd * 16 + fr] = v;
        }
    }
}

// -------------------- gate mix (dot, softmax-2, blend) ---------------------
__global__ __launch_bounds__(256)
void mix_kernel(const float* __restrict__ gctx, const float* __restrict__ mixw,
                const float* __restrict__ mixb, const float* __restrict__ so,
                const float* __restrict__ co, u16* __restrict__ mixed)
{
    const size_t row = blockIdx.x;
    const float* g = gctx + row * 512;
    float d0 = 0.f, d1 = 0.f;
    for (int c = threadIdx.x; c < 512; c += 256) {
        const float gv = g[c];
        d0 = fmaf(gv, mixw[c], d0);
        d1 = fmaf(gv, mixw[512 + c], d1);
    }
    #pragma unroll
    for (int off = 32; off > 0; off >>= 1) {
        d0 += __shfl_down(d0, off);
        d1 += __shfl_down(d1, off);
    }
    __shared__ float sA[4], sB[4];
    const int wid = threadIdx.x >> 6;
    if ((threadIdx.x & 63) == 0) { sA[wid] = d0; sB[wid] = d1; }
    __syncthreads();
    const float t0 = sA[0] + sA[1] + sA[2] + sA[3] + mixb[0];
    const float t1 = sB[0] + sB[1] + sB[2] + sB[3] + mixb[1];
    const float mx = fmaxf(t0, t1);
    const float e0 = __expf(t0 - mx), e1 = __expf(t1 - mx);
    const float inv = 1.f / (e0 + e1);
    const float w0 = e0 * inv, w1 = e1 * inv;
    for (int c = threadIdx.x; c < 512; c += 256)
        mixed[row * 512 + c] = f2b(w0 * so[row * 512 + c] + w1 * co[row * 512 + c]);
}

// ---------------------------------------------------------------------------
extern "C" void kernel_launch(void* const* d_in, const int* in_sizes, int n_in,
                              void* d_out, int out_size, void* d_ws, size_t ws_size,
                              hipStream_t stream)
{
    const float* query     = (const float*)d_in[0];
    const float* kvwt      = (const float*)d_in[1];
    const float* nq_w      = (const float*)d_in[2];
    const float* nq_b      = (const float*)d_in[3];
    const float* nkv_w     = (const float*)d_in[4];
    const float* nkv_b     = (const float*)d_in[5];
    const float* wq_cross  = (const float*)d_in[6];
    const float* wkv_cross = (const float*)d_in[7];
    const float* wqkv_self = (const float*)d_in[8];
    const float* gn_w      = (const float*)d_in[9];
    const float* gn_b      = (const float*)d_in[10];
    const float* mha_in_w  = (const float*)d_in[11];
    const float* mha_out_w = (const float*)d_in[12];
    const float* mix_w     = (const float*)d_in[13];
    const float* mix_b     = (const float*)d_in[14];
    const float* w_out     = (const float*)d_in[15];
    const float* ff_ln_w   = (const float*)d_in[16];
    const float* ff_ln_b   = (const float*)d_in[17];
    const float* ff_fc1    = (const float*)d_in[18];
    const float* ff_fc2    = (const float*)d_in[19];
    const float* ff_gate   = (const float*)d_in[20];

    float* delta_out = (float*)d_out;                          // stack[0]
    float* wt_out    = (float*)d_out + (size_t)M_ROWS * 1024;  // stack[1]

    // ---- workspace layout (byte offsets; total 59,768,832 B = 57 MB) ----
    char* wsb = (char*)d_ws;
    u16*   qkv_b   = (u16*)  (wsb + 0);          // bf16 [2048,1536]
    u16*   kv_c_b  = (u16*)  (wsb + 6291456);    // bf16 [2048,1024]
    u16*   q_c_b   = (u16*)  (wsb + 10485760);   // bf16 [2048,512]
    float* cross_f = (float*)(wsb + 12582912);   // f32  [2048,512]
    float* self_f  = (float*)(wsb + 16777216);   // f32  [2048,512]
    u16*   kvn_b   = (u16*)  (wsb + 20971520);   // bf16 [2048,1024]
    u16*   qn_b    = (u16*)  (wsb + 25165824);   // bf16 [2048,1024]
    u16*   wta_b   = (u16*)  (wsb + 29360128);   // bf16 [2048,512]
    u16*   con_b   = (u16*)  (wsb + 31457280);   // bf16 [2048,512]
    // aliases (liveness audited):
    u16*   gq_b    = qkv_b;
    u16*   gk_b    = qkv_b + 1048576;
    u16*   gv_b    = qkv_b + 2097152;
    float* gctx_f  = (float*)kv_c_b;
    u16*   gattn_b = kvn_b;
    u16*   mixed_b = kvn_b + 1048576;
    u16*   lnd_b   = qn_b;
    u16*   son_b   = wta_b;
    u16*   ffh_b   = qkv_b;
    // bf16 weights:
    u16* wqkv_self_b = (u16*)(wsb + 33554432);
    u16* wq_cross_b  = (u16*)(wsb + 36700160);
    u16* wkv_cross_b = (u16*)(wsb + 37748736);
    u16* mha_in_b    = (u16*)(wsb + 39845888);
    u16* mha_out_b   = (u16*)(wsb + 41418752);
    u16* w_out_b     = (u16*)(wsb + 41943040);
    u16* ff_fc1_b    = (u16*)(wsb + 42991616);
    u16* ff_fc2_b    = (u16*)(wsb + 51380224);

    const dim3 blk(256);
    const dim3 attn_grid(SEQ / 64, 16);
    auto cvt = [&](const float* src, u16* dst, int n) {
        f2b_kernel<<<dim3(n / 1024), blk, 0, stream>>>(src, dst, n);
    };

    // 0. weight conversions
    cvt(wqkv_self, wqkv_self_b, 1536 * 1024);
    cvt(wq_cross,  wq_cross_b,   512 * 1024);
    cvt(wkv_cross, wkv_cross_b, 1024 * 1024);
    cvt(mha_in_w,  mha_in_b,    1536 * 512);
    cvt(mha_out_w, mha_out_b,    512 * 512);
    cvt(w_out,     w_out_b,     1024 * 512);
    cvt(ff_fc1,    ff_fc1_b,    4096 * 1024);
    cvt(ff_fc2,    ff_fc2_b,    1024 * 4096);

    // 1. kvn = LN(kv_feats_wt)
    ln_bf16<<<M_ROWS, blk, 0, stream>>>(kvwt, nkv_w, nkv_b, kvn_b, 1024);
    // 2. qkv_wt = kvn @ wqkv_self^T               [2048x1536 K=1024] grid 384
    gemm_mfma<64,128,0,1><<<dim3(12, 32), blk, 0, stream>>>(kvn_b, wqkv_self_b, qkv_b, 1536, 1024, nullptr);
    // 3. wt_attn (bf16 out)
    attn_mfma<1><<<attn_grid, blk, 0, stream>>>(qkv_b, qkv_b + 512, qkv_b + 1024, wta_b, 1536, 1536, 1536, 512);
    // 4. wt_out = wt_attn @ w_out^T -> stack[1]   [2048x1024 K=512] grid 256
    gemm_mfma<64,128,0,0><<<dim3(8, 32), blk, 0, stream>>>(wta_b, w_out_b, wt_out, 1024, 512, nullptr);
    // 5. qn = LN(query_feats)
    ln_bf16<<<M_ROWS, blk, 0, stream>>>(query, nq_w, nq_b, qn_b, 1024);
    // 6. q_c = qn @ wq_cross^T                    [2048x512 K=1024] grid 256
    gemm_mfma<64,64,0,1><<<dim3(8, 32), blk, 0, stream>>>(qn_b, wq_cross_b, q_c_b, 512, 1024, nullptr);
    // 7. kv_c = kvn @ wkv_cross^T                 [2048x1024 K=1024] grid 256
    gemm_mfma<64,128,0,1><<<dim3(8, 32), blk, 0, stream>>>(kvn_b, wkv_cross_b, kv_c_b, 1024, 1024, nullptr);
    // 8. cross_out (f32 out)
    attn_mfma<0><<<attn_grid, blk, 0, stream>>>(q_c_b, kv_c_b, kv_c_b + 512, cross_f, 512, 1024, 1024, 512);
    // 9. qkv_s = qn @ wqkv_self^T                 grid 384
    gemm_mfma<64,128,0,1><<<dim3(12, 32), blk, 0, stream>>>(qn_b, wqkv_self_b, qkv_b, 1536, 1024, nullptr);
    // 10. self_out (f32 out)
    attn_mfma<0><<<attn_grid, blk, 0, stream>>>(qkv_b, qkv_b + 512, qkv_b + 1024, self_f, 1536, 1536, 1536, 512);
    // 11. son = LN(self_out; gn), con = LN(cross_out; gn)
    ln_bf16<<<M_ROWS, blk, 0, stream>>>(self_f,  gn_w, gn_b, son_b, 512);
    ln_bf16<<<M_ROWS, blk, 0, stream>>>(cross_f, gn_w, gn_b, con_b, 512);
    // 12. gq/gk/gv                                [2048x512 K=512] grid 256
    gemm_mfma<64,64,0,1><<<dim3(8, 32), blk, 0, stream>>>(son_b, mha_in_b,            gq_b, 512, 512, nullptr);
    gemm_mfma<64,64,0,1><<<dim3(8, 32), blk, 0, stream>>>(con_b, mha_in_b + 512*512,  gk_b, 512, 512, nullptr);
    gemm_mfma<64,64,0,1><<<dim3(8, 32), blk, 0, stream>>>(con_b, mha_in_b + 1024*512, gv_b, 512, 512, nullptr);
    // 13. gate attention (bf16 out)
    attn_mfma<1><<<attn_grid, blk, 0, stream>>>(gq_b, gk_b, gv_b, gattn_b, 512, 512, 512, 512);
    // 14. gate_ctx = gate_attn @ mha_out_w^T (f32 out)  grid 256
    gemm_mfma<64,64,0,0><<<dim3(8, 32), blk, 0, stream>>>(gattn_b, mha_out_b, gctx_f, 512, 512, nullptr);
    // 15. mixed = softmax-gate blend (bf16 out)
    mix_kernel<<<M_ROWS, blk, 0, stream>>>(gctx_f, mix_w, mix_b, self_f, cross_f, mixed_b);
    // 16. delta = mixed @ w_out^T -> stack[0] (f32)     grid 256
    gemm_mfma<64,128,0,0><<<dim3(8, 32), blk, 0, stream>>>(mixed_b, w_out_b, delta_out, 1024, 512, nullptr);
    // 17. ln_delta = LN(delta; ff_ln)
    ln_bf16<<<M_ROWS, blk, 0, stream>>>(delta_out, ff_ln_w, ff_ln_b, lnd_b, 1024);
    // 18. ffh = gelu(ln_delta @ ff_fc1^T)         [2048x4096 K=1024] grid 512
    gemm_mfma<128,128,1,1><<<dim3(32, 16), blk, 0, stream>>>(lnd_b, ff_fc1_b, ffh_b, 4096, 1024, nullptr);
    // 19. delta += ff_gate * (ffh @ ff_fc2^T)     [2048x1024 K=4096] grid 256
    gemm_mfma<64,128,2,0><<<dim3(8, 32), blk, 0, stream>>>(ffh_b, ff_fc2_b, delta_out, 1024, 4096, ff_gate);
}

// Round 5
// 395.579 us; speedup vs baseline: 3.8040x; 1.0068x over previous
//
#include <hip/hip_runtime.h>
#include <math.h>

// ---------------------------------------------------------------------------
// GatedCrossAttention: B=2, NQ=NK=1024, QD=KVD=OD=1024, H=8, DH=64, INNER=512
// Round 5: GEMM pipeline rework — 3-deep LDS ring with counted vmcnt (never
// drain to 0 in main loop, T4), XOR chunk-swizzle (linear gload dest +
// swizzled source + swizzled ds_read, rule #21) to kill 8-way bank conflicts.
// Attention unchanged (bf16 MFMA swapped-QK^T).
// ---------------------------------------------------------------------------

#define M_ROWS 2048   // B*NQ
#define SEQ    1024

typedef unsigned short u16;
typedef __attribute__((ext_vector_type(8))) short short8;
typedef __attribute__((ext_vector_type(4))) float f32x4;

__device__ inline u16 f2b(float f) {
    unsigned u = __builtin_bit_cast(unsigned, f);
    u += 0x7FFFu + ((u >> 16) & 1u);   // round-to-nearest-even
    return (u16)(u >> 16);
}
__device__ inline float b2f(u16 h) {
    return __builtin_bit_cast(float, (unsigned)h << 16);
}

__device__ inline void gload16(const u16* g, u16* l) {
    __builtin_amdgcn_global_load_lds(
        (const __attribute__((address_space(1))) void*)g,
        (__attribute__((address_space(3))) void*)l, 16, 0, 0);
}

// ------------------------- f32 -> bf16 convert -----------------------------
__global__ __launch_bounds__(256)
void f2b_kernel(const float* __restrict__ in, u16* __restrict__ out, int n)
{
    const int i = (blockIdx.x * 256 + threadIdx.x) * 4;
    if (i < n) {
        const float4 v = *reinterpret_cast<const float4*>(&in[i]);
        ushort4 o;
        o.x = f2b(v.x); o.y = f2b(v.y); o.z = f2b(v.z); o.w = f2b(v.w);
        *reinterpret_cast<ushort4*>(&out[i]) = o;
    }
}

// ----------------------------- LayerNorm -----------------------------------
__global__ __launch_bounds__(256)
void ln_bf16(const float* __restrict__ x, const float* __restrict__ w,
             const float* __restrict__ bias, u16* __restrict__ out, int D)
{
    const size_t row = blockIdx.x;
    const float* xr = x + row * (size_t)D;
    const int c = threadIdx.x * 4;
    float4 v = make_float4(0.f, 0.f, 0.f, 0.f);
    if (c < D) v = *reinterpret_cast<const float4*>(&xr[c]);
    float sum = v.x + v.y + v.z + v.w;
    float sq  = v.x*v.x + v.y*v.y + v.z*v.z + v.w*v.w;
    #pragma unroll
    for (int off = 32; off > 0; off >>= 1) {
        sum += __shfl_down(sum, off);
        sq  += __shfl_down(sq,  off);
    }
    __shared__ float s1[4], s2[4];
    const int wid = threadIdx.x >> 6;
    if ((threadIdx.x & 63) == 0) { s1[wid] = sum; s2[wid] = sq; }
    __syncthreads();
    const float tsum = s1[0] + s1[1] + s1[2] + s1[3];
    const float tsq  = s2[0] + s2[1] + s2[2] + s2[3];
    const float mean = tsum / (float)D;
    const float var  = tsq / (float)D - mean * mean;
    const float rstd = rsqrtf(var + 1e-5f);
    if (c < D) {
        ushort4 o;
        o.x = f2b((v.x - mean) * rstd * w[c+0] + bias[c+0]);
        o.y = f2b((v.y - mean) * rstd * w[c+1] + bias[c+1]);
        o.z = f2b((v.z - mean) * rstd * w[c+2] + bias[c+2]);
        o.w = f2b((v.w - mean) * rstd * w[c+3] + bias[c+3]);
        *reinterpret_cast<ushort4*>(&out[row * (size_t)D + c]) = o;
    }
}

// ------------------------------ MFMA GEMM ----------------------------------
// C[M,N] = A[M,K]*W[N,K]^T, bf16 in, f32 acc. Tile BM x BN, BK=32, 4 waves.
// 3-deep LDS ring; counted vmcnt: per K-step one fused
//   s_waitcnt vmcnt(LPT); s_barrier
// keeps the next tile's loads in flight across the barrier (AITER pattern,
// never vmcnt(0) in the loop). Stage(t+2) issued BEFORE compute(t).
// LDS chunk swizzle: chunk ^= (row>>1)&3 applied to the GLOBAL source (gload
// dest stays linear) and to the ds_read address -> 8-way conflict becomes
// free 2-way. EPI: 0=none, 1=exact GELU, 2=C += gate*acc. OB: bf16 output.
template<int BM, int BN, int EPI, int OB>
__global__ __launch_bounds__(256)
void gemm_mfma(const u16* __restrict__ A, const u16* __restrict__ W,
               void* __restrict__ Cv, int N, int K, const float* __restrict__ gatep)
{
    constexpr int MF  = BM / 32;            // 16x16 frags per wave (M)
    constexpr int NF  = BN / 32;            // 16x16 frags per wave (N)
    constexpr int LPT = BM / 64 + BN / 64;  // gload insts per tile per wave
    __shared__ __align__(16) u16 As[3][BM * 32];
    __shared__ __align__(16) u16 Ws[3][BN * 32];
    const int tid  = threadIdx.x;
    const int lane = tid & 63;
    const int wave = tid >> 6;
    const int wr = wave >> 1, wc = wave & 1;
    const int m0 = blockIdx.y * BM, n0 = blockIdx.x * BN;

    // staging: thread tid -> LDS row tid>>2 (linear dest), global chunk
    // pre-swizzled so LDS[row][c] holds global[row][c ^ ((row>>1)&3)].
    const int srow = tid >> 2;
    const int scol = (((tid & 3) ^ ((srow >> 1) & 3))) * 8;
    const u16* Ag = A + (size_t)(m0 + srow) * K + scol;
    const u16* Wg = W + (size_t)(n0 + srow) * K + scol;

    const int fr = lane & 15;
    const int fq = lane >> 4;

    f32x4 acc[MF][NF] = {};

    auto stage = [&](int buf, int k0) {
        #pragma unroll
        for (int i = 0; i < BM / 64; ++i)
            gload16(Ag + k0 + (size_t)(i * 64) * K, &As[buf][tid * 8 + i * 2048]);
        #pragma unroll
        for (int i = 0; i < BN / 64; ++i)
            gload16(Wg + k0 + (size_t)(i * 64) * K, &Ws[buf][tid * 8 + i * 2048]);
    };
    auto compute = [&](int buf) {
        short8 a[MF], b[NF];
        #pragma unroll
        for (int m = 0; m < MF; ++m) {
            const int r = wr * (BM / 2) + m * 16 + fr;
            a[m] = *reinterpret_cast<const short8*>(
                &As[buf][r * 32 + ((fq ^ ((r >> 1) & 3)) << 3)]);
        }
        #pragma unroll
        for (int n = 0; n < NF; ++n) {
            const int r = wc * (BN / 2) + n * 16 + fr;
            b[n] = *reinterpret_cast<const short8*>(
                &Ws[buf][r * 32 + ((fq ^ ((r >> 1) & 3)) << 3)]);
        }
        #pragma unroll
        for (int m = 0; m < MF; ++m)
            #pragma unroll
            for (int n = 0; n < NF; ++n)
                acc[m][n] = __builtin_amdgcn_mfma_f32_16x16x32_bf16(
                    a[m], b[n], acc[m][n], 0, 0, 0);
    };

    const int nt = K / 32;                  // >= 16 for all shapes here
    stage(0, 0);
    stage(1, 32);
    for (int t = 0; t < nt - 1; ++t) {
        // tile t fully resident once <= LPT (newest tile's) loads outstanding
        asm volatile("s_waitcnt vmcnt(%0)\n\ts_barrier" :: "n"(LPT) : "memory");
        if (t + 2 < nt) stage((t + 2) % 3, (t + 2) * 32);
        compute(t % 3);
    }
    asm volatile("s_waitcnt vmcnt(0)\n\ts_barrier" ::: "memory");
    compute((nt - 1) % 3);

    // C/D layout: col = lane&15, row = (lane>>4)*4 + reg  [m89/m91 verified]
    const float gate = (EPI == 2) ? gatep[0] : 0.f;
    #pragma unroll
    for (int m = 0; m < MF; ++m) {
        #pragma unroll
        for (int j = 0; j < 4; ++j) {
            const size_t row = (size_t)(m0 + wr * (BM / 2) + m * 16 + fq * 4 + j);
            #pragma unroll
            for (int n = 0; n < NF; ++n) {
                float v = acc[m][n][j];
                const size_t idx = row * (size_t)N + (size_t)(n0 + wc * (BN / 2) + n * 16 + fr);
                if (EPI == 1) v = 0.5f * v * (1.f + erff(v * 0.70710678118654752f));
                if (OB) {
                    ((u16*)Cv)[idx] = f2b(v);
                } else {
                    float* C = (float*)Cv;
                    if (EPI == 2) C[idx] = C[idx] + gate * v;
                    else          C[idx] = v;
                }
            }
        }
    }
}

// ------------------------- MFMA fused attention ----------------------------
// grid = (NQ/64, B*H), 256 threads = 4 waves x 16 q-rows. bf16 QKV.
template<int OB>
__global__ __launch_bounds__(256)
void attn_mfma(const u16* __restrict__ Q, const u16* __restrict__ K,
               const u16* __restrict__ V, void* __restrict__ Ov,
               int qs, int ks, int vs, int os)
{
    __shared__ __align__(16) u16 Ks[64 * 72];      // [kv][d], pad 72
    __shared__ __align__(16) u16 Vt[64 * 72];      // [d][kv], pad 72
    __shared__ __align__(16) u16 Ps[4][16 * 72];   // per-wave P [q][kv]
    const int tid  = threadIdx.x;
    const int lane = tid & 63;
    const int wave = tid >> 6;
    const int fr = lane & 15;
    const int fq = lane >> 4;
    const int b  = blockIdx.y >> 3;
    const int hc = (blockIdx.y & 7) * 64;
    const size_t qrow0 = (size_t)b * SEQ + (size_t)blockIdx.x * 64;
    const size_t krow0 = (size_t)b * SEQ;

    short8 qf[2];
    {
        const u16* qp = Q + (qrow0 + wave * 16 + fr) * qs + hc + fq * 8;
        qf[0] = *reinterpret_cast<const short8*>(qp);
        qf[1] = *reinterpret_cast<const short8*>(qp + 32);
    }

    const int skr = tid >> 2;
    const int skc = (tid & 3) * 16;
    const int svk = (tid >> 4) * 4;
    const int svd = (tid & 15) * 4;

    float m_run = -1e30f, l_run = 0.f;
    f32x4 acc[4] = {};

    for (int kt = 0; kt < SEQ / 64; ++kt) {
        __syncthreads();
        {   // stage K [kv][d]
            const u16* kp = K + (krow0 + kt * 64 + skr) * ks + hc + skc;
            *reinterpret_cast<short8*>(&Ks[skr * 72 + skc]) =
                *reinterpret_cast<const short8*>(kp);
            *reinterpret_cast<short8*>(&Ks[skr * 72 + skc + 8]) =
                *reinterpret_cast<const short8*>(kp + 8);
        }
        {   // stage V transposed: Vt[d][kv]
            const u16* vp = V + (krow0 + kt * 64 + svk) * vs + hc + svd;
            const ushort4 l0 = *reinterpret_cast<const ushort4*>(vp);
            const ushort4 l1 = *reinterpret_cast<const ushort4*>(vp + vs);
            const ushort4 l2 = *reinterpret_cast<const ushort4*>(vp + 2 * (size_t)vs);
            const ushort4 l3 = *reinterpret_cast<const ushort4*>(vp + 3 * (size_t)vs);
            uint2 w;
            w.x = (unsigned)l0.x | ((unsigned)l1.x << 16);
            w.y = (unsigned)l2.x | ((unsigned)l3.x << 16);
            *reinterpret_cast<uint2*>(&Vt[(svd + 0) * 72 + svk]) = w;
            w.x = (unsigned)l0.y | ((unsigned)l1.y << 16);
            w.y = (unsigned)l2.y | ((unsigned)l3.y << 16);
            *reinterpret_cast<uint2*>(&Vt[(svd + 1) * 72 + svk]) = w;
            w.x = (unsigned)l0.z | ((unsigned)l1.z << 16);
            w.y = (unsigned)l2.z | ((unsigned)l3.z << 16);
            *reinterpret_cast<uint2*>(&Vt[(svd + 2) * 72 + svk]) = w;
            w.x = (unsigned)l0.w | ((unsigned)l1.w << 16);
            w.y = (unsigned)l2.w | ((unsigned)l3.w << 16);
            *reinterpret_cast<uint2*>(&Vt[(svd + 3) * 72 + svk]) = w;
        }
        __syncthreads();

        f32x4 st[4] = {};
        #pragma unroll
        for (int kn = 0; kn < 4; ++kn) {
            const short8 ka0 = *reinterpret_cast<const short8*>(
                &Ks[(kn * 16 + fr) * 72 + fq * 8]);
            const short8 ka1 = *reinterpret_cast<const short8*>(
                &Ks[(kn * 16 + fr) * 72 + 32 + fq * 8]);
            st[kn] = __builtin_amdgcn_mfma_f32_16x16x32_bf16(ka0, qf[0], st[kn], 0, 0, 0);
            st[kn] = __builtin_amdgcn_mfma_f32_16x16x32_bf16(ka1, qf[1], st[kn], 0, 0, 0);
        }

        float mx = -1e30f;
        #pragma unroll
        for (int kn = 0; kn < 4; ++kn)
            #pragma unroll
            for (int r = 0; r < 4; ++r) {
                st[kn][r] *= 0.125f;
                mx = fmaxf(mx, st[kn][r]);
            }
        mx = fmaxf(mx, __shfl_xor(mx, 16, 64));
        mx = fmaxf(mx, __shfl_xor(mx, 32, 64));
        const float mnew = fmaxf(m_run, mx);
        const float corr = __expf(m_run - mnew);
        m_run = mnew;
        float psum = 0.f;
        #pragma unroll
        for (int kn = 0; kn < 4; ++kn) {
            const float p0 = __expf(st[kn][0] - mnew);
            const float p1 = __expf(st[kn][1] - mnew);
            const float p2 = __expf(st[kn][2] - mnew);
            const float p3 = __expf(st[kn][3] - mnew);
            psum += (p0 + p1) + (p2 + p3);
            uint2 w;
            w.x = (unsigned)f2b(p0) | ((unsigned)f2b(p1) << 16);
            w.y = (unsigned)f2b(p2) | ((unsigned)f2b(p3) << 16);
            *reinterpret_cast<uint2*>(&Ps[wave][fr * 72 + kn * 16 + fq * 4]) = w;
        }
        psum += __shfl_xor(psum, 16, 64);
        psum += __shfl_xor(psum, 32, 64);
        l_run = l_run * corr + psum;

        float cq[4];
        #pragma unroll
        for (int j = 0; j < 4; ++j) cq[j] = __shfl(corr, fq * 4 + j, 64);
        #pragma unroll
        for (int nd = 0; nd < 4; ++nd)
            #pragma unroll
            for (int j = 0; j < 4; ++j)
                acc[nd][j] *= cq[j];

        short8 pa0 = *reinterpret_cast<const short8*>(&Ps[wave][fr * 72 + fq * 8]);
        short8 pa1 = *reinterpret_cast<const short8*>(&Ps[wave][fr * 72 + 32 + fq * 8]);
        #pragma unroll
        for (int nd = 0; nd < 4; ++nd) {
            const short8 vb0 = *reinterpret_cast<const short8*>(
                &Vt[(nd * 16 + fr) * 72 + fq * 8]);
            const short8 vb1 = *reinterpret_cast<const short8*>(
                &Vt[(nd * 16 + fr) * 72 + 32 + fq * 8]);
            acc[nd] = __builtin_amdgcn_mfma_f32_16x16x32_bf16(pa0, vb0, acc[nd], 0, 0, 0);
            acc[nd] = __builtin_amdgcn_mfma_f32_16x16x32_bf16(pa1, vb1, acc[nd], 0, 0, 0);
        }
    }

    float iq[4];
    #pragma unroll
    for (int j = 0; j < 4; ++j) iq[j] = 1.f / __shfl(l_run, fq * 4 + j, 64);
    #pragma unroll
    for (int j = 0; j < 4; ++j) {
        const size_t orow = (qrow0 + wave * 16 + fq * 4 + j) * os + hc;
        #pragma unroll
        for (int nd = 0; nd < 4; ++nd) {
            const float v = acc[nd][j] * iq[j];
            if (OB) ((u16*)Ov)[orow + nd * 16 + fr] = f2b(v);
            else    ((float*)Ov)[orow + nd * 16 + fr] = v;
        }
    }
}

// -------------------- gate mix (dot, softmax-2, blend) ---------------------
__global__ __launch_bounds__(256)
void mix_kernel(const float* __restrict__ gctx, const float* __restrict__ mixw,
                const float* __restrict__ mixb, const float* __restrict__ so,
                const float* __restrict__ co, u16* __restrict__ mixed)
{
    const size_t row = blockIdx.x;
    const float* g = gctx + row * 512;
    float d0 = 0.f, d1 = 0.f;
    for (int c = threadIdx.x; c < 512; c += 256) {
        const float gv = g[c];
        d0 = fmaf(gv, mixw[c], d0);
        d1 = fmaf(gv, mixw[512 + c], d1);
    }
    #pragma unroll
    for (int off = 32; off > 0; off >>= 1) {
        d0 += __shfl_down(d0, off);
        d1 += __shfl_down(d1, off);
    }
    __shared__ float sA[4], sB[4];
    const int wid = threadIdx.x >> 6;
    if ((threadIdx.x & 63) == 0) { sA[wid] = d0; sB[wid] = d1; }
    __syncthreads();
    const float t0 = sA[0] + sA[1] + sA[2] + sA[3] + mixb[0];
    const float t1 = sB[0] + sB[1] + sB[2] + sB[3] + mixb[1];
    const float mx = fmaxf(t0, t1);
    const float e0 = __expf(t0 - mx), e1 = __expf(t1 - mx);
    const float inv = 1.f / (e0 + e1);
    const float w0 = e0 * inv, w1 = e1 * inv;
    for (int c = threadIdx.x; c < 512; c += 256)
        mixed[row * 512 + c] = f2b(w0 * so[row * 512 + c] + w1 * co[row * 512 + c]);
}

// ---------------------------------------------------------------------------
extern "C" void kernel_launch(void* const* d_in, const int* in_sizes, int n_in,
                              void* d_out, int out_size, void* d_ws, size_t ws_size,
                              hipStream_t stream)
{
    const float* query     = (const float*)d_in[0];
    const float* kvwt      = (const float*)d_in[1];
    const float* nq_w      = (const float*)d_in[2];
    const float* nq_b      = (const float*)d_in[3];
    const float* nkv_w     = (const float*)d_in[4];
    const float* nkv_b     = (const float*)d_in[5];
    const float* wq_cross  = (const float*)d_in[6];
    const float* wkv_cross = (const float*)d_in[7];
    const float* wqkv_self = (const float*)d_in[8];
    const float* gn_w      = (const float*)d_in[9];
    const float* gn_b      = (const float*)d_in[10];
    const float* mha_in_w  = (const float*)d_in[11];
    const float* mha_out_w = (const float*)d_in[12];
    const float* mix_w     = (const float*)d_in[13];
    const float* mix_b     = (const float*)d_in[14];
    const float* w_out     = (const float*)d_in[15];
    const float* ff_ln_w   = (const float*)d_in[16];
    const float* ff_ln_b   = (const float*)d_in[17];
    const float* ff_fc1    = (const float*)d_in[18];
    const float* ff_fc2    = (const float*)d_in[19];
    const float* ff_gate   = (const float*)d_in[20];

    float* delta_out = (float*)d_out;                          // stack[0]
    float* wt_out    = (float*)d_out + (size_t)M_ROWS * 1024;  // stack[1]

    // ---- workspace layout (byte offsets; total 59,768,832 B = 57 MB) ----
    char* wsb = (char*)d_ws;
    u16*   qkv_b   = (u16*)  (wsb + 0);          // bf16 [2048,1536]
    u16*   kv_c_b  = (u16*)  (wsb + 6291456);    // bf16 [2048,1024]
    u16*   q_c_b   = (u16*)  (wsb + 10485760);   // bf16 [2048,512]
    float* cross_f = (float*)(wsb + 12582912);   // f32  [2048,512]
    float* self_f  = (float*)(wsb + 16777216);   // f32  [2048,512]
    u16*   kvn_b   = (u16*)  (wsb + 20971520);   // bf16 [2048,1024]
    u16*   qn_b    = (u16*)  (wsb + 25165824);   // bf16 [2048,1024]
    u16*   wta_b   = (u16*)  (wsb + 29360128);   // bf16 [2048,512]
    u16*   con_b   = (u16*)  (wsb + 31457280);   // bf16 [2048,512]
    // aliases (liveness audited):
    u16*   gq_b    = qkv_b;
    u16*   gk_b    = qkv_b + 1048576;
    u16*   gv_b    = qkv_b + 2097152;
    float* gctx_f  = (float*)kv_c_b;
    u16*   gattn_b = kvn_b;
    u16*   mixed_b = kvn_b + 1048576;
    u16*   lnd_b   = qn_b;
    u16*   son_b   = wta_b;
    u16*   ffh_b   = qkv_b;
    // bf16 weights:
    u16* wqkv_self_b = (u16*)(wsb + 33554432);
    u16* wq_cross_b  = (u16*)(wsb + 36700160);
    u16* wkv_cross_b = (u16*)(wsb + 37748736);
    u16* mha_in_b    = (u16*)(wsb + 39845888);
    u16* mha_out_b   = (u16*)(wsb + 41418752);
    u16* w_out_b     = (u16*)(wsb + 41943040);
    u16* ff_fc1_b    = (u16*)(wsb + 42991616);
    u16* ff_fc2_b    = (u16*)(wsb + 51380224);

    const dim3 blk(256);
    const dim3 attn_grid(SEQ / 64, 16);
    auto cvt = [&](const float* src, u16* dst, int n) {
        f2b_kernel<<<dim3(n / 1024), blk, 0, stream>>>(src, dst, n);
    };

    // 0. weight conversions
    cvt(wqkv_self, wqkv_self_b, 1536 * 1024);
    cvt(wq_cross,  wq_cross_b,   512 * 1024);
    cvt(wkv_cross, wkv_cross_b, 1024 * 1024);
    cvt(mha_in_w,  mha_in_b,    1536 * 512);
    cvt(mha_out_w, mha_out_b,    512 * 512);
    cvt(w_out,     w_out_b,     1024 * 512);
    cvt(ff_fc1,    ff_fc1_b,    4096 * 1024);
    cvt(ff_fc2,    ff_fc2_b,    1024 * 4096);

    // 1. kvn = LN(kv_feats_wt)
    ln_bf16<<<M_ROWS, blk, 0, stream>>>(kvwt, nkv_w, nkv_b, kvn_b, 1024);
    // 2. qkv_wt = kvn @ wqkv_self^T               [2048x1536 K=1024] grid 384
    gemm_mfma<64,128,0,1><<<dim3(12, 32), blk, 0, stream>>>(kvn_b, wqkv_self_b, qkv_b, 1536, 1024, nullptr);
    // 3. wt_attn (bf16 out)
    attn_mfma<1><<<attn_grid, blk, 0, stream>>>(qkv_b, qkv_b + 512, qkv_b + 1024, wta_b, 1536, 1536, 1536, 512);
    // 4. wt_out = wt_attn @ w_out^T -> stack[1]   [2048x1024 K=512] grid 256
    gemm_mfma<64,128,0,0><<<dim3(8, 32), blk, 0, stream>>>(wta_b, w_out_b, wt_out, 1024, 512, nullptr);
    // 5. qn = LN(query_feats)
    ln_bf16<<<M_ROWS, blk, 0, stream>>>(query, nq_w, nq_b, qn_b, 1024);
    // 6. q_c = qn @ wq_cross^T                    [2048x512 K=1024] grid 256
    gemm_mfma<64,64,0,1><<<dim3(8, 32), blk, 0, stream>>>(qn_b, wq_cross_b, q_c_b, 512, 1024, nullptr);
    // 7. kv_c = kvn @ wkv_cross^T                 [2048x1024 K=1024] grid 256
    gemm_mfma<64,128,0,1><<<dim3(8, 32), blk, 0, stream>>>(kvn_b, wkv_cross_b, kv_c_b, 1024, 1024, nullptr);
    // 8. cross_out (f32 out)
    attn_mfma<0><<<attn_grid, blk, 0, stream>>>(q_c_b, kv_c_b, kv_c_b + 512, cross_f, 512, 1024, 1024, 512);
    // 9. qkv_s = qn @ wqkv_self^T                 grid 384
    gemm_mfma<64,128,0,1><<<dim3(12, 32), blk, 0, stream>>>(qn_b, wqkv_self_b, qkv_b, 1536, 1024, nullptr);
    // 10. self_out (f32 out)
    attn_mfma<0><<<attn_grid, blk, 0, stream>>>(qkv_b, qkv_b + 512, qkv_b + 1024, self_f, 1536, 1536, 1536, 512);
    // 11. son = LN(self_out; gn), con = LN(cross_out; gn)
    ln_bf16<<<M_ROWS, blk, 0, stream>>>(self_f,  gn_w, gn_b, son_b, 512);
    ln_bf16<<<M_ROWS, blk, 0, stream>>>(cross_f, gn_w, gn_b, con_b, 512);
    // 12. gq/gk/gv                                [2048x512 K=512] grid 256
    gemm_mfma<64,64,0,1><<<dim3(8, 32), blk, 0, stream>>>(son_b, mha_in_b,            gq_b, 512, 512, nullptr);
    gemm_mfma<64,64,0,1><<<dim3(8, 32), blk, 0, stream>>>(con_b, mha_in_b + 512*512,  gk_b, 512, 512, nullptr);
    gemm_mfma<64,64,0,1><<<dim3(8, 32), blk, 0, stream>>>(con_b, mha_in_b + 1024*512, gv_b, 512, 512, nullptr);
    // 13. gate attention (bf16 out)
    attn_mfma<1><<<attn_grid, blk, 0, stream>>>(gq_b, gk_b, gv_b, gattn_b, 512, 512, 512, 512);
    // 14. gate_ctx = gate_attn @ mha_out_w^T (f32 out)  grid 256
    gemm_mfma<64,64,0,0><<<dim3(8, 32), blk, 0, stream>>>(gattn_b, mha_out_b, gctx_f, 512, 512, nullptr);
    // 15. mixed = softmax-gate blend (bf16 out)
    mix_kernel<<<M_ROWS, blk, 0, stream>>>(gctx_f, mix_w, mix_b, self_f, cross_f, mixed_b);
    // 16. delta = mixed @ w_out^T -> stack[0] (f32)     grid 256
    gemm_mfma<64,128,0,0><<<dim3(8, 32), blk, 0, stream>>>(mixed_b, w_out_b, delta_out, 1024, 512, nullptr);
    // 17. ln_delta = LN(delta; ff_ln)
    ln_bf16<<<M_ROWS, blk, 0, stream>>>(delta_out, ff_ln_w, ff_ln_b, lnd_b, 1024);
    // 18. ffh = gelu(ln_delta @ ff_fc1^T)         [2048x4096 K=1024] grid 1024
    gemm_mfma<64,128,1,1><<<dim3(32, 32), blk, 0, stream>>>(lnd_b, ff_fc1_b, ffh_b, 4096, 1024, nullptr);
    // 19. delta += ff_gate * (ffh @ ff_fc2^T)     [2048x1024 K=4096] grid 256
    gemm_mfma<64,128,2,0><<<dim3(8, 32), blk, 0, stream>>>(ffh_b, ff_fc2_b, delta_out, 1024, 4096, ff_gate);
}

// Round 6
// 391.657 us; speedup vs baseline: 3.8420x; 1.0100x over previous
//
#include <hip/hip_runtime.h>
#include <math.h>

// ---------------------------------------------------------------------------
// GatedCrossAttention: B=2, NQ=NK=1024, QD=KVD=OD=1024, H=8, DH=64, INNER=512
// Round 6: deep GEMM pipeline — 5 tiles in flight (ring-6 LDS), counted vmcnt
// never 0 in steady state, compile-time tail drain; XCD column-chunk swizzle
// for per-XCD W-slice L2 residency. Attention unchanged.
// ---------------------------------------------------------------------------

#define M_ROWS 2048   // B*NQ
#define SEQ    1024

typedef unsigned short u16;
typedef __attribute__((ext_vector_type(8))) short short8;
typedef __attribute__((ext_vector_type(4))) float f32x4;

__device__ inline u16 f2b(float f) {
    unsigned u = __builtin_bit_cast(unsigned, f);
    u += 0x7FFFu + ((u >> 16) & 1u);   // round-to-nearest-even
    return (u16)(u >> 16);
}
__device__ inline float b2f(u16 h) {
    return __builtin_bit_cast(float, (unsigned)h << 16);
}

__device__ inline void gload16(const u16* g, u16* l) {
    __builtin_amdgcn_global_load_lds(
        (const __attribute__((address_space(1))) void*)g,
        (__attribute__((address_space(3))) void*)l, 16, 0, 0);
}

// ------------------------- f32 -> bf16 convert -----------------------------
__global__ __launch_bounds__(256)
void f2b_kernel(const float* __restrict__ in, u16* __restrict__ out, int n)
{
    const int i = (blockIdx.x * 256 + threadIdx.x) * 4;
    if (i < n) {
        const float4 v = *reinterpret_cast<const float4*>(&in[i]);
        ushort4 o;
        o.x = f2b(v.x); o.y = f2b(v.y); o.z = f2b(v.z); o.w = f2b(v.w);
        *reinterpret_cast<ushort4*>(&out[i]) = o;
    }
}

// ----------------------------- LayerNorm -----------------------------------
__global__ __launch_bounds__(256)
void ln_bf16(const float* __restrict__ x, const float* __restrict__ w,
             const float* __restrict__ bias, u16* __restrict__ out, int D)
{
    const size_t row = blockIdx.x;
    const float* xr = x + row * (size_t)D;
    const int c = threadIdx.x * 4;
    float4 v = make_float4(0.f, 0.f, 0.f, 0.f);
    if (c < D) v = *reinterpret_cast<const float4*>(&xr[c]);
    float sum = v.x + v.y + v.z + v.w;
    float sq  = v.x*v.x + v.y*v.y + v.z*v.z + v.w*v.w;
    #pragma unroll
    for (int off = 32; off > 0; off >>= 1) {
        sum += __shfl_down(sum, off);
        sq  += __shfl_down(sq,  off);
    }
    __shared__ float s1[4], s2[4];
    const int wid = threadIdx.x >> 6;
    if ((threadIdx.x & 63) == 0) { s1[wid] = sum; s2[wid] = sq; }
    __syncthreads();
    const float tsum = s1[0] + s1[1] + s1[2] + s1[3];
    const float tsq  = s2[0] + s2[1] + s2[2] + s2[3];
    const float mean = tsum / (float)D;
    const float var  = tsq / (float)D - mean * mean;
    const float rstd = rsqrtf(var + 1e-5f);
    if (c < D) {
        ushort4 o;
        o.x = f2b((v.x - mean) * rstd * w[c+0] + bias[c+0]);
        o.y = f2b((v.y - mean) * rstd * w[c+1] + bias[c+1]);
        o.z = f2b((v.z - mean) * rstd * w[c+2] + bias[c+2]);
        o.w = f2b((v.w - mean) * rstd * w[c+3] + bias[c+3]);
        *reinterpret_cast<ushort4*>(&out[row * (size_t)D + c]) = o;
    }
}

// ------------------------------ MFMA GEMM ----------------------------------
// C[M,N] = A[M,K]*W[N,K]^T, bf16 in, f32 acc. Tile BM x BN, BK=32, 4 waves.
// PF=5 tiles in flight through a ring-6 LDS buffer; per K-step one fused
//   s_waitcnt vmcnt((PF-1)*LPT); s_barrier
// (never 0 in steady state). Tail drains with compile-time decreasing waits.
// LDS chunk swizzle: linear gload dest + swizzled global source + swizzled
// ds_read (rule #21) -> bank-conflict-free (verified: 2.1e6 -> 0).
// XCD column-chunk swizzle: each XCD owns contiguous grid COLUMNS so its
// W-slice stays L2-resident. EPI: 0=none, 1=GELU, 2=C += gate*acc. OB: bf16.
template<int BM, int BN, int EPI, int OB>
__global__ __launch_bounds__(256)
void gemm_mfma(const u16* __restrict__ A, const u16* __restrict__ W,
               void* __restrict__ Cv, int N, int K, const float* __restrict__ gatep)
{
    constexpr int MF  = BM / 32;            // 16x16 frags per wave (M)
    constexpr int NF  = BN / 32;            // 16x16 frags per wave (N)
    constexpr int LPT = BM / 64 + BN / 64;  // gload insts per tile per thread
    constexpr int PF  = 5;                  // tiles in flight
    constexpr int R   = PF + 1;             // LDS ring depth
    __shared__ __align__(16) u16 As[R][BM * 32];
    __shared__ __align__(16) u16 Ws[R][BN * 32];
    const int tid  = threadIdx.x;
    const int lane = tid & 63;
    const int wave = tid >> 6;
    const int wr = wave >> 1, wc = wave & 1;

    // XCD-aware column-chunk swizzle (all grids here are multiples of 8).
    const int nwg = gridDim.x * gridDim.y;
    const int bid = blockIdx.y * gridDim.x + blockIdx.x;   // dispatch order
    const int nid = (bid & 7) * (nwg >> 3) + (bid >> 3);   // chunk per XCD
    const int by  = nid % gridDim.y;                       // column-major:
    const int bx  = nid / gridDim.y;                       // chunk = bx cols
    const int m0 = by * BM, n0 = bx * BN;

    // staging: thread tid -> LDS row tid>>2 (linear dest), global chunk
    // pre-swizzled so LDS[row][c] holds global[row][c ^ ((row>>1)&3)].
    const int srow = tid >> 2;
    const int scol = (((tid & 3) ^ ((srow >> 1) & 3))) * 8;
    const u16* Ag = A + (size_t)(m0 + srow) * K + scol;
    const u16* Wg = W + (size_t)(n0 + srow) * K + scol;

    const int fr = lane & 15;
    const int fq = lane >> 4;

    f32x4 acc[MF][NF] = {};

    auto stage = [&](int buf, int k0) {
        #pragma unroll
        for (int i = 0; i < BM / 64; ++i)
            gload16(Ag + k0 + (size_t)(i * 64) * K, &As[buf][tid * 8 + i * 2048]);
        #pragma unroll
        for (int i = 0; i < BN / 64; ++i)
            gload16(Wg + k0 + (size_t)(i * 64) * K, &Ws[buf][tid * 8 + i * 2048]);
    };
    auto compute = [&](int buf) {
        short8 a[MF], b[NF];
        #pragma unroll
        for (int m = 0; m < MF; ++m) {
            const int r = wr * (BM / 2) + m * 16 + fr;
            a[m] = *reinterpret_cast<const short8*>(
                &As[buf][r * 32 + ((fq ^ ((r >> 1) & 3)) << 3)]);
        }
        #pragma unroll
        for (int n = 0; n < NF; ++n) {
            const int r = wc * (BN / 2) + n * 16 + fr;
            b[n] = *reinterpret_cast<const short8*>(
                &Ws[buf][r * 32 + ((fq ^ ((r >> 1) & 3)) << 3)]);
        }
        #pragma unroll
        for (int m = 0; m < MF; ++m)
            #pragma unroll
            for (int n = 0; n < NF; ++n)
                acc[m][n] = __builtin_amdgcn_mfma_f32_16x16x32_bf16(
                    a[m], b[n], acc[m][n], 0, 0, 0);
    };

    const int nt = K / 32;                  // >= 16 for all shapes here
    #pragma unroll
    for (int i = 0; i < PF; ++i) stage(i, i * 32);

    int cbuf = 0, sbuf = PF;
    for (int t = 0; t <= nt - PF; ++t) {
        // tile t resident once <= (PF-1)*LPT newest loads outstanding
        asm volatile("s_waitcnt vmcnt(%0)\n\ts_barrier"
                     :: "n"((PF - 1) * LPT) : "memory");
        if (t + PF < nt) {
            stage(sbuf, (t + PF) * 32);
            if (++sbuf == R) sbuf = 0;
        }
        compute(cbuf);
        if (++cbuf == R) cbuf = 0;
    }
    #pragma unroll
    for (int i = 1; i < PF; ++i) {          // drain tail, compile-time waits
        asm volatile("s_waitcnt vmcnt(%0)\n\ts_barrier"
                     :: "n"((PF - 1 - i) * LPT) : "memory");
        compute(cbuf);
        if (++cbuf == R) cbuf = 0;
    }

    // C/D layout: col = lane&15, row = (lane>>4)*4 + reg  [m89/m91 verified]
    const float gate = (EPI == 2) ? gatep[0] : 0.f;
    #pragma unroll
    for (int m = 0; m < MF; ++m) {
        #pragma unroll
        for (int j = 0; j < 4; ++j) {
            const size_t row = (size_t)(m0 + wr * (BM / 2) + m * 16 + fq * 4 + j);
            #pragma unroll
            for (int n = 0; n < NF; ++n) {
                float v = acc[m][n][j];
                const size_t idx = row * (size_t)N + (size_t)(n0 + wc * (BN / 2) + n * 16 + fr);
                if (EPI == 1) v = 0.5f * v * (1.f + erff(v * 0.70710678118654752f));
                if (OB) {
                    ((u16*)Cv)[idx] = f2b(v);
                } else {
                    float* C = (float*)Cv;
                    if (EPI == 2) C[idx] = C[idx] + gate * v;
                    else          C[idx] = v;
                }
            }
        }
    }
}

// ------------------------- MFMA fused attention ----------------------------
// grid = (NQ/64, B*H), 256 threads = 4 waves x 16 q-rows. bf16 QKV.
template<int OB>
__global__ __launch_bounds__(256)
void attn_mfma(const u16* __restrict__ Q, const u16* __restrict__ K,
               const u16* __restrict__ V, void* __restrict__ Ov,
               int qs, int ks, int vs, int os)
{
    __shared__ __align__(16) u16 Ks[64 * 72];      // [kv][d], pad 72
    __shared__ __align__(16) u16 Vt[64 * 72];      // [d][kv], pad 72
    __shared__ __align__(16) u16 Ps[4][16 * 72];   // per-wave P [q][kv]
    const int tid  = threadIdx.x;
    const int lane = tid & 63;
    const int wave = tid >> 6;
    const int fr = lane & 15;
    const int fq = lane >> 4;
    const int b  = blockIdx.y >> 3;
    const int hc = (blockIdx.y & 7) * 64;
    const size_t qrow0 = (size_t)b * SEQ + (size_t)blockIdx.x * 64;
    const size_t krow0 = (size_t)b * SEQ;

    short8 qf[2];
    {
        const u16* qp = Q + (qrow0 + wave * 16 + fr) * qs + hc + fq * 8;
        qf[0] = *reinterpret_cast<const short8*>(qp);
        qf[1] = *reinterpret_cast<const short8*>(qp + 32);
    }

    const int skr = tid >> 2;
    const int skc = (tid & 3) * 16;
    const int svk = (tid >> 4) * 4;
    const int svd = (tid & 15) * 4;

    float m_run = -1e30f, l_run = 0.f;
    f32x4 acc[4] = {};

    for (int kt = 0; kt < SEQ / 64; ++kt) {
        __syncthreads();
        {   // stage K [kv][d]
            const u16* kp = K + (krow0 + kt * 64 + skr) * ks + hc + skc;
            *reinterpret_cast<short8*>(&Ks[skr * 72 + skc]) =
                *reinterpret_cast<const short8*>(kp);
            *reinterpret_cast<short8*>(&Ks[skr * 72 + skc + 8]) =
                *reinterpret_cast<const short8*>(kp + 8);
        }
        {   // stage V transposed: Vt[d][kv]
            const u16* vp = V + (krow0 + kt * 64 + svk) * vs + hc + svd;
            const ushort4 l0 = *reinterpret_cast<const ushort4*>(vp);
            const ushort4 l1 = *reinterpret_cast<const ushort4*>(vp + vs);
            const ushort4 l2 = *reinterpret_cast<const ushort4*>(vp + 2 * (size_t)vs);
            const ushort4 l3 = *reinterpret_cast<const ushort4*>(vp + 3 * (size_t)vs);
            uint2 w;
            w.x = (unsigned)l0.x | ((unsigned)l1.x << 16);
            w.y = (unsigned)l2.x | ((unsigned)l3.x << 16);
            *reinterpret_cast<uint2*>(&Vt[(svd + 0) * 72 + svk]) = w;
            w.x = (unsigned)l0.y | ((unsigned)l1.y << 16);
            w.y = (unsigned)l2.y | ((unsigned)l3.y << 16);
            *reinterpret_cast<uint2*>(&Vt[(svd + 1) * 72 + svk]) = w;
            w.x = (unsigned)l0.z | ((unsigned)l1.z << 16);
            w.y = (unsigned)l2.z | ((unsigned)l3.z << 16);
            *reinterpret_cast<uint2*>(&Vt[(svd + 2) * 72 + svk]) = w;
            w.x = (unsigned)l0.w | ((unsigned)l1.w << 16);
            w.y = (unsigned)l2.w | ((unsigned)l3.w << 16);
            *reinterpret_cast<uint2*>(&Vt[(svd + 3) * 72 + svk]) = w;
        }
        __syncthreads();

        f32x4 st[4] = {};
        #pragma unroll
        for (int kn = 0; kn < 4; ++kn) {
            const short8 ka0 = *reinterpret_cast<const short8*>(
                &Ks[(kn * 16 + fr) * 72 + fq * 8]);
            const short8 ka1 = *reinterpret_cast<const short8*>(
                &Ks[(kn * 16 + fr) * 72 + 32 + fq * 8]);
            st[kn] = __builtin_amdgcn_mfma_f32_16x16x32_bf16(ka0, qf[0], st[kn], 0, 0, 0);
            st[kn] = __builtin_amdgcn_mfma_f32_16x16x32_bf16(ka1, qf[1], st[kn], 0, 0, 0);
        }

        float mx = -1e30f;
        #pragma unroll
        for (int kn = 0; kn < 4; ++kn)
            #pragma unroll
            for (int r = 0; r < 4; ++r) {
                st[kn][r] *= 0.125f;
                mx = fmaxf(mx, st[kn][r]);
            }
        mx = fmaxf(mx, __shfl_xor(mx, 16, 64));
        mx = fmaxf(mx, __shfl_xor(mx, 32, 64));
        const float mnew = fmaxf(m_run, mx);
        const float corr = __expf(m_run - mnew);
        m_run = mnew;
        float psum = 0.f;
        #pragma unroll
        for (int kn = 0; kn < 4; ++kn) {
            const float p0 = __expf(st[kn][0] - mnew);
            const float p1 = __expf(st[kn][1] - mnew);
            const float p2 = __expf(st[kn][2] - mnew);
            const float p3 = __expf(st[kn][3] - mnew);
            psum += (p0 + p1) + (p2 + p3);
            uint2 w;
            w.x = (unsigned)f2b(p0) | ((unsigned)f2b(p1) << 16);
            w.y = (unsigned)f2b(p2) | ((unsigned)f2b(p3) << 16);
            *reinterpret_cast<uint2*>(&Ps[wave][fr * 72 + kn * 16 + fq * 4]) = w;
        }
        psum += __shfl_xor(psum, 16, 64);
        psum += __shfl_xor(psum, 32, 64);
        l_run = l_run * corr + psum;

        float cq[4];
        #pragma unroll
        for (int j = 0; j < 4; ++j) cq[j] = __shfl(corr, fq * 4 + j, 64);
        #pragma unroll
        for (int nd = 0; nd < 4; ++nd)
            #pragma unroll
            for (int j = 0; j < 4; ++j)
                acc[nd][j] *= cq[j];

        short8 pa0 = *reinterpret_cast<const short8*>(&Ps[wave][fr * 72 + fq * 8]);
        short8 pa1 = *reinterpret_cast<const short8*>(&Ps[wave][fr * 72 + 32 + fq * 8]);
        #pragma unroll
        for (int nd = 0; nd < 4; ++nd) {
            const short8 vb0 = *reinterpret_cast<const short8*>(
                &Vt[(nd * 16 + fr) * 72 + fq * 8]);
            const short8 vb1 = *reinterpret_cast<const short8*>(
                &Vt[(nd * 16 + fr) * 72 + 32 + fq * 8]);
            acc[nd] = __builtin_amdgcn_mfma_f32_16x16x32_bf16(pa0, vb0, acc[nd], 0, 0, 0);
            acc[nd] = __builtin_amdgcn_mfma_f32_16x16x32_bf16(pa1, vb1, acc[nd], 0, 0, 0);
        }
    }

    float iq[4];
    #pragma unroll
    for (int j = 0; j < 4; ++j) iq[j] = 1.f / __shfl(l_run, fq * 4 + j, 64);
    #pragma unroll
    for (int j = 0; j < 4; ++j) {
        const size_t orow = (qrow0 + wave * 16 + fq * 4 + j) * os + hc;
        #pragma unroll
        for (int nd = 0; nd < 4; ++nd) {
            const float v = acc[nd][j] * iq[j];
            if (OB) ((u16*)Ov)[orow + nd * 16 + fr] = f2b(v);
            else    ((float*)Ov)[orow + nd * 16 + fr] = v;
        }
    }
}

// -------------------- gate mix (dot, softmax-2, blend) ---------------------
__global__ __launch_bounds__(256)
void mix_kernel(const float* __restrict__ gctx, const float* __restrict__ mixw,
                const float* __restrict__ mixb, const float* __restrict__ so,
                const float* __restrict__ co, u16* __restrict__ mixed)
{
    const size_t row = blockIdx.x;
    const float* g = gctx + row * 512;
    float d0 = 0.f, d1 = 0.f;
    for (int c = threadIdx.x; c < 512; c += 256) {
        const float gv = g[c];
        d0 = fmaf(gv, mixw[c], d0);
        d1 = fmaf(gv, mixw[512 + c], d1);
    }
    #pragma unroll
    for (int off = 32; off > 0; off >>= 1) {
        d0 += __shfl_down(d0, off);
        d1 += __shfl_down(d1, off);
    }
    __shared__ float sA[4], sB[4];
    const int wid = threadIdx.x >> 6;
    if ((threadIdx.x & 63) == 0) { sA[wid] = d0; sB[wid] = d1; }
    __syncthreads();
    const float t0 = sA[0] + sA[1] + sA[2] + sA[3] + mixb[0];
    const float t1 = sB[0] + sB[1] + sB[2] + sB[3] + mixb[1];
    const float mx = fmaxf(t0, t1);
    const float e0 = __expf(t0 - mx), e1 = __expf(t1 - mx);
    const float inv = 1.f / (e0 + e1);
    const float w0 = e0 * inv, w1 = e1 * inv;
    for (int c = threadIdx.x; c < 512; c += 256)
        mixed[row * 512 + c] = f2b(w0 * so[row * 512 + c] + w1 * co[row * 512 + c]);
}

// ---------------------------------------------------------------------------
extern "C" void kernel_launch(void* const* d_in, const int* in_sizes, int n_in,
                              void* d_out, int out_size, void* d_ws, size_t ws_size,
                              hipStream_t stream)
{
    const float* query     = (const float*)d_in[0];
    const float* kvwt      = (const float*)d_in[1];
    const float* nq_w      = (const float*)d_in[2];
    const float* nq_b      = (const float*)d_in[3];
    const float* nkv_w     = (const float*)d_in[4];
    const float* nkv_b     = (const float*)d_in[5];
    const float* wq_cross  = (const float*)d_in[6];
    const float* wkv_cross = (const float*)d_in[7];
    const float* wqkv_self = (const float*)d_in[8];
    const float* gn_w      = (const float*)d_in[9];
    const float* gn_b      = (const float*)d_in[10];
    const float* mha_in_w  = (const float*)d_in[11];
    const float* mha_out_w = (const float*)d_in[12];
    const float* mix_w     = (const float*)d_in[13];
    const float* mix_b     = (const float*)d_in[14];
    const float* w_out     = (const float*)d_in[15];
    const float* ff_ln_w   = (const float*)d_in[16];
    const float* ff_ln_b   = (const float*)d_in[17];
    const float* ff_fc1    = (const float*)d_in[18];
    const float* ff_fc2    = (const float*)d_in[19];
    const float* ff_gate   = (const float*)d_in[20];

    float* delta_out = (float*)d_out;                          // stack[0]
    float* wt_out    = (float*)d_out + (size_t)M_ROWS * 1024;  // stack[1]

    // ---- workspace layout (byte offsets; total 59,768,832 B = 57 MB) ----
    char* wsb = (char*)d_ws;
    u16*   qkv_b   = (u16*)  (wsb + 0);          // bf16 [2048,1536]
    u16*   kv_c_b  = (u16*)  (wsb + 6291456);    // bf16 [2048,1024]
    u16*   q_c_b   = (u16*)  (wsb + 10485760);   // bf16 [2048,512]
    float* cross_f = (float*)(wsb + 12582912);   // f32  [2048,512]
    float* self_f  = (float*)(wsb + 16777216);   // f32  [2048,512]
    u16*   kvn_b   = (u16*)  (wsb + 20971520);   // bf16 [2048,1024]
    u16*   qn_b    = (u16*)  (wsb + 25165824);   // bf16 [2048,1024]
    u16*   wta_b   = (u16*)  (wsb + 29360128);   // bf16 [2048,512]
    u16*   con_b   = (u16*)  (wsb + 31457280);   // bf16 [2048,512]
    // aliases (liveness audited):
    u16*   gq_b    = qkv_b;
    u16*   gk_b    = qkv_b + 1048576;
    u16*   gv_b    = qkv_b + 2097152;
    float* gctx_f  = (float*)kv_c_b;
    u16*   gattn_b = kvn_b;
    u16*   mixed_b = kvn_b + 1048576;
    u16*   lnd_b   = qn_b;
    u16*   son_b   = wta_b;
    u16*   ffh_b   = qkv_b;
    // bf16 weights:
    u16* wqkv_self_b = (u16*)(wsb + 33554432);
    u16* wq_cross_b  = (u16*)(wsb + 36700160);
    u16* wkv_cross_b = (u16*)(wsb + 37748736);
    u16* mha_in_b    = (u16*)(wsb + 39845888);
    u16* mha_out_b   = (u16*)(wsb + 41418752);
    u16* w_out_b     = (u16*)(wsb + 41943040);
    u16* ff_fc1_b    = (u16*)(wsb + 42991616);
    u16* ff_fc2_b    = (u16*)(wsb + 51380224);

    const dim3 blk(256);
    const dim3 attn_grid(SEQ / 64, 16);
    auto cvt = [&](const float* src, u16* dst, int n) {
        f2b_kernel<<<dim3(n / 1024), blk, 0, stream>>>(src, dst, n);
    };

    // 0. weight conversions
    cvt(wqkv_self, wqkv_self_b, 1536 * 1024);
    cvt(wq_cross,  wq_cross_b,   512 * 1024);
    cvt(wkv_cross, wkv_cross_b, 1024 * 1024);
    cvt(mha_in_w,  mha_in_b,    1536 * 512);
    cvt(mha_out_w, mha_out_b,    512 * 512);
    cvt(w_out,     w_out_b,     1024 * 512);
    cvt(ff_fc1,    ff_fc1_b,    4096 * 1024);
    cvt(ff_fc2,    ff_fc2_b,    1024 * 4096);

    // 1. kvn = LN(kv_feats_wt)
    ln_bf16<<<M_ROWS, blk, 0, stream>>>(kvwt, nkv_w, nkv_b, kvn_b, 1024);
    // 2. qkv_wt = kvn @ wqkv_self^T               [2048x1536 K=1024] grid 384
    gemm_mfma<64,128,0,1><<<dim3(12, 32), blk, 0, stream>>>(kvn_b, wqkv_self_b, qkv_b, 1536, 1024, nullptr);
    // 3. wt_attn (bf16 out)
    attn_mfma<1><<<attn_grid, blk, 0, stream>>>(qkv_b, qkv_b + 512, qkv_b + 1024, wta_b, 1536, 1536, 1536, 512);
    // 4. wt_out = wt_attn @ w_out^T -> stack[1]   [2048x1024 K=512] grid 256
    gemm_mfma<64,128,0,0><<<dim3(8, 32), blk, 0, stream>>>(wta_b, w_out_b, wt_out, 1024, 512, nullptr);
    // 5. qn = LN(query_feats)
    ln_bf16<<<M_ROWS, blk, 0, stream>>>(query, nq_w, nq_b, qn_b, 1024);
    // 6. q_c = qn @ wq_cross^T                    [2048x512 K=1024] grid 256
    gemm_mfma<64,64,0,1><<<dim3(8, 32), blk, 0, stream>>>(qn_b, wq_cross_b, q_c_b, 512, 1024, nullptr);
    // 7. kv_c = kvn @ wkv_cross^T                 [2048x1024 K=1024] grid 256
    gemm_mfma<64,128,0,1><<<dim3(8, 32), blk, 0, stream>>>(kvn_b, wkv_cross_b, kv_c_b, 1024, 1024, nullptr);
    // 8. cross_out (f32 out)
    attn_mfma<0><<<attn_grid, blk, 0, stream>>>(q_c_b, kv_c_b, kv_c_b + 512, cross_f, 512, 1024, 1024, 512);
    // 9. qkv_s = qn @ wqkv_self^T                 grid 384
    gemm_mfma<64,128,0,1><<<dim3(12, 32), blk, 0, stream>>>(qn_b, wqkv_self_b, qkv_b, 1536, 1024, nullptr);
    // 10. self_out (f32 out)
    attn_mfma<0><<<attn_grid, blk, 0, stream>>>(qkv_b, qkv_b + 512, qkv_b + 1024, self_f, 1536, 1536, 1536, 512);
    // 11. son = LN(self_out; gn), con = LN(cross_out; gn)
    ln_bf16<<<M_ROWS, blk, 0, stream>>>(self_f,  gn_w, gn_b, son_b, 512);
    ln_bf16<<<M_ROWS, blk, 0, stream>>>(cross_f, gn_w, gn_b, con_b, 512);
    // 12. gq/gk/gv                                [2048x512 K=512] grid 256
    gemm_mfma<64,64,0,1><<<dim3(8, 32), blk, 0, stream>>>(son_b, mha_in_b,            gq_b, 512, 512, nullptr);
    gemm_mfma<64,64,0,1><<<dim3(8, 32), blk, 0, stream>>>(con_b, mha_in_b + 512*512,  gk_b, 512, 512, nullptr);
    gemm_mfma<64,64,0,1><<<dim3(8, 32), blk, 0, stream>>>(con_b, mha_in_b + 1024*512, gv_b, 512, 512, nullptr);
    // 13. gate attention (bf16 out)
    attn_mfma<1><<<attn_grid, blk, 0, stream>>>(gq_b, gk_b, gv_b, gattn_b, 512, 512, 512, 512);
    // 14. gate_ctx = gate_attn @ mha_out_w^T (f32 out)  grid 256
    gemm_mfma<64,64,0,0><<<dim3(8, 32), blk, 0, stream>>>(gattn_b, mha_out_b, gctx_f, 512, 512, nullptr);
    // 15. mixed = softmax-gate blend (bf16 out)
    mix_kernel<<<M_ROWS, blk, 0, stream>>>(gctx_f, mix_w, mix_b, self_f, cross_f, mixed_b);
    // 16. delta = mixed @ w_out^T -> stack[0] (f32)     grid 256
    gemm_mfma<64,128,0,0><<<dim3(8, 32), blk, 0, stream>>>(mixed_b, w_out_b, delta_out, 1024, 512, nullptr);
    // 17. ln_delta = LN(delta; ff_ln)
    ln_bf16<<<M_ROWS, blk, 0, stream>>>(delta_out, ff_ln_w, ff_ln_b, lnd_b, 1024);
    // 18. ffh = gelu(ln_delta @ ff_fc1^T)         [2048x4096 K=1024] grid 1024
    gemm_mfma<64,128,1,1><<<dim3(32, 32), blk, 0, stream>>>(lnd_b, ff_fc1_b, ffh_b, 4096, 1024, nullptr);
    // 19. delta += ff_gate * (ffh @ ff_fc2^T)     [2048x1024 K=4096] grid 256
    gemm_mfma<64,128,2,0><<<dim3(8, 32), blk, 0, stream>>>(ffh_b, ff_fc2_b, delta_out, 1024, 4096, ff_gate);
}

// Round 7
// 335.096 us; speedup vs baseline: 4.4905x; 1.1688x over previous
//
#include <hip/hip_runtime.h>
#include <math.h>

// ---------------------------------------------------------------------------
// GatedCrossAttention: B=2, NQ=NK=1024, QD=KVD=OD=1024, H=8, DH=64, INNER=512
// Round 7: concurrency fix — per-block memory delivery is HW-capped (~10-15
// B/cyc/block), so multiply streams: all GEMMs 64x64/PF=3/ring-4 (32 KB LDS,
// up to 5 blocks/CU), fc2 split-K=4 (grid 2048 + reduce), attention T14
// async-stage (reg prefetch of next K/V tile), gk/gv merged.
// ---------------------------------------------------------------------------

#define M_ROWS 2048   // B*NQ
#define SEQ    1024

typedef unsigned short u16;
typedef __attribute__((ext_vector_type(8))) short short8;
typedef __attribute__((ext_vector_type(4))) float f32x4;

__device__ inline u16 f2b(float f) {
    unsigned u = __builtin_bit_cast(unsigned, f);
    u += 0x7FFFu + ((u >> 16) & 1u);   // round-to-nearest-even
    return (u16)(u >> 16);
}
__device__ inline float b2f(u16 h) {
    return __builtin_bit_cast(float, (unsigned)h << 16);
}

__device__ inline void gload16(const u16* g, u16* l) {
    __builtin_amdgcn_global_load_lds(
        (const __attribute__((address_space(1))) void*)g,
        (__attribute__((address_space(3))) void*)l, 16, 0, 0);
}

// ------------------------- f32 -> bf16 convert -----------------------------
__global__ __launch_bounds__(256)
void f2b_kernel(const float* __restrict__ in, u16* __restrict__ out, int n)
{
    const int i = (blockIdx.x * 256 + threadIdx.x) * 4;
    if (i < n) {
        const float4 v = *reinterpret_cast<const float4*>(&in[i]);
        ushort4 o;
        o.x = f2b(v.x); o.y = f2b(v.y); o.z = f2b(v.z); o.w = f2b(v.w);
        *reinterpret_cast<ushort4*>(&out[i]) = o;
    }
}

// ----------------------------- LayerNorm -----------------------------------
__global__ __launch_bounds__(256)
void ln_bf16(const float* __restrict__ x, const float* __restrict__ w,
             const float* __restrict__ bias, u16* __restrict__ out, int D)
{
    const size_t row = blockIdx.x;
    const float* xr = x + row * (size_t)D;
    const int c = threadIdx.x * 4;
    float4 v = make_float4(0.f, 0.f, 0.f, 0.f);
    if (c < D) v = *reinterpret_cast<const float4*>(&xr[c]);
    float sum = v.x + v.y + v.z + v.w;
    float sq  = v.x*v.x + v.y*v.y + v.z*v.z + v.w*v.w;
    #pragma unroll
    for (int off = 32; off > 0; off >>= 1) {
        sum += __shfl_down(sum, off);
        sq  += __shfl_down(sq,  off);
    }
    __shared__ float s1[4], s2[4];
    const int wid = threadIdx.x >> 6;
    if ((threadIdx.x & 63) == 0) { s1[wid] = sum; s2[wid] = sq; }
    __syncthreads();
    const float tsum = s1[0] + s1[1] + s1[2] + s1[3];
    const float tsq  = s2[0] + s2[1] + s2[2] + s2[3];
    const float mean = tsum / (float)D;
    const float var  = tsq / (float)D - mean * mean;
    const float rstd = rsqrtf(var + 1e-5f);
    if (c < D) {
        ushort4 o;
        o.x = f2b((v.x - mean) * rstd * w[c+0] + bias[c+0]);
        o.y = f2b((v.y - mean) * rstd * w[c+1] + bias[c+1]);
        o.z = f2b((v.z - mean) * rstd * w[c+2] + bias[c+2]);
        o.w = f2b((v.w - mean) * rstd * w[c+3] + bias[c+3]);
        *reinterpret_cast<ushort4*>(&out[row * (size_t)D + c]) = o;
    }
}

// ------------------------------ MFMA GEMM ----------------------------------
// C[M,N] = A[M,K]*W[N,K]^T, bf16 in, f32 acc. 64x64 tile, BK=32, 4 waves
// (2x2), PF=3 tiles in flight / ring-4 LDS (32 KB -> up to 5 blocks/CU).
// Counted vmcnt (never 0 in steady loop), compile-time tail drain.
// Chunk swizzle: linear gload dest + swizzled global source + swizzled
// ds_read -> bank-conflict-free (verified 2.1e6 -> 0).
// Split-K: kchunk < K selects K-range [z*kchunk,(z+1)*kchunk), partial plane
// z of C (f32). EPI: 0=none, 1=exact GELU, 2=C += gate*acc. OB: bf16 output.
template<int EPI, int OB>
__global__ __launch_bounds__(256)
void gemm_mfma(const u16* __restrict__ A, const u16* __restrict__ W,
               void* __restrict__ Cv, int N, int K,
               const float* __restrict__ gatep, int kchunk)
{
    constexpr int PF  = 3;                  // tiles in flight
    constexpr int LPT = 2;                  // gload insts per tile per thread
    __shared__ __align__(16) u16 As[4][64 * 32];
    __shared__ __align__(16) u16 Ws[4][64 * 32];
    const int tid  = threadIdx.x;
    const int lane = tid & 63;
    const int wave = tid >> 6;
    const int wr = wave >> 1, wc = wave & 1;

    // XCD-aware column-chunk swizzle (all x*y grids here are multiples of 8).
    const int nwg = gridDim.x * gridDim.y;
    const int bid = blockIdx.y * gridDim.x + blockIdx.x;   // dispatch order
    const int nid = (bid & 7) * (nwg >> 3) + (bid >> 3);   // chunk per XCD
    const int by  = nid % gridDim.y;
    const int bx  = nid / gridDim.y;
    const int m0 = by * 64, n0 = bx * 64;
    const int kz = blockIdx.z * kchunk;

    // staging: thread tid -> LDS row tid>>2 (linear dest), global chunk
    // pre-swizzled so LDS[row][c] holds global[row][c ^ ((row>>1)&3)].
    const int srow = tid >> 2;
    const int scol = (((tid & 3) ^ ((srow >> 1) & 3))) * 8;
    const u16* Ag = A + (size_t)(m0 + srow) * K + scol + kz;
    const u16* Wg = W + (size_t)(n0 + srow) * K + scol + kz;

    const int fr = lane & 15;
    const int fq = lane >> 4;

    f32x4 acc[2][2] = {};

    auto stage = [&](int buf, int k0) {
        gload16(Ag + k0, &As[buf][tid * 8]);
        gload16(Wg + k0, &Ws[buf][tid * 8]);
    };
    auto compute = [&](int buf) {
        short8 a[2], b[2];
        #pragma unroll
        for (int m = 0; m < 2; ++m) {
            const int r = wr * 32 + m * 16 + fr;
            a[m] = *reinterpret_cast<const short8*>(
                &As[buf][r * 32 + ((fq ^ ((r >> 1) & 3)) << 3)]);
        }
        #pragma unroll
        for (int n = 0; n < 2; ++n) {
            const int r = wc * 32 + n * 16 + fr;
            b[n] = *reinterpret_cast<const short8*>(
                &Ws[buf][r * 32 + ((fq ^ ((r >> 1) & 3)) << 3)]);
        }
        #pragma unroll
        for (int m = 0; m < 2; ++m)
            #pragma unroll
            for (int n = 0; n < 2; ++n)
                acc[m][n] = __builtin_amdgcn_mfma_f32_16x16x32_bf16(
                    a[m], b[n], acc[m][n], 0, 0, 0);
    };

    const int nt = kchunk / 32;             // >= 16 for all shapes here
    #pragma unroll
    for (int i = 0; i < PF; ++i) stage(i, i * 32);

    int cbuf = 0, sbuf = PF;
    for (int t = 0; t <= nt - PF; ++t) {
        // tile t resident once <= (PF-1)*LPT newest loads outstanding
        asm volatile("s_waitcnt vmcnt(%0)\n\ts_barrier"
                     :: "n"((PF - 1) * LPT) : "memory");
        if (t + PF < nt) {
            stage(sbuf & 3, (t + PF) * 32);
            ++sbuf;
        }
        compute(cbuf & 3);
        ++cbuf;
    }
    #pragma unroll
    for (int i = 1; i < PF; ++i) {          // drain tail, compile-time waits
        asm volatile("s_waitcnt vmcnt(%0)\n\ts_barrier"
                     :: "n"((PF - 1 - i) * LPT) : "memory");
        compute(cbuf & 3);
        ++cbuf;
    }

    // C/D layout: col = lane&15, row = (lane>>4)*4 + reg  [m89/m91 verified]
    float* Cz = (float*)Cv + (size_t)blockIdx.z * M_ROWS * N;  // split-K plane
    const float gate = (EPI == 2) ? gatep[0] : 0.f;
    #pragma unroll
    for (int m = 0; m < 2; ++m) {
        #pragma unroll
        for (int j = 0; j < 4; ++j) {
            const size_t row = (size_t)(m0 + wr * 32 + m * 16 + fq * 4 + j);
            #pragma unroll
            for (int n = 0; n < 2; ++n) {
                float v = acc[m][n][j];
                const size_t idx = row * (size_t)N + (size_t)(n0 + wc * 32 + n * 16 + fr);
                if (EPI == 1) v = 0.5f * v * (1.f + erff(v * 0.70710678118654752f));
                if (OB) {
                    ((u16*)Cv)[idx] = f2b(v);
                } else {
                    if (EPI == 2) Cz[idx] = Cz[idx] + gate * v;
                    else          Cz[idx] = v;
                }
            }
        }
    }
}

// ---------------- split-K reduce: C += gate * (p0+p1+p2+p3) ----------------
__global__ __launch_bounds__(256)
void redk(const float* __restrict__ p, const float* __restrict__ gatep,
          float* __restrict__ C)
{
    const int i = (blockIdx.x * 256 + threadIdx.x) * 4;
    const float g = gatep[0];
    const float4 a = *reinterpret_cast<const float4*>(p + i);
    const float4 b = *reinterpret_cast<const float4*>(p + 2097152 + i);
    const float4 c = *reinterpret_cast<const float4*>(p + 4194304 + i);
    const float4 d = *reinterpret_cast<const float4*>(p + 6291456 + i);
    float4 o = *reinterpret_cast<float4*>(C + i);
    o.x += g * ((a.x + b.x) + (c.x + d.x));
    o.y += g * ((a.y + b.y) + (c.y + d.y));
    o.z += g * ((a.z + b.z) + (c.z + d.z));
    o.w += g * ((a.w + b.w) + (c.w + d.w));
    *reinterpret_cast<float4*>(C + i) = o;
}

// ------------------------- MFMA fused attention ----------------------------
// grid = (NQ/64, B*H), 256 threads = 4 waves x 16 q-rows. bf16 QKV.
// Swapped QK^T; P via wave-private LDS round-trip; V staged transposed.
// T14 async-stage: next K/V tile loaded to REGISTERS before compute, written
// to LDS after the post-compute barrier (HBM latency hides under compute).
template<int OB>
__global__ __launch_bounds__(256)
void attn_mfma(const u16* __restrict__ Q, const u16* __restrict__ K,
               const u16* __restrict__ V, void* __restrict__ Ov,
               int qs, int ks, int vs, int os)
{
    __shared__ __align__(16) u16 Ks[64 * 72];      // [kv][d], pad 72
    __shared__ __align__(16) u16 Vt[64 * 72];      // [d][kv], pad 72
    __shared__ __align__(16) u16 Ps[4][16 * 72];   // per-wave P [q][kv]
    const int tid  = threadIdx.x;
    const int lane = tid & 63;
    const int wave = tid >> 6;
    const int fr = lane & 15;
    const int fq = lane >> 4;
    const int b  = blockIdx.y >> 3;
    const int hc = (blockIdx.y & 7) * 64;
    const size_t qrow0 = (size_t)b * SEQ + (size_t)blockIdx.x * 64;
    const size_t krow0 = (size_t)b * SEQ;

    short8 qf[2];
    {
        const u16* qp = Q + (qrow0 + wave * 16 + fr) * qs + hc + fq * 8;
        qf[0] = *reinterpret_cast<const short8*>(qp);
        qf[1] = *reinterpret_cast<const short8*>(qp + 32);
    }

    const int skr = tid >> 2;
    const int skc = (tid & 3) * 16;
    const int svk = (tid >> 4) * 4;
    const int svd = (tid & 15) * 4;

    // register-staged next tile (T14)
    short8 kreg0, kreg1;
    ushort4 vr0, vr1, vr2, vr3;
    auto load_tile = [&](int kt) {
        const u16* kp = K + (krow0 + kt * 64 + skr) * ks + hc + skc;
        kreg0 = *reinterpret_cast<const short8*>(kp);
        kreg1 = *reinterpret_cast<const short8*>(kp + 8);
        const u16* vp = V + (krow0 + kt * 64 + svk) * vs + hc + svd;
        vr0 = *reinterpret_cast<const ushort4*>(vp);
        vr1 = *reinterpret_cast<const ushort4*>(vp + vs);
        vr2 = *reinterpret_cast<const ushort4*>(vp + 2 * (size_t)vs);
        vr3 = *reinterpret_cast<const ushort4*>(vp + 3 * (size_t)vs);
    };
    auto write_tile = [&]() {
        *reinterpret_cast<short8*>(&Ks[skr * 72 + skc]) = kreg0;
        *reinterpret_cast<short8*>(&Ks[skr * 72 + skc + 8]) = kreg1;
        uint2 w;
        w.x = (unsigned)vr0.x | ((unsigned)vr1.x << 16);
        w.y = (unsigned)vr2.x | ((unsigned)vr3.x << 16);
        *reinterpret_cast<uint2*>(&Vt[(svd + 0) * 72 + svk]) = w;
        w.x = (unsigned)vr0.y | ((unsigned)vr1.y << 16);
        w.y = (unsigned)vr2.y | ((unsigned)vr3.y << 16);
        *reinterpret_cast<uint2*>(&Vt[(svd + 1) * 72 + svk]) = w;
        w.x = (unsigned)vr0.z | ((unsigned)vr1.z << 16);
        w.y = (unsigned)vr2.z | ((unsigned)vr3.z << 16);
        *reinterpret_cast<uint2*>(&Vt[(svd + 2) * 72 + svk]) = w;
        w.x = (unsigned)vr0.w | ((unsigned)vr1.w << 16);
        w.y = (unsigned)vr2.w | ((unsigned)vr3.w << 16);
        *reinterpret_cast<uint2*>(&Vt[(svd + 3) * 72 + svk]) = w;
    };

    float m_run = -1e30f, l_run = 0.f;
    f32x4 acc[4] = {};

    load_tile(0);
    write_tile();
    __syncthreads();

    constexpr int NT = SEQ / 64;
    for (int kt = 0; kt < NT; ++kt) {
        if (kt + 1 < NT) load_tile(kt + 1);   // issue early (hidden by compute)

        f32x4 st[4] = {};
        #pragma unroll
        for (int kn = 0; kn < 4; ++kn) {
            const short8 ka0 = *reinterpret_cast<const short8*>(
                &Ks[(kn * 16 + fr) * 72 + fq * 8]);
            const short8 ka1 = *reinterpret_cast<const short8*>(
                &Ks[(kn * 16 + fr) * 72 + 32 + fq * 8]);
            st[kn] = __builtin_amdgcn_mfma_f32_16x16x32_bf16(ka0, qf[0], st[kn], 0, 0, 0);
            st[kn] = __builtin_amdgcn_mfma_f32_16x16x32_bf16(ka1, qf[1], st[kn], 0, 0, 0);
        }

        float mx = -1e30f;
        #pragma unroll
        for (int kn = 0; kn < 4; ++kn)
            #pragma unroll
            for (int r = 0; r < 4; ++r) {
                st[kn][r] *= 0.125f;
                mx = fmaxf(mx, st[kn][r]);
            }
        mx = fmaxf(mx, __shfl_xor(mx, 16, 64));
        mx = fmaxf(mx, __shfl_xor(mx, 32, 64));
        const float mnew = fmaxf(m_run, mx);
        const float corr = __expf(m_run - mnew);
        m_run = mnew;
        float psum = 0.f;
        #pragma unroll
        for (int kn = 0; kn < 4; ++kn) {
            const float p0 = __expf(st[kn][0] - mnew);
            const float p1 = __expf(st[kn][1] - mnew);
            const float p2 = __expf(st[kn][2] - mnew);
            const float p3 = __expf(st[kn][3] - mnew);
            psum += (p0 + p1) + (p2 + p3);
            uint2 w;
            w.x = (unsigned)f2b(p0) | ((unsigned)f2b(p1) << 16);
            w.y = (unsigned)f2b(p2) | ((unsigned)f2b(p3) << 16);
            *reinterpret_cast<uint2*>(&Ps[wave][fr * 72 + kn * 16 + fq * 4]) = w;
        }
        psum += __shfl_xor(psum, 16, 64);
        psum += __shfl_xor(psum, 32, 64);
        l_run = l_run * corr + psum;

        float cq[4];
        #pragma unroll
        for (int j = 0; j < 4; ++j) cq[j] = __shfl(corr, fq * 4 + j, 64);
        #pragma unroll
        for (int nd = 0; nd < 4; ++nd)
            #pragma unroll
            for (int j = 0; j < 4; ++j)
                acc[nd][j] *= cq[j];

        short8 pa0 = *reinterpret_cast<const short8*>(&Ps[wave][fr * 72 + fq * 8]);
        short8 pa1 = *reinterpret_cast<const short8*>(&Ps[wave][fr * 72 + 32 + fq * 8]);
        #pragma unroll
        for (int nd = 0; nd < 4; ++nd) {
            const short8 vb0 = *reinterpret_cast<const short8*>(
                &Vt[(nd * 16 + fr) * 72 + fq * 8]);
            const short8 vb1 = *reinterpret_cast<const short8*>(
                &Vt[(nd * 16 + fr) * 72 + 32 + fq * 8]);
            acc[nd] = __builtin_amdgcn_mfma_f32_16x16x32_bf16(pa0, vb0, acc[nd], 0, 0, 0);
            acc[nd] = __builtin_amdgcn_mfma_f32_16x16x32_bf16(pa1, vb1, acc[nd], 0, 0, 0);
        }

        __syncthreads();                      // all reads of current tile done
        if (kt + 1 < NT) write_tile();        // write next tile (late, T14)
        __syncthreads();                      // writes visible
    }

    float iq[4];
    #pragma unroll
    for (int j = 0; j < 4; ++j) iq[j] = 1.f / __shfl(l_run, fq * 4 + j, 64);
    #pragma unroll
    for (int j = 0; j < 4; ++j) {
        const size_t orow = (qrow0 + wave * 16 + fq * 4 + j) * os + hc;
        #pragma unroll
        for (int nd = 0; nd < 4; ++nd) {
            const float v = acc[nd][j] * iq[j];
            if (OB) ((u16*)Ov)[orow + nd * 16 + fr] = f2b(v);
            else    ((float*)Ov)[orow + nd * 16 + fr] = v;
        }
    }
}

// -------------------- gate mix (dot, softmax-2, blend) ---------------------
__global__ __launch_bounds__(256)
void mix_kernel(const float* __restrict__ gctx, const float* __restrict__ mixw,
                const float* __restrict__ mixb, const float* __restrict__ so,
                const float* __restrict__ co, u16* __restrict__ mixed)
{
    const size_t row = blockIdx.x;
    const float* g = gctx + row * 512;
    float d0 = 0.f, d1 = 0.f;
    for (int c = threadIdx.x; c < 512; c += 256) {
        const float gv = g[c];
        d0 = fmaf(gv, mixw[c], d0);
        d1 = fmaf(gv, mixw[512 + c], d1);
    }
    #pragma unroll
    for (int off = 32; off > 0; off >>= 1) {
        d0 += __shfl_down(d0, off);
        d1 += __shfl_down(d1, off);
    }
    __shared__ float sA[4], sB[4];
    const int wid = threadIdx.x >> 6;
    if ((threadIdx.x & 63) == 0) { sA[wid] = d0; sB[wid] = d1; }
    __syncthreads();
    const float t0 = sA[0] + sA[1] + sA[2] + sA[3] + mixb[0];
    const float t1 = sB[0] + sB[1] + sB[2] + sB[3] + mixb[1];
    const float mx = fmaxf(t0, t1);
    const float e0 = __expf(t0 - mx), e1 = __expf(t1 - mx);
    const float inv = 1.f / (e0 + e1);
    const float w0 = e0 * inv, w1 = e1 * inv;
    for (int c = threadIdx.x; c < 512; c += 256)
        mixed[row * 512 + c] = f2b(w0 * so[row * 512 + c] + w1 * co[row * 512 + c]);
}

// ---------------------------------------------------------------------------
extern "C" void kernel_launch(void* const* d_in, const int* in_sizes, int n_in,
                              void* d_out, int out_size, void* d_ws, size_t ws_size,
                              hipStream_t stream)
{
    const float* query     = (const float*)d_in[0];
    const float* kvwt      = (const float*)d_in[1];
    const float* nq_w      = (const float*)d_in[2];
    const float* nq_b      = (const float*)d_in[3];
    const float* nkv_w     = (const float*)d_in[4];
    const float* nkv_b     = (const float*)d_in[5];
    const float* wq_cross  = (const float*)d_in[6];
    const float* wkv_cross = (const float*)d_in[7];
    const float* wqkv_self = (const float*)d_in[8];
    const float* gn_w      = (const float*)d_in[9];
    const float* gn_b      = (const float*)d_in[10];
    const float* mha_in_w  = (const float*)d_in[11];
    const float* mha_out_w = (const float*)d_in[12];
    const float* mix_w     = (const float*)d_in[13];
    const float* mix_b     = (const float*)d_in[14];
    const float* w_out     = (const float*)d_in[15];
    const float* ff_ln_w   = (const float*)d_in[16];
    const float* ff_ln_b   = (const float*)d_in[17];
    const float* ff_fc1    = (const float*)d_in[18];
    const float* ff_fc2    = (const float*)d_in[19];
    const float* ff_gate   = (const float*)d_in[20];

    float* delta_out = (float*)d_out;                          // stack[0]
    float* wt_out    = (float*)d_out + (size_t)M_ROWS * 1024;  // stack[1]

    // ---- workspace layout (byte offsets; total 59,768,832 B = 57 MB) ----
    char* wsb = (char*)d_ws;
    u16*   qkv_b   = (u16*)  (wsb + 0);          // bf16 [2048,1536]
    u16*   kv_c_b  = (u16*)  (wsb + 6291456);    // bf16 [2048,1024]
    u16*   q_c_b   = (u16*)  (wsb + 10485760);   // bf16 [2048,512]
    float* cross_f = (float*)(wsb + 12582912);   // f32  [2048,512]
    float* self_f  = (float*)(wsb + 16777216);   // f32  [2048,512]
    u16*   kvn_b   = (u16*)  (wsb + 20971520);   // bf16 [2048,1024]
    u16*   qn_b    = (u16*)  (wsb + 25165824);   // bf16 [2048,1024]
    u16*   wta_b   = (u16*)  (wsb + 29360128);   // bf16 [2048,512]
    u16*   con_b   = (u16*)  (wsb + 31457280);   // bf16 [2048,512]
    // aliases (liveness audited):
    u16*   gq_b    = qkv_b;                      // [2048,512]
    u16*   gkv_b   = qkv_b + 1048576;            // [2048,1024] fused k|v
    float* gctx_f  = (float*)kv_c_b;
    u16*   gattn_b = kvn_b;
    u16*   mixed_b = kvn_b + 1048576;
    u16*   lnd_b   = qn_b;
    u16*   son_b   = wta_b;
    u16*   ffh_b   = qkv_b;                      // [2048,4096] spans 0..16.78MB
    // split-K partials: 4 x [2048,1024] f32 = 33.55 MB in the dead region
    // 16.78..50.33 MB (self_f..ff_fc1_b inclusive all dead by step 19).
    float* part_f  = (float*)(wsb + 16777216);
    // bf16 weights:
    u16* wqkv_self_b = (u16*)(wsb + 33554432);
    u16* wq_cross_b  = (u16*)(wsb + 36700160);
    u16* wkv_cross_b = (u16*)(wsb + 37748736);
    u16* mha_in_b    = (u16*)(wsb + 39845888);
    u16* mha_out_b   = (u16*)(wsb + 41418752);
    u16* w_out_b     = (u16*)(wsb + 41943040);
    u16* ff_fc1_b    = (u16*)(wsb + 42991616);
    u16* ff_fc2_b    = (u16*)(wsb + 51380224);

    const dim3 blk(256);
    const dim3 attn_grid(SEQ / 64, 16);
    auto cvt = [&](const float* src, u16* dst, int n) {
        f2b_kernel<<<dim3(n / 1024), blk, 0, stream>>>(src, dst, n);
    };

    // 0. weight conversions
    cvt(wqkv_self, wqkv_self_b, 1536 * 1024);
    cvt(wq_cross,  wq_cross_b,   512 * 1024);
    cvt(wkv_cross, wkv_cross_b, 1024 * 1024);
    cvt(mha_in_w,  mha_in_b,    1536 * 512);
    cvt(mha_out_w, mha_out_b,    512 * 512);
    cvt(w_out,     w_out_b,     1024 * 512);
    cvt(ff_fc1,    ff_fc1_b,    4096 * 1024);
    cvt(ff_fc2,    ff_fc2_b,    1024 * 4096);

    // 1. kvn = LN(kv_feats_wt)
    ln_bf16<<<M_ROWS, blk, 0, stream>>>(kvwt, nkv_w, nkv_b, kvn_b, 1024);
    // 2. qkv_wt = kvn @ wqkv_self^T               grid 768 (3/CU)
    gemm_mfma<0,1><<<dim3(24, 32), blk, 0, stream>>>(kvn_b, wqkv_self_b, qkv_b, 1536, 1024, nullptr, 1024);
    // 3. wt_attn (bf16 out)
    attn_mfma<1><<<attn_grid, blk, 0, stream>>>(qkv_b, qkv_b + 512, qkv_b + 1024, wta_b, 1536, 1536, 1536, 512);
    // 4. wt_out = wt_attn @ w_out^T -> stack[1]   grid 512
    gemm_mfma<0,0><<<dim3(16, 32), blk, 0, stream>>>(wta_b, w_out_b, wt_out, 1024, 512, nullptr, 512);
    // 5. qn = LN(query_feats)
    ln_bf16<<<M_ROWS, blk, 0, stream>>>(query, nq_w, nq_b, qn_b, 1024);
    // 6. q_c = qn @ wq_cross^T                    grid 256
    gemm_mfma<0,1><<<dim3(8, 32), blk, 0, stream>>>(qn_b, wq_cross_b, q_c_b, 512, 1024, nullptr, 1024);
    // 7. kv_c = kvn @ wkv_cross^T                 grid 512
    gemm_mfma<0,1><<<dim3(16, 32), blk, 0, stream>>>(kvn_b, wkv_cross_b, kv_c_b, 1024, 1024, nullptr, 1024);
    // 8. cross_out (f32 out)
    attn_mfma<0><<<attn_grid, blk, 0, stream>>>(q_c_b, kv_c_b, kv_c_b + 512, cross_f, 512, 1024, 1024, 512);
    // 9. qkv_s = qn @ wqkv_self^T                 grid 768
    gemm_mfma<0,1><<<dim3(24, 32), blk, 0, stream>>>(qn_b, wqkv_self_b, qkv_b, 1536, 1024, nullptr, 1024);
    // 10. self_out (f32 out)
    attn_mfma<0><<<attn_grid, blk, 0, stream>>>(qkv_b, qkv_b + 512, qkv_b + 1024, self_f, 1536, 1536, 1536, 512);
    // 11. son = LN(self_out; gn), con = LN(cross_out; gn)
    ln_bf16<<<M_ROWS, blk, 0, stream>>>(self_f,  gn_w, gn_b, son_b, 512);
    ln_bf16<<<M_ROWS, blk, 0, stream>>>(cross_f, gn_w, gn_b, con_b, 512);
    // 12. gq (N=512) + fused gkv (N=1024, wk|wv rows 512..1535)
    gemm_mfma<0,1><<<dim3(8, 32),  blk, 0, stream>>>(son_b, mha_in_b,           gq_b,  512,  512, nullptr, 512);
    gemm_mfma<0,1><<<dim3(16, 32), blk, 0, stream>>>(con_b, mha_in_b + 512*512, gkv_b, 1024, 512, nullptr, 512);
    // 13. gate attention (bf16 out): K = gkv[:, :512], V = gkv[:, 512:]
    attn_mfma<1><<<attn_grid, blk, 0, stream>>>(gq_b, gkv_b, gkv_b + 512, gattn_b, 512, 1024, 1024, 512);
    // 14. gate_ctx = gate_attn @ mha_out_w^T (f32 out)  grid 256
    gemm_mfma<0,0><<<dim3(8, 32), blk, 0, stream>>>(gattn_b, mha_out_b, gctx_f, 512, 512, nullptr, 512);
    // 15. mixed = softmax-gate blend (bf16 out)
    mix_kernel<<<M_ROWS, blk, 0, stream>>>(gctx_f, mix_w, mix_b, self_f, cross_f, mixed_b);
    // 16. delta = mixed @ w_out^T -> stack[0] (f32)     grid 512
    gemm_mfma<0,0><<<dim3(16, 32), blk, 0, stream>>>(mixed_b, w_out_b, delta_out, 1024, 512, nullptr, 512);
    // 17. ln_delta = LN(delta; ff_ln)
    ln_bf16<<<M_ROWS, blk, 0, stream>>>(delta_out, ff_ln_w, ff_ln_b, lnd_b, 1024);
    // 18. ffh = gelu(ln_delta @ ff_fc1^T)         grid 2048 (5/CU)
    gemm_mfma<1,1><<<dim3(64, 32), blk, 0, stream>>>(lnd_b, ff_fc1_b, ffh_b, 4096, 1024, nullptr, 1024);
    // 19a. fc2 split-K=4 partials                 grid 2048 (5/CU)
    gemm_mfma<0,0><<<dim3(16, 32, 4), blk, 0, stream>>>(ffh_b, ff_fc2_b, part_f, 1024, 4096, nullptr, 1024);
    // 19b. delta += gate * sum(partials)
    redk<<<dim3(2048), blk, 0, stream>>>(part_f, ff_gate, delta_out);
}

// Round 8
// 308.266 us; speedup vs baseline: 4.8814x; 1.0870x over previous
//
#include <hip/hip_runtime.h>
#include <math.h>

// ---------------------------------------------------------------------------
// GatedCrossAttention: B=2, NQ=NK=1024, QD=KVD=OD=1024, H=8, DH=64, INNER=512
// Round 8: GEMM PF=4/ring-5 (deeper in-flight, 41 KB LDS keeps 3-4 blocks/CU);
// attention double-buffered K/V (1 barrier per kv-tile) + XCD head-chunk
// swizzle (K/V L2-resident); 8 cvt launches fused into 1.
// ---------------------------------------------------------------------------

#define M_ROWS 2048   // B*NQ
#define SEQ    1024

typedef unsigned short u16;
typedef __attribute__((ext_vector_type(8))) short short8;
typedef __attribute__((ext_vector_type(4))) float f32x4;

__device__ inline u16 f2b(float f) {
    unsigned u = __builtin_bit_cast(unsigned, f);
    u += 0x7FFFu + ((u >> 16) & 1u);   // round-to-nearest-even
    return (u16)(u >> 16);
}
__device__ inline float b2f(u16 h) {
    return __builtin_bit_cast(float, (unsigned)h << 16);
}

__device__ inline void gload16(const u16* g, u16* l) {
    __builtin_amdgcn_global_load_lds(
        (const __attribute__((address_space(1))) void*)g,
        (__attribute__((address_space(3))) void*)l, 16, 0, 0);
}

// ------------------- fused f32 -> bf16 weight convert -----------------------
// All 8 weight tensors in one launch; segments hard-coded (1024-elem blocks).
struct CvtPack { const float* s[8]; u16* d[8]; };

__global__ __launch_bounds__(256)
void cvt8_kernel(CvtPack p)
{
    // prefix sums in 1024-elem units: wqkv(1536K) wq(512K) wkv(1024K)
    // mha_in(768K) mha_out(256K) w_out(512K) fc1(4096K) fc2(4096K)
    constexpr int pre[9] = {0, 1536, 2048, 3072, 3840, 4096, 4608, 8704, 12800};
    const int b = blockIdx.x;
    int seg = 0;
    #pragma unroll
    for (int i = 1; i < 8; ++i) seg += (b >= pre[i]);
    const int off = (b - pre[seg]) * 1024 + threadIdx.x * 4;
    const float4 v = *reinterpret_cast<const float4*>(p.s[seg] + off);
    ushort4 o;
    o.x = f2b(v.x); o.y = f2b(v.y); o.z = f2b(v.z); o.w = f2b(v.w);
    *reinterpret_cast<ushort4*>(p.d[seg] + off) = o;
}

// ----------------------------- LayerNorm -----------------------------------
__global__ __launch_bounds__(256)
void ln_bf16(const float* __restrict__ x, const float* __restrict__ w,
             const float* __restrict__ bias, u16* __restrict__ out, int D)
{
    const size_t row = blockIdx.x;
    const float* xr = x + row * (size_t)D;
    const int c = threadIdx.x * 4;
    float4 v = make_float4(0.f, 0.f, 0.f, 0.f);
    if (c < D) v = *reinterpret_cast<const float4*>(&xr[c]);
    float sum = v.x + v.y + v.z + v.w;
    float sq  = v.x*v.x + v.y*v.y + v.z*v.z + v.w*v.w;
    #pragma unroll
    for (int off = 32; off > 0; off >>= 1) {
        sum += __shfl_down(sum, off);
        sq  += __shfl_down(sq,  off);
    }
    __shared__ float s1[4], s2[4];
    const int wid = threadIdx.x >> 6;
    if ((threadIdx.x & 63) == 0) { s1[wid] = sum; s2[wid] = sq; }
    __syncthreads();
    const float tsum = s1[0] + s1[1] + s1[2] + s1[3];
    const float tsq  = s2[0] + s2[1] + s2[2] + s2[3];
    const float mean = tsum / (float)D;
    const float var  = tsq / (float)D - mean * mean;
    const float rstd = rsqrtf(var + 1e-5f);
    if (c < D) {
        ushort4 o;
        o.x = f2b((v.x - mean) * rstd * w[c+0] + bias[c+0]);
        o.y = f2b((v.y - mean) * rstd * w[c+1] + bias[c+1]);
        o.z = f2b((v.z - mean) * rstd * w[c+2] + bias[c+2]);
        o.w = f2b((v.w - mean) * rstd * w[c+3] + bias[c+3]);
        *reinterpret_cast<ushort4*>(&out[row * (size_t)D + c]) = o;
    }
}

// ------------------------------ MFMA GEMM ----------------------------------
// C[M,N] = A[M,K]*W[N,K]^T, bf16 in, f32 acc. 64x64 tile, BK=32, 4 waves,
// PF=4 tiles in flight / ring-5 LDS (41 KB -> 3-4 blocks/CU). Counted vmcnt
// (never 0 in steady loop), compile-time tail drain. Chunk swizzle: linear
// gload dest + swizzled global source + swizzled ds_read (conflict-free,
// verified). Split-K via kchunk + blockIdx.z partial planes.
// EPI: 0=none, 1=exact GELU, 2=C += gate*acc. OB: bf16 output.
template<int EPI, int OB>
__global__ __launch_bounds__(256)
void gemm_mfma(const u16* __restrict__ A, const u16* __restrict__ W,
               void* __restrict__ Cv, int N, int K,
               const float* __restrict__ gatep, int kchunk)
{
    constexpr int PF  = 4;                  // tiles in flight
    constexpr int LPT = 2;                  // gload insts per tile per thread
    constexpr int RD  = PF + 1;             // ring depth
    __shared__ __align__(16) u16 As[RD][64 * 32];
    __shared__ __align__(16) u16 Ws[RD][64 * 32];
    const int tid  = threadIdx.x;
    const int lane = tid & 63;
    const int wave = tid >> 6;
    const int wr = wave >> 1, wc = wave & 1;

    // XCD-aware column-chunk swizzle (all x*y grids here are multiples of 8).
    const int nwg = gridDim.x * gridDim.y;
    const int bid = blockIdx.y * gridDim.x + blockIdx.x;   // dispatch order
    const int nid = (bid & 7) * (nwg >> 3) + (bid >> 3);   // chunk per XCD
    const int by  = nid % gridDim.y;
    const int bx  = nid / gridDim.y;
    const int m0 = by * 64, n0 = bx * 64;
    const int kz = blockIdx.z * kchunk;

    // staging: thread tid -> LDS row tid>>2 (linear dest), global chunk
    // pre-swizzled so LDS[row][c] holds global[row][c ^ ((row>>1)&3)].
    const int srow = tid >> 2;
    const int scol = (((tid & 3) ^ ((srow >> 1) & 3))) * 8;
    const u16* Ag = A + (size_t)(m0 + srow) * K + scol + kz;
    const u16* Wg = W + (size_t)(n0 + srow) * K + scol + kz;

    const int fr = lane & 15;
    const int fq = lane >> 4;

    f32x4 acc[2][2] = {};

    auto stage = [&](int buf, int k0) {
        gload16(Ag + k0, &As[buf][tid * 8]);
        gload16(Wg + k0, &Ws[buf][tid * 8]);
    };
    auto compute = [&](int buf) {
        short8 a[2], b[2];
        #pragma unroll
        for (int m = 0; m < 2; ++m) {
            const int r = wr * 32 + m * 16 + fr;
            a[m] = *reinterpret_cast<const short8*>(
                &As[buf][r * 32 + ((fq ^ ((r >> 1) & 3)) << 3)]);
        }
        #pragma unroll
        for (int n = 0; n < 2; ++n) {
            const int r = wc * 32 + n * 16 + fr;
            b[n] = *reinterpret_cast<const short8*>(
                &Ws[buf][r * 32 + ((fq ^ ((r >> 1) & 3)) << 3)]);
        }
        #pragma unroll
        for (int m = 0; m < 2; ++m)
            #pragma unroll
            for (int n = 0; n < 2; ++n)
                acc[m][n] = __builtin_amdgcn_mfma_f32_16x16x32_bf16(
                    a[m], b[n], acc[m][n], 0, 0, 0);
    };

    const int nt = kchunk / 32;             // >= 16 for all shapes here
    #pragma unroll
    for (int i = 0; i < PF; ++i) stage(i, i * 32);

    int cbuf = 0, sbuf = PF;
    for (int t = 0; t <= nt - PF; ++t) {
        // tile t resident once <= (PF-1)*LPT newest loads outstanding
        asm volatile("s_waitcnt vmcnt(%0)\n\ts_barrier"
                     :: "n"((PF - 1) * LPT) : "memory");
        if (t + PF < nt) {
            stage(sbuf, (t + PF) * 32);
            if (++sbuf == RD) sbuf = 0;
        }
        compute(cbuf);
        if (++cbuf == RD) cbuf = 0;
    }
    #pragma unroll
    for (int i = 1; i < PF; ++i) {          // drain tail, compile-time waits
        asm volatile("s_waitcnt vmcnt(%0)\n\ts_barrier"
                     :: "n"((PF - 1 - i) * LPT) : "memory");
        compute(cbuf);
        if (++cbuf == RD) cbuf = 0;
    }

    // C/D layout: col = lane&15, row = (lane>>4)*4 + reg  [m89/m91 verified]
    float* Cz = (float*)Cv + (size_t)blockIdx.z * M_ROWS * N;  // split-K plane
    const float gate = (EPI == 2) ? gatep[0] : 0.f;
    #pragma unroll
    for (int m = 0; m < 2; ++m) {
        #pragma unroll
        for (int j = 0; j < 4; ++j) {
            const size_t row = (size_t)(m0 + wr * 32 + m * 16 + fq * 4 + j);
            #pragma unroll
            for (int n = 0; n < 2; ++n) {
                float v = acc[m][n][j];
                const size_t idx = row * (size_t)N + (size_t)(n0 + wc * 32 + n * 16 + fr);
                if (EPI == 1) v = 0.5f * v * (1.f + erff(v * 0.70710678118654752f));
                if (OB) {
                    ((u16*)Cv)[idx] = f2b(v);
                } else {
                    if (EPI == 2) Cz[idx] = Cz[idx] + gate * v;
                    else          Cz[idx] = v;
                }
            }
        }
    }
}

// ---------------- split-K reduce: C += gate * (p0+p1+p2+p3) ----------------
__global__ __launch_bounds__(256)
void redk(const float* __restrict__ p, const float* __restrict__ gatep,
          float* __restrict__ C)
{
    const int i = (blockIdx.x * 256 + threadIdx.x) * 4;
    const float g = gatep[0];
    const float4 a = *reinterpret_cast<const float4*>(p + i);
    const float4 b = *reinterpret_cast<const float4*>(p + 2097152 + i);
    const float4 c = *reinterpret_cast<const float4*>(p + 4194304 + i);
    const float4 d = *reinterpret_cast<const float4*>(p + 6291456 + i);
    float4 o = *reinterpret_cast<float4*>(C + i);
    o.x += g * ((a.x + b.x) + (c.x + d.x));
    o.y += g * ((a.y + b.y) + (c.y + d.y));
    o.z += g * ((a.z + b.z) + (c.z + d.z));
    o.w += g * ((a.w + b.w) + (c.w + d.w));
    *reinterpret_cast<float4*>(C + i) = o;
}

// ------------------------- MFMA fused attention ----------------------------
// grid = 256 blocks (16 qtiles x 16 bh), 256 threads = 4 waves x 16 q-rows.
// XCD head-chunk swizzle: each XCD owns 2 heads -> K/V L2-resident.
// Double-buffered K/V LDS: ONE barrier per kv-tile (write buf^1 while buf is
// read -- disjoint). T14: next tile global->reg issued before compute.
template<int OB>
__global__ __launch_bounds__(256)
void attn_mfma(const u16* __restrict__ Q, const u16* __restrict__ K,
               const u16* __restrict__ V, void* __restrict__ Ov,
               int qs, int ks, int vs, int os)
{
    __shared__ __align__(16) u16 Ks[2][64 * 72];   // [kv][d], pad 72
    __shared__ __align__(16) u16 Vt[2][64 * 72];   // [d][kv], pad 72
    __shared__ __align__(16) u16 Ps[4][16 * 72];   // per-wave P [q][kv]
    const int tid  = threadIdx.x;
    const int lane = tid & 63;
    const int wave = tid >> 6;
    const int fr = lane & 15;
    const int fq = lane >> 4;

    // head-chunk swizzle: XCD x gets nid in [x*32, x*32+32) = 2 heads
    const int bid = blockIdx.y * gridDim.x + blockIdx.x;
    const int nid = (bid & 7) * 32 + (bid >> 3);
    const int qt  = nid & 15;
    const int bh  = nid >> 4;
    const int b   = bh >> 3;
    const int hc  = (bh & 7) * 64;
    const size_t qrow0 = (size_t)b * SEQ + (size_t)qt * 64;
    const size_t krow0 = (size_t)b * SEQ;

    short8 qf[2];
    {
        const u16* qp = Q + (qrow0 + wave * 16 + fr) * qs + hc + fq * 8;
        qf[0] = *reinterpret_cast<const short8*>(qp);
        qf[1] = *reinterpret_cast<const short8*>(qp + 32);
    }

    const int skr = tid >> 2;
    const int skc = (tid & 3) * 16;
    const int svk = (tid >> 4) * 4;
    const int svd = (tid & 15) * 4;

    // register-staged next tile (T14)
    short8 kreg0, kreg1;
    ushort4 vr0, vr1, vr2, vr3;
    auto load_tile = [&](int kt) {
        const u16* kp = K + (krow0 + kt * 64 + skr) * ks + hc + skc;
        kreg0 = *reinterpret_cast<const short8*>(kp);
        kreg1 = *reinterpret_cast<const short8*>(kp + 8);
        const u16* vp = V + (krow0 + kt * 64 + svk) * vs + hc + svd;
        vr0 = *reinterpret_cast<const ushort4*>(vp);
        vr1 = *reinterpret_cast<const ushort4*>(vp + vs);
        vr2 = *reinterpret_cast<const ushort4*>(vp + 2 * (size_t)vs);
        vr3 = *reinterpret_cast<const ushort4*>(vp + 3 * (size_t)vs);
    };
    auto write_tile = [&](int bf) {
        *reinterpret_cast<short8*>(&Ks[bf][skr * 72 + skc]) = kreg0;
        *reinterpret_cast<short8*>(&Ks[bf][skr * 72 + skc + 8]) = kreg1;
        uint2 w;
        w.x = (unsigned)vr0.x | ((unsigned)vr1.x << 16);
        w.y = (unsigned)vr2.x | ((unsigned)vr3.x << 16);
        *reinterpret_cast<uint2*>(&Vt[bf][(svd + 0) * 72 + svk]) = w;
        w.x = (unsigned)vr0.y | ((unsigned)vr1.y << 16);
        w.y = (unsigned)vr2.y | ((unsigned)vr3.y << 16);
        *reinterpret_cast<uint2*>(&Vt[bf][(svd + 1) * 72 + svk]) = w;
        w.x = (unsigned)vr0.z | ((unsigned)vr1.z << 16);
        w.y = (unsigned)vr2.z | ((unsigned)vr3.z << 16);
        *reinterpret_cast<uint2*>(&Vt[bf][(svd + 2) * 72 + svk]) = w;
        w.x = (unsigned)vr0.w | ((unsigned)vr1.w << 16);
        w.y = (unsigned)vr2.w | ((unsigned)vr3.w << 16);
        *reinterpret_cast<uint2*>(&Vt[bf][(svd + 3) * 72 + svk]) = w;
    };

    float m_run = -1e30f, l_run = 0.f;
    f32x4 acc[4] = {};

    load_tile(0);
    write_tile(0);
    __syncthreads();

    constexpr int NT = SEQ / 64;
    for (int kt = 0; kt < NT; ++kt) {
        const int bf = kt & 1;
        if (kt + 1 < NT) load_tile(kt + 1);   // issue early (hidden by compute)

        f32x4 st[4] = {};
        #pragma unroll
        for (int kn = 0; kn < 4; ++kn) {
            const short8 ka0 = *reinterpret_cast<const short8*>(
                &Ks[bf][(kn * 16 + fr) * 72 + fq * 8]);
            const short8 ka1 = *reinterpret_cast<const short8*>(
                &Ks[bf][(kn * 16 + fr) * 72 + 32 + fq * 8]);
            st[kn] = __builtin_amdgcn_mfma_f32_16x16x32_bf16(ka0, qf[0], st[kn], 0, 0, 0);
            st[kn] = __builtin_amdgcn_mfma_f32_16x16x32_bf16(ka1, qf[1], st[kn], 0, 0, 0);
        }

        float mx = -1e30f;
        #pragma unroll
        for (int kn = 0; kn < 4; ++kn)
            #pragma unroll
            for (int r = 0; r < 4; ++r) {
                st[kn][r] *= 0.125f;
                mx = fmaxf(mx, st[kn][r]);
            }
        mx = fmaxf(mx, __shfl_xor(mx, 16, 64));
        mx = fmaxf(mx, __shfl_xor(mx, 32, 64));
        const float mnew = fmaxf(m_run, mx);
        const float corr = __expf(m_run - mnew);
        m_run = mnew;
        float psum = 0.f;
        #pragma unroll
        for (int kn = 0; kn < 4; ++kn) {
            const float p0 = __expf(st[kn][0] - mnew);
            const float p1 = __expf(st[kn][1] - mnew);
            const float p2 = __expf(st[kn][2] - mnew);
            const float p3 = __expf(st[kn][3] - mnew);
            psum += (p0 + p1) + (p2 + p3);
            uint2 w;
            w.x = (unsigned)f2b(p0) | ((unsigned)f2b(p1) << 16);
            w.y = (unsigned)f2b(p2) | ((unsigned)f2b(p3) << 16);
            *reinterpret_cast<uint2*>(&Ps[wave][fr * 72 + kn * 16 + fq * 4]) = w;
        }
        psum += __shfl_xor(psum, 16, 64);
        psum += __shfl_xor(psum, 32, 64);
        l_run = l_run * corr + psum;

        float cq[4];
        #pragma unroll
        for (int j = 0; j < 4; ++j) cq[j] = __shfl(corr, fq * 4 + j, 64);
        #pragma unroll
        for (int nd = 0; nd < 4; ++nd)
            #pragma unroll
            for (int j = 0; j < 4; ++j)
                acc[nd][j] *= cq[j];

        short8 pa0 = *reinterpret_cast<const short8*>(&Ps[wave][fr * 72 + fq * 8]);
        short8 pa1 = *reinterpret_cast<const short8*>(&Ps[wave][fr * 72 + 32 + fq * 8]);
        #pragma unroll
        for (int nd = 0; nd < 4; ++nd) {
            const short8 vb0 = *reinterpret_cast<const short8*>(
                &Vt[bf][(nd * 16 + fr) * 72 + fq * 8]);
            const short8 vb1 = *reinterpret_cast<const short8*>(
                &Vt[bf][(nd * 16 + fr) * 72 + 32 + fq * 8]);
            acc[nd] = __builtin_amdgcn_mfma_f32_16x16x32_bf16(pa0, vb0, acc[nd], 0, 0, 0);
            acc[nd] = __builtin_amdgcn_mfma_f32_16x16x32_bf16(pa1, vb1, acc[nd], 0, 0, 0);
        }

        // write NEXT tile into the other buffer (disjoint from current reads),
        // then a single barrier makes it visible for the next iteration.
        if (kt + 1 < NT) write_tile(bf ^ 1);
        __syncthreads();
    }

    float iq[4];
    #pragma unroll
    for (int j = 0; j < 4; ++j) iq[j] = 1.f / __shfl(l_run, fq * 4 + j, 64);
    #pragma unroll
    for (int j = 0; j < 4; ++j) {
        const size_t orow = (qrow0 + wave * 16 + fq * 4 + j) * os + hc;
        #pragma unroll
        for (int nd = 0; nd < 4; ++nd) {
            const float v = acc[nd][j] * iq[j];
            if (OB) ((u16*)Ov)[orow + nd * 16 + fr] = f2b(v);
            else    ((float*)Ov)[orow + nd * 16 + fr] = v;
        }
    }
}

// -------------------- gate mix (dot, softmax-2, blend) ---------------------
__global__ __launch_bounds__(256)
void mix_kernel(const float* __restrict__ gctx, const float* __restrict__ mixw,
                const float* __restrict__ mixb, const float* __restrict__ so,
                const float* __restrict__ co, u16* __restrict__ mixed)
{
    const size_t row = blockIdx.x;
    const float* g = gctx + row * 512;
    float d0 = 0.f, d1 = 0.f;
    for (int c = threadIdx.x; c < 512; c += 256) {
        const float gv = g[c];
        d0 = fmaf(gv, mixw[c], d0);
        d1 = fmaf(gv, mixw[512 + c], d1);
    }
    #pragma unroll
    for (int off = 32; off > 0; off >>= 1) {
        d0 += __shfl_down(d0, off);
        d1 += __shfl_down(d1, off);
    }
    __shared__ float sA[4], sB[4];
    const int wid = threadIdx.x >> 6;
    if ((threadIdx.x & 63) == 0) { sA[wid] = d0; sB[wid] = d1; }
    __syncthreads();
    const float t0 = sA[0] + sA[1] + sA[2] + sA[3] + mixb[0];
    const float t1 = sB[0] + sB[1] + sB[2] + sB[3] + mixb[1];
    const float mx = fmaxf(t0, t1);
    const float e0 = __expf(t0 - mx), e1 = __expf(t1 - mx);
    const float inv = 1.f / (e0 + e1);
    const float w0 = e0 * inv, w1 = e1 * inv;
    for (int c = threadIdx.x; c < 512; c += 256)
        mixed[row * 512 + c] = f2b(w0 * so[row * 512 + c] + w1 * co[row * 512 + c]);
}

// ---------------------------------------------------------------------------
extern "C" void kernel_launch(void* const* d_in, const int* in_sizes, int n_in,
                              void* d_out, int out_size, void* d_ws, size_t ws_size,
                              hipStream_t stream)
{
    const float* query     = (const float*)d_in[0];
    const float* kvwt      = (const float*)d_in[1];
    const float* nq_w      = (const float*)d_in[2];
    const float* nq_b      = (const float*)d_in[3];
    const float* nkv_w     = (const float*)d_in[4];
    const float* nkv_b     = (const float*)d_in[5];
    const float* wq_cross  = (const float*)d_in[6];
    const float* wkv_cross = (const float*)d_in[7];
    const float* wqkv_self = (const float*)d_in[8];
    const float* gn_w      = (const float*)d_in[9];
    const float* gn_b      = (const float*)d_in[10];
    const float* mha_in_w  = (const float*)d_in[11];
    const float* mha_out_w = (const float*)d_in[12];
    const float* mix_w     = (const float*)d_in[13];
    const float* mix_b     = (const float*)d_in[14];
    const float* w_out     = (const float*)d_in[15];
    const float* ff_ln_w   = (const float*)d_in[16];
    const float* ff_ln_b   = (const float*)d_in[17];
    const float* ff_fc1    = (const float*)d_in[18];
    const float* ff_fc2    = (const float*)d_in[19];
    const float* ff_gate   = (const float*)d_in[20];

    float* delta_out = (float*)d_out;                          // stack[0]
    float* wt_out    = (float*)d_out + (size_t)M_ROWS * 1024;  // stack[1]

    // ---- workspace layout (byte offsets; total 59,768,832 B = 57 MB) ----
    char* wsb = (char*)d_ws;
    u16*   qkv_b   = (u16*)  (wsb + 0);          // bf16 [2048,1536]
    u16*   kv_c_b  = (u16*)  (wsb + 6291456);    // bf16 [2048,1024]
    u16*   q_c_b   = (u16*)  (wsb + 10485760);   // bf16 [2048,512]
    float* cross_f = (float*)(wsb + 12582912);   // f32  [2048,512]
    float* self_f  = (float*)(wsb + 16777216);   // f32  [2048,512]
    u16*   kvn_b   = (u16*)  (wsb + 20971520);   // bf16 [2048,1024]
    u16*   qn_b    = (u16*)  (wsb + 25165824);   // bf16 [2048,1024]
    u16*   wta_b   = (u16*)  (wsb + 29360128);   // bf16 [2048,512]
    u16*   con_b   = (u16*)  (wsb + 31457280);   // bf16 [2048,512]
    // aliases (liveness audited):
    u16*   gq_b    = qkv_b;                      // [2048,512]
    u16*   gkv_b   = qkv_b + 1048576;            // [2048,1024] fused k|v
    float* gctx_f  = (float*)kv_c_b;
    u16*   gattn_b = kvn_b;
    u16*   mixed_b = kvn_b + 1048576;
    u16*   lnd_b   = qn_b;
    u16*   son_b   = wta_b;
    u16*   ffh_b   = qkv_b;                      // [2048,4096] spans 0..16.78MB
    float* part_f  = (float*)(wsb + 16777216);   // 4x[2048,1024] f32, dead region
    // bf16 weights:
    u16* wqkv_self_b = (u16*)(wsb + 33554432);
    u16* wq_cross_b  = (u16*)(wsb + 36700160);
    u16* wkv_cross_b = (u16*)(wsb + 37748736);
    u16* mha_in_b    = (u16*)(wsb + 39845888);
    u16* mha_out_b   = (u16*)(wsb + 41418752);
    u16* w_out_b     = (u16*)(wsb + 41943040);
    u16* ff_fc1_b    = (u16*)(wsb + 42991616);
    u16* ff_fc2_b    = (u16*)(wsb + 51380224);

    const dim3 blk(256);
    const dim3 attn_grid(16, 16);

    // 0. fused weight conversion (one launch, 8 segments)
    CvtPack cp;
    cp.s[0] = wqkv_self; cp.d[0] = wqkv_self_b;
    cp.s[1] = wq_cross;  cp.d[1] = wq_cross_b;
    cp.s[2] = wkv_cross; cp.d[2] = wkv_cross_b;
    cp.s[3] = mha_in_w;  cp.d[3] = mha_in_b;
    cp.s[4] = mha_out_w; cp.d[4] = mha_out_b;
    cp.s[5] = w_out;     cp.d[5] = w_out_b;
    cp.s[6] = ff_fc1;    cp.d[6] = ff_fc1_b;
    cp.s[7] = ff_fc2;    cp.d[7] = ff_fc2_b;
    cvt8_kernel<<<dim3(12800), blk, 0, stream>>>(cp);

    // 1. kvn = LN(kv_feats_wt)
    ln_bf16<<<M_ROWS, blk, 0, stream>>>(kvwt, nkv_w, nkv_b, kvn_b, 1024);
    // 2. qkv_wt = kvn @ wqkv_self^T               grid 768 (3/CU)
    gemm_mfma<0,1><<<dim3(24, 32), blk, 0, stream>>>(kvn_b, wqkv_self_b, qkv_b, 1536, 1024, nullptr, 1024);
    // 3. wt_attn (bf16 out)
    attn_mfma<1><<<attn_grid, blk, 0, stream>>>(qkv_b, qkv_b + 512, qkv_b + 1024, wta_b, 1536, 1536, 1536, 512);
    // 4. wt_out = wt_attn @ w_out^T -> stack[1]   grid 512
    gemm_mfma<0,0><<<dim3(16, 32), blk, 0, stream>>>(wta_b, w_out_b, wt_out, 1024, 512, nullptr, 512);
    // 5. qn = LN(query_feats)
    ln_bf16<<<M_ROWS, blk, 0, stream>>>(query, nq_w, nq_b, qn_b, 1024);
    // 6. q_c = qn @ wq_cross^T                    grid 256
    gemm_mfma<0,1><<<dim3(8, 32), blk, 0, stream>>>(qn_b, wq_cross_b, q_c_b, 512, 1024, nullptr, 1024);
    // 7. kv_c = kvn @ wkv_cross^T                 grid 512
    gemm_mfma<0,1><<<dim3(16, 32), blk, 0, stream>>>(kvn_b, wkv_cross_b, kv_c_b, 1024, 1024, nullptr, 1024);
    // 8. cross_out (f32 out)
    attn_mfma<0><<<attn_grid, blk, 0, stream>>>(q_c_b, kv_c_b, kv_c_b + 512, cross_f, 512, 1024, 1024, 512);
    // 9. qkv_s = qn @ wqkv_self^T                 grid 768
    gemm_mfma<0,1><<<dim3(24, 32), blk, 0, stream>>>(qn_b, wqkv_self_b, qkv_b, 1536, 1024, nullptr, 1024);
    // 10. self_out (f32 out)
    attn_mfma<0><<<attn_grid, blk, 0, stream>>>(qkv_b, qkv_b + 512, qkv_b + 1024, self_f, 1536, 1536, 1536, 512);
    // 11. son = LN(self_out; gn), con = LN(cross_out; gn)
    ln_bf16<<<M_ROWS, blk, 0, stream>>>(self_f,  gn_w, gn_b, son_b, 512);
    ln_bf16<<<M_ROWS, blk, 0, stream>>>(cross_f, gn_w, gn_b, con_b, 512);
    // 12. gq (N=512) + fused gkv (N=1024, wk|wv rows 512..1535)
    gemm_mfma<0,1><<<dim3(8, 32),  blk, 0, stream>>>(son_b, mha_in_b,           gq_b,  512,  512, nullptr, 512);
    gemm_mfma<0,1><<<dim3(16, 32), blk, 0, stream>>>(con_b, mha_in_b + 512*512, gkv_b, 1024, 512, nullptr, 512);
    // 13. gate attention (bf16 out): K = gkv[:, :512], V = gkv[:, 512:]
    attn_mfma<1><<<attn_grid, blk, 0, stream>>>(gq_b, gkv_b, gkv_b + 512, gattn_b, 512, 1024, 1024, 512);
    // 14. gate_ctx = gate_attn @ mha_out_w^T (f32 out)  grid 256
    gemm_mfma<0,0><<<dim3(8, 32), blk, 0, stream>>>(gattn_b, mha_out_b, gctx_f, 512, 512, nullptr, 512);
    // 15. mixed = softmax-gate blend (bf16 out)
    mix_kernel<<<M_ROWS, blk, 0, stream>>>(gctx_f, mix_w, mix_b, self_f, cross_f, mixed_b);
    // 16. delta = mixed @ w_out^T -> stack[0] (f32)     grid 512
    gemm_mfma<0,0><<<dim3(16, 32), blk, 0, stream>>>(mixed_b, w_out_b, delta_out, 1024, 512, nullptr, 512);
    // 17. ln_delta = LN(delta; ff_ln)
    ln_bf16<<<M_ROWS, blk, 0, stream>>>(delta_out, ff_ln_w, ff_ln_b, lnd_b, 1024);
    // 18. ffh = gelu(ln_delta @ ff_fc1^T)         grid 2048
    gemm_mfma<1,1><<<dim3(64, 32), blk, 0, stream>>>(lnd_b, ff_fc1_b, ffh_b, 4096, 1024, nullptr, 1024);
    // 19a. fc2 split-K=4 partials                 grid 2048
    gemm_mfma<0,0><<<dim3(16, 32, 4), blk, 0, stream>>>(ffh_b, ff_fc2_b, part_f, 1024, 4096, nullptr, 1024);
    // 19b. delta += gate * sum(partials)
    redk<<<dim3(2048), blk, 0, stream>>>(part_f, ff_gate, delta_out);
}

// Round 10
// 289.475 us; speedup vs baseline: 5.1983x; 1.0649x over previous
//
#include <hip/hip_runtime.h>
#include <math.h>

// ---------------------------------------------------------------------------
// GatedCrossAttention: B=2, NQ=NK=1024, QD=KVD=OD=1024, H=8, DH=64, INNER=512
// Round 10: round 9 with the qkv_s aliasing race fixed (qkv_s_b was placed
// overlapping self_f -> attention z=2 wrote its own K/V input). qkv_s now
// lives at the workspace tail (59.77..66.06 MB; ws >= 71.3 MB per round 0).
// Everything else: 128x128 fc1/fc2 (AI 64), 64x128 mid GEMMs, batched
// 3-attention launch, dual-LN fusion, PF=3 ring-4 counted-vmcnt pipeline.
// ---------------------------------------------------------------------------

#define M_ROWS 2048   // B*NQ
#define SEQ    1024

typedef unsigned short u16;
typedef __attribute__((ext_vector_type(8))) short short8;
typedef __attribute__((ext_vector_type(4))) float f32x4;

__device__ inline u16 f2b(float f) {
    unsigned u = __builtin_bit_cast(unsigned, f);
    u += 0x7FFFu + ((u >> 16) & 1u);   // round-to-nearest-even
    return (u16)(u >> 16);
}
__device__ inline float b2f(u16 h) {
    return __builtin_bit_cast(float, (unsigned)h << 16);
}

__device__ inline void gload16(const u16* g, u16* l) {
    __builtin_amdgcn_global_load_lds(
        (const __attribute__((address_space(1))) void*)g,
        (__attribute__((address_space(3))) void*)l, 16, 0, 0);
}

// ------------------- fused f32 -> bf16 weight convert -----------------------
struct CvtPack { const float* s[8]; u16* d[8]; };

__global__ __launch_bounds__(256)
void cvt8_kernel(CvtPack p)
{
    constexpr int pre[9] = {0, 1536, 2048, 3072, 3840, 4096, 4608, 8704, 12800};
    const int b = blockIdx.x;
    int seg = 0;
    #pragma unroll
    for (int i = 1; i < 8; ++i) seg += (b >= pre[i]);
    const int off = (b - pre[seg]) * 1024 + threadIdx.x * 4;
    const float4 v = *reinterpret_cast<const float4*>(p.s[seg] + off);
    ushort4 o;
    o.x = f2b(v.x); o.y = f2b(v.y); o.z = f2b(v.z); o.w = f2b(v.w);
    *reinterpret_cast<ushort4*>(p.d[seg] + off) = o;
}

// --------------------------- dual LayerNorm --------------------------------
// rows [0,2048): x0 -> out0 with (w0,b0); rows [2048,4096): x1 -> out1 (w1,b1)
__global__ __launch_bounds__(256)
void ln_dual(const float* __restrict__ x0, const float* __restrict__ w0,
             const float* __restrict__ b0, u16* __restrict__ out0,
             const float* __restrict__ x1, const float* __restrict__ w1,
             const float* __restrict__ b1, u16* __restrict__ out1, int D)
{
    const int r = blockIdx.x;
    const int sel = r >= M_ROWS;
    const size_t row = sel ? r - M_ROWS : r;
    const float* x = sel ? x1 : x0;
    const float* w = sel ? w1 : w0;
    const float* bias = sel ? b1 : b0;
    u16* out = sel ? out1 : out0;
    const float* xr = x + row * (size_t)D;
    const int c = threadIdx.x * 4;
    float4 v = make_float4(0.f, 0.f, 0.f, 0.f);
    if (c < D) v = *reinterpret_cast<const float4*>(&xr[c]);
    float sum = v.x + v.y + v.z + v.w;
    float sq  = v.x*v.x + v.y*v.y + v.z*v.z + v.w*v.w;
    #pragma unroll
    for (int off = 32; off > 0; off >>= 1) {
        sum += __shfl_down(sum, off);
        sq  += __shfl_down(sq,  off);
    }
    __shared__ float s1[4], s2[4];
    const int wid = threadIdx.x >> 6;
    if ((threadIdx.x & 63) == 0) { s1[wid] = sum; s2[wid] = sq; }
    __syncthreads();
    const float tsum = s1[0] + s1[1] + s1[2] + s1[3];
    const float tsq  = s2[0] + s2[1] + s2[2] + s2[3];
    const float mean = tsum / (float)D;
    const float var  = tsq / (float)D - mean * mean;
    const float rstd = rsqrtf(var + 1e-5f);
    if (c < D) {
        ushort4 o;
        o.x = f2b((v.x - mean) * rstd * w[c+0] + bias[c+0]);
        o.y = f2b((v.y - mean) * rstd * w[c+1] + bias[c+1]);
        o.z = f2b((v.z - mean) * rstd * w[c+2] + bias[c+2]);
        o.w = f2b((v.w - mean) * rstd * w[c+3] + bias[c+3]);
        *reinterpret_cast<ushort4*>(&out[row * (size_t)D + c]) = o;
    }
}

// single LN (for ln_delta)
__global__ __launch_bounds__(256)
void ln_bf16(const float* __restrict__ x, const float* __restrict__ w,
             const float* __restrict__ bias, u16* __restrict__ out, int D)
{
    const size_t row = blockIdx.x;
    const float* xr = x + row * (size_t)D;
    const int c = threadIdx.x * 4;
    float4 v = make_float4(0.f, 0.f, 0.f, 0.f);
    if (c < D) v = *reinterpret_cast<const float4*>(&xr[c]);
    float sum = v.x + v.y + v.z + v.w;
    float sq  = v.x*v.x + v.y*v.y + v.z*v.z + v.w*v.w;
    #pragma unroll
    for (int off = 32; off > 0; off >>= 1) {
        sum += __shfl_down(sum, off);
        sq  += __shfl_down(sq,  off);
    }
    __shared__ float s1[4], s2[4];
    const int wid = threadIdx.x >> 6;
    if ((threadIdx.x & 63) == 0) { s1[wid] = sum; s2[wid] = sq; }
    __syncthreads();
    const float tsum = s1[0] + s1[1] + s1[2] + s1[3];
    const float tsq  = s2[0] + s2[1] + s2[2] + s2[3];
    const float mean = tsum / (float)D;
    const float var  = tsq / (float)D - mean * mean;
    const float rstd = rsqrtf(var + 1e-5f);
    if (c < D) {
        ushort4 o;
        o.x = f2b((v.x - mean) * rstd * w[c+0] + bias[c+0]);
        o.y = f2b((v.y - mean) * rstd * w[c+1] + bias[c+1]);
        o.z = f2b((v.z - mean) * rstd * w[c+2] + bias[c+2]);
        o.w = f2b((v.w - mean) * rstd * w[c+3] + bias[c+3]);
        *reinterpret_cast<ushort4*>(&out[row * (size_t)D + c]) = o;
    }
}

// ------------------------------ MFMA GEMM ----------------------------------
// C[M,N] = A[M,K]*W[N,K]^T, bf16 in, f32 acc. Tile BM x BN, BK=32, 4 waves
// (2x2), PF=3 / ring-4. Counted vmcnt (never 0 in steady loop), compile-time
// tail drain. Chunk swizzle (linear gload dest + swizzled source + swizzled
// ds_read): conflict-free. Split-K via kchunk + blockIdx.z planes.
// EPI: 0=none, 1=exact GELU, 2=C += gate*acc. OB: bf16 output.
template<int BM, int BN, int EPI, int OB>
__global__ __launch_bounds__(256)
void gemm_mfma(const u16* __restrict__ A, const u16* __restrict__ W,
               void* __restrict__ Cv, int N, int K,
               const float* __restrict__ gatep, int kchunk)
{
    constexpr int MF  = BM / 32;
    constexpr int NF  = BN / 32;
    constexpr int LPT = BM / 64 + BN / 64;  // gloads per tile per thread
    constexpr int PF  = 3;
    constexpr int RD  = 4;
    __shared__ __align__(16) u16 As[RD][BM * 32];
    __shared__ __align__(16) u16 Ws[RD][BN * 32];
    const int tid  = threadIdx.x;
    const int lane = tid & 63;
    const int wave = tid >> 6;
    const int wr = wave >> 1, wc = wave & 1;

    // XCD-aware column-chunk swizzle (x*y grids here are multiples of 8)
    const int nwg = gridDim.x * gridDim.y;
    const int bid = blockIdx.y * gridDim.x + blockIdx.x;
    const int nid = (bid & 7) * (nwg >> 3) + (bid >> 3);
    const int by  = nid % gridDim.y;
    const int bx  = nid / gridDim.y;
    const int m0 = by * BM, n0 = bx * BN;
    const int kz = blockIdx.z * kchunk;

    const int srow = tid >> 2;
    const int scol = (((tid & 3) ^ ((srow >> 1) & 3))) * 8;
    const u16* Ag = A + (size_t)(m0 + srow) * K + scol + kz;
    const u16* Wg = W + (size_t)(n0 + srow) * K + scol + kz;

    const int fr = lane & 15;
    const int fq = lane >> 4;

    f32x4 acc[MF][NF] = {};

    auto stage = [&](int buf, int k0) {
        #pragma unroll
        for (int i = 0; i < BM / 64; ++i)
            gload16(Ag + k0 + (size_t)(i * 64) * K, &As[buf][tid * 8 + i * 2048]);
        #pragma unroll
        for (int i = 0; i < BN / 64; ++i)
            gload16(Wg + k0 + (size_t)(i * 64) * K, &Ws[buf][tid * 8 + i * 2048]);
    };
    auto compute = [&](int buf) {
        short8 a[MF], b[NF];
        #pragma unroll
        for (int m = 0; m < MF; ++m) {
            const int r = wr * (BM / 2) + m * 16 + fr;
            a[m] = *reinterpret_cast<const short8*>(
                &As[buf][r * 32 + ((fq ^ ((r >> 1) & 3)) << 3)]);
        }
        #pragma unroll
        for (int n = 0; n < NF; ++n) {
            const int r = wc * (BN / 2) + n * 16 + fr;
            b[n] = *reinterpret_cast<const short8*>(
                &Ws[buf][r * 32 + ((fq ^ ((r >> 1) & 3)) << 3)]);
        }
        #pragma unroll
        for (int m = 0; m < MF; ++m)
            #pragma unroll
            for (int n = 0; n < NF; ++n)
                acc[m][n] = __builtin_amdgcn_mfma_f32_16x16x32_bf16(
                    a[m], b[n], acc[m][n], 0, 0, 0);
    };

    const int nt = kchunk / 32;
    #pragma unroll
    for (int i = 0; i < PF; ++i) stage(i, i * 32);

    int cbuf = 0, sbuf = PF;
    for (int t = 0; t <= nt - PF; ++t) {
        asm volatile("s_waitcnt vmcnt(%0)\n\ts_barrier"
                     :: "n"((PF - 1) * LPT) : "memory");
        if (t + PF < nt) {
            stage(sbuf, (t + PF) * 32);
            if (++sbuf == RD) sbuf = 0;
        }
        compute(cbuf);
        if (++cbuf == RD) cbuf = 0;
    }
    #pragma unroll
    for (int i = 1; i < PF; ++i) {
        asm volatile("s_waitcnt vmcnt(%0)\n\ts_barrier"
                     :: "n"((PF - 1 - i) * LPT) : "memory");
        compute(cbuf);
        if (++cbuf == RD) cbuf = 0;
    }

    // C/D layout: col = lane&15, row = (lane>>4)*4 + reg  [m89/m91 verified]
    float* Cz = (float*)Cv + (size_t)blockIdx.z * M_ROWS * N;
    const float gate = (EPI == 2) ? gatep[0] : 0.f;
    #pragma unroll
    for (int m = 0; m < MF; ++m) {
        #pragma unroll
        for (int j = 0; j < 4; ++j) {
            const size_t row = (size_t)(m0 + wr * (BM / 2) + m * 16 + fq * 4 + j);
            #pragma unroll
            for (int n = 0; n < NF; ++n) {
                float v = acc[m][n][j];
                const size_t idx = row * (size_t)N + (size_t)(n0 + wc * (BN / 2) + n * 16 + fr);
                if (EPI == 1) v = 0.5f * v * (1.f + erff(v * 0.70710678118654752f));
                if (OB) {
                    ((u16*)Cv)[idx] = f2b(v);
                } else {
                    if (EPI == 2) Cz[idx] = Cz[idx] + gate * v;
                    else          Cz[idx] = v;
                }
            }
        }
    }
}

// ---------------- split-K reduce: C += gate * (p0+p1+p2+p3) ----------------
__global__ __launch_bounds__(256)
void redk(const float* __restrict__ p, const float* __restrict__ gatep,
          float* __restrict__ C)
{
    const int i = (blockIdx.x * 256 + threadIdx.x) * 4;
    const float g = gatep[0];
    const float4 a = *reinterpret_cast<const float4*>(p + i);
    const float4 b = *reinterpret_cast<const float4*>(p + 2097152 + i);
    const float4 c = *reinterpret_cast<const float4*>(p + 4194304 + i);
    const float4 d = *reinterpret_cast<const float4*>(p + 6291456 + i);
    float4 o = *reinterpret_cast<float4*>(C + i);
    o.x += g * ((a.x + b.x) + (c.x + d.x));
    o.y += g * ((a.y + b.y) + (c.y + d.y));
    o.z += g * ((a.z + b.z) + (c.z + d.z));
    o.w += g * ((a.w + b.w) + (c.w + d.w));
    *reinterpret_cast<float4*>(C + i) = o;
}

// ------------------------- MFMA fused attention ----------------------------
// Batched: grid (16, 16, NP); blockIdx.z selects problem from AttnPack.
// 256 threads = 4 waves x 16 q-rows. XCD head-chunk swizzle per z-slice.
// Double-buffered K/V LDS (1 barrier/kv-tile); T14 reg-staged next tile.
struct AttnPack {
    const u16* Q[3]; const u16* K[3]; const u16* V[3]; void* O[3];
    int qs[3], ks[3], vs[3], os[3], ob[3];
};

__global__ __launch_bounds__(256)
void attn_mfma(AttnPack p)
{
    const int z = blockIdx.z;
    const u16* __restrict__ Q = p.Q[z];
    const u16* __restrict__ K = p.K[z];
    const u16* __restrict__ V = p.V[z];
    void* __restrict__ Ov = p.O[z];
    const int qs = p.qs[z], ks = p.ks[z], vs = p.vs[z], os = p.os[z];
    const int ob = p.ob[z];

    __shared__ __align__(16) u16 Ks[2][64 * 72];   // [kv][d], pad 72
    __shared__ __align__(16) u16 Vt[2][64 * 72];   // [d][kv], pad 72
    __shared__ __align__(16) u16 Ps[4][16 * 72];   // per-wave P [q][kv]
    const int tid  = threadIdx.x;
    const int lane = tid & 63;
    const int wave = tid >> 6;
    const int fr = lane & 15;
    const int fq = lane >> 4;

    // head-chunk swizzle: XCD x gets nid in [x*32, x*32+32) = 2 heads
    const int bid = blockIdx.y * gridDim.x + blockIdx.x;
    const int nid = (bid & 7) * 32 + (bid >> 3);
    const int qt  = nid & 15;
    const int bh  = nid >> 4;
    const int b   = bh >> 3;
    const int hc  = (bh & 7) * 64;
    const size_t qrow0 = (size_t)b * SEQ + (size_t)qt * 64;
    const size_t krow0 = (size_t)b * SEQ;

    short8 qf[2];
    {
        const u16* qp = Q + (qrow0 + wave * 16 + fr) * qs + hc + fq * 8;
        qf[0] = *reinterpret_cast<const short8*>(qp);
        qf[1] = *reinterpret_cast<const short8*>(qp + 32);
    }

    const int skr = tid >> 2;
    const int skc = (tid & 3) * 16;
    const int svk = (tid >> 4) * 4;
    const int svd = (tid & 15) * 4;

    short8 kreg0, kreg1;
    ushort4 vr0, vr1, vr2, vr3;
    auto load_tile = [&](int kt) {
        const u16* kp = K + (krow0 + kt * 64 + skr) * ks + hc + skc;
        kreg0 = *reinterpret_cast<const short8*>(kp);
        kreg1 = *reinterpret_cast<const short8*>(kp + 8);
        const u16* vp = V + (krow0 + kt * 64 + svk) * vs + hc + svd;
        vr0 = *reinterpret_cast<const ushort4*>(vp);
        vr1 = *reinterpret_cast<const ushort4*>(vp + vs);
        vr2 = *reinterpret_cast<const ushort4*>(vp + 2 * (size_t)vs);
        vr3 = *reinterpret_cast<const ushort4*>(vp + 3 * (size_t)vs);
    };
    auto write_tile = [&](int bf) {
        *reinterpret_cast<short8*>(&Ks[bf][skr * 72 + skc]) = kreg0;
        *reinterpret_cast<short8*>(&Ks[bf][skr * 72 + skc + 8]) = kreg1;
        uint2 w;
        w.x = (unsigned)vr0.x | ((unsigned)vr1.x << 16);
        w.y = (unsigned)vr2.x | ((unsigned)vr3.x << 16);
        *reinterpret_cast<uint2*>(&Vt[bf][(svd + 0) * 72 + svk]) = w;
        w.x = (unsigned)vr0.y | ((unsigned)vr1.y << 16);
        w.y = (unsigned)vr2.y | ((unsigned)vr3.y << 16);
        *reinterpret_cast<uint2*>(&Vt[bf][(svd + 1) * 72 + svk]) = w;
        w.x = (unsigned)vr0.z | ((unsigned)vr1.z << 16);
        w.y = (unsigned)vr2.z | ((unsigned)vr3.z << 16);
        *reinterpret_cast<uint2*>(&Vt[bf][(svd + 2) * 72 + svk]) = w;
        w.x = (unsigned)vr0.w | ((unsigned)vr1.w << 16);
        w.y = (unsigned)vr2.w | ((unsigned)vr3.w << 16);
        *reinterpret_cast<uint2*>(&Vt[bf][(svd + 3) * 72 + svk]) = w;
    };

    float m_run = -1e30f, l_run = 0.f;
    f32x4 acc[4] = {};

    load_tile(0);
    write_tile(0);
    __syncthreads();

    constexpr int NT = SEQ / 64;
    for (int kt = 0; kt < NT; ++kt) {
        const int bf = kt & 1;
        if (kt + 1 < NT) load_tile(kt + 1);

        f32x4 st[4] = {};
        #pragma unroll
        for (int kn = 0; kn < 4; ++kn) {
            const short8 ka0 = *reinterpret_cast<const short8*>(
                &Ks[bf][(kn * 16 + fr) * 72 + fq * 8]);
            const short8 ka1 = *reinterpret_cast<const short8*>(
                &Ks[bf][(kn * 16 + fr) * 72 + 32 + fq * 8]);
            st[kn] = __builtin_amdgcn_mfma_f32_16x16x32_bf16(ka0, qf[0], st[kn], 0, 0, 0);
            st[kn] = __builtin_amdgcn_mfma_f32_16x16x32_bf16(ka1, qf[1], st[kn], 0, 0, 0);
        }

        float mx = -1e30f;
        #pragma unroll
        for (int kn = 0; kn < 4; ++kn)
            #pragma unroll
            for (int r = 0; r < 4; ++r) {
                st[kn][r] *= 0.125f;
                mx = fmaxf(mx, st[kn][r]);
            }
        mx = fmaxf(mx, __shfl_xor(mx, 16, 64));
        mx = fmaxf(mx, __shfl_xor(mx, 32, 64));
        const float mnew = fmaxf(m_run, mx);
        const float corr = __expf(m_run - mnew);
        m_run = mnew;
        float psum = 0.f;
        #pragma unroll
        for (int kn = 0; kn < 4; ++kn) {
            const float p0 = __expf(st[kn][0] - mnew);
            const float p1 = __expf(st[kn][1] - mnew);
            const float p2 = __expf(st[kn][2] - mnew);
            const float p3 = __expf(st[kn][3] - mnew);
            psum += (p0 + p1) + (p2 + p3);
            uint2 w;
            w.x = (unsigned)f2b(p0) | ((unsigned)f2b(p1) << 16);
            w.y = (unsigned)f2b(p2) | ((unsigned)f2b(p3) << 16);
            *reinterpret_cast<uint2*>(&Ps[wave][fr * 72 + kn * 16 + fq * 4]) = w;
        }
        psum += __shfl_xor(psum, 16, 64);
        psum += __shfl_xor(psum, 32, 64);
        l_run = l_run * corr + psum;

        float cq[4];
        #pragma unroll
        for (int j = 0; j < 4; ++j) cq[j] = __shfl(corr, fq * 4 + j, 64);
        #pragma unroll
        for (int nd = 0; nd < 4; ++nd)
            #pragma unroll
            for (int j = 0; j < 4; ++j)
                acc[nd][j] *= cq[j];

        short8 pa0 = *reinterpret_cast<const short8*>(&Ps[wave][fr * 72 + fq * 8]);
        short8 pa1 = *reinterpret_cast<const short8*>(&Ps[wave][fr * 72 + 32 + fq * 8]);
        #pragma unroll
        for (int nd = 0; nd < 4; ++nd) {
            const short8 vb0 = *reinterpret_cast<const short8*>(
                &Vt[bf][(nd * 16 + fr) * 72 + fq * 8]);
            const short8 vb1 = *reinterpret_cast<const short8*>(
                &Vt[bf][(nd * 16 + fr) * 72 + 32 + fq * 8]);
            acc[nd] = __builtin_amdgcn_mfma_f32_16x16x32_bf16(pa0, vb0, acc[nd], 0, 0, 0);
            acc[nd] = __builtin_amdgcn_mfma_f32_16x16x32_bf16(pa1, vb1, acc[nd], 0, 0, 0);
        }

        if (kt + 1 < NT) write_tile(bf ^ 1);
        __syncthreads();
    }

    float iq[4];
    #pragma unroll
    for (int j = 0; j < 4; ++j) iq[j] = 1.f / __shfl(l_run, fq * 4 + j, 64);
    #pragma unroll
    for (int j = 0; j < 4; ++j) {
        const size_t orow = (qrow0 + wave * 16 + fq * 4 + j) * os + hc;
        #pragma unroll
        for (int nd = 0; nd < 4; ++nd) {
            const float v = acc[nd][j] * iq[j];
            if (ob) ((u16*)Ov)[orow + nd * 16 + fr] = f2b(v);
            else    ((float*)Ov)[orow + nd * 16 + fr] = v;
        }
    }
}

// -------------------- gate mix (dot, softmax-2, blend) ---------------------
__global__ __launch_bounds__(256)
void mix_kernel(const float* __restrict__ gctx, const float* __restrict__ mixw,
                const float* __restrict__ mixb, const float* __restrict__ so,
                const float* __restrict__ co, u16* __restrict__ mixed)
{
    const size_t row = blockIdx.x;
    const float* g = gctx + row * 512;
    float d0 = 0.f, d1 = 0.f;
    for (int c = threadIdx.x; c < 512; c += 256) {
        const float gv = g[c];
        d0 = fmaf(gv, mixw[c], d0);
        d1 = fmaf(gv, mixw[512 + c], d1);
    }
    #pragma unroll
    for (int off = 32; off > 0; off >>= 1) {
        d0 += __shfl_down(d0, off);
        d1 += __shfl_down(d1, off);
    }
    __shared__ float sA[4], sB[4];
    const int wid = threadIdx.x >> 6;
    if ((threadIdx.x & 63) == 0) { sA[wid] = d0; sB[wid] = d1; }
    __syncthreads();
    const float t0 = sA[0] + sA[1] + sA[2] + sA[3] + mixb[0];
    const float t1 = sB[0] + sB[1] + sB[2] + sB[3] + mixb[1];
    const float mx = fmaxf(t0, t1);
    const float e0 = __expf(t0 - mx), e1 = __expf(t1 - mx);
    const float inv = 1.f / (e0 + e1);
    const float w0 = e0 * inv, w1 = e1 * inv;
    for (int c = threadIdx.x; c < 512; c += 256)
        mixed[row * 512 + c] = f2b(w0 * so[row * 512 + c] + w1 * co[row * 512 + c]);
}

// ---------------------------------------------------------------------------
extern "C" void kernel_launch(void* const* d_in, const int* in_sizes, int n_in,
                              void* d_out, int out_size, void* d_ws, size_t ws_size,
                              hipStream_t stream)
{
    const float* query     = (const float*)d_in[0];
    const float* kvwt      = (const float*)d_in[1];
    const float* nq_w      = (const float*)d_in[2];
    const float* nq_b      = (const float*)d_in[3];
    const float* nkv_w     = (const float*)d_in[4];
    const float* nkv_b     = (const float*)d_in[5];
    const float* wq_cross  = (const float*)d_in[6];
    const float* wkv_cross = (const float*)d_in[7];
    const float* wqkv_self = (const float*)d_in[8];
    const float* gn_w      = (const float*)d_in[9];
    const float* gn_b      = (const float*)d_in[10];
    const float* mha_in_w  = (const float*)d_in[11];
    const float* mha_out_w = (const float*)d_in[12];
    const float* mix_w     = (const float*)d_in[13];
    const float* mix_b     = (const float*)d_in[14];
    const float* w_out     = (const float*)d_in[15];
    const float* ff_ln_w   = (const float*)d_in[16];
    const float* ff_ln_b   = (const float*)d_in[17];
    const float* ff_fc1    = (const float*)d_in[18];
    const float* ff_fc2    = (const float*)d_in[19];
    const float* ff_gate   = (const float*)d_in[20];

    float* delta_out = (float*)d_out;                          // stack[0]
    float* wt_out    = (float*)d_out + (size_t)M_ROWS * 1024;  // stack[1]

    // ---- workspace layout (byte offsets; high-water 66,060,288 B < 71.3 MB
    // proven available in round 0) ----
    char* wsb = (char*)d_ws;
    u16*   qkv_b   = (u16*)  (wsb + 0);          // bf16 [2048,1536]
    u16*   kv_c_b  = (u16*)  (wsb + 6291456);    // bf16 [2048,1024]
    u16*   q_c_b   = (u16*)  (wsb + 10485760);   // bf16 [2048,512]
    float* cross_f = (float*)(wsb + 12582912);   // f32  [2048,512]
    float* self_f  = (float*)(wsb + 16777216);   // f32  [2048,512]
    u16*   kvn_b   = (u16*)  (wsb + 20971520);   // bf16 [2048,1024]
    u16*   qn_b    = (u16*)  (wsb + 25165824);   // bf16 [2048,1024]
    u16*   wta_b   = (u16*)  (wsb + 29360128);   // bf16 [2048,512]
    u16*   con_b   = (u16*)  (wsb + 31457280);   // bf16 [2048,512]
    // aliases (liveness audited):
    u16*   gq_b    = qkv_b;                      // [2048,512]
    u16*   gkv_b   = qkv_b + 1048576;            // [2048,1024] fused k|v
    float* gctx_f  = (float*)kv_c_b;
    u16*   gattn_b = kvn_b;
    u16*   mixed_b = kvn_b + 1048576;
    u16*   lnd_b   = qn_b;
    u16*   son_b   = wta_b;
    u16*   ffh_b   = qkv_b;                      // [2048,4096] spans 0..16.78MB
    float* part_f  = (float*)(wsb + 16777216);   // 4x[2048,1024] f32; planes
                                                 // overlap only step-19-dead data
    // qkv_s: workspace TAIL — disjoint from everything (fix for r9 race where
    // it overlapped self_f, attention z=2's own output).
    u16*   qkv_s_b = (u16*)  (wsb + 59768832);   // bf16 [2048,1536], ..66060288
    // bf16 weights:
    u16* wqkv_self_b = (u16*)(wsb + 33554432);
    u16* wq_cross_b  = (u16*)(wsb + 36700160);
    u16* wkv_cross_b = (u16*)(wsb + 37748736);
    u16* mha_in_b    = (u16*)(wsb + 39845888);
    u16* mha_out_b   = (u16*)(wsb + 41418752);
    u16* w_out_b     = (u16*)(wsb + 41943040);
    u16* ff_fc1_b    = (u16*)(wsb + 42991616);
    u16* ff_fc2_b    = (u16*)(wsb + 51380224);

    const dim3 blk(256);

    // 0. fused weight conversion
    CvtPack cp;
    cp.s[0] = wqkv_self; cp.d[0] = wqkv_self_b;
    cp.s[1] = wq_cross;  cp.d[1] = wq_cross_b;
    cp.s[2] = wkv_cross; cp.d[2] = wkv_cross_b;
    cp.s[3] = mha_in_w;  cp.d[3] = mha_in_b;
    cp.s[4] = mha_out_w; cp.d[4] = mha_out_b;
    cp.s[5] = w_out;     cp.d[5] = w_out_b;
    cp.s[6] = ff_fc1;    cp.d[6] = ff_fc1_b;
    cp.s[7] = ff_fc2;    cp.d[7] = ff_fc2_b;
    cvt8_kernel<<<dim3(12800), blk, 0, stream>>>(cp);

    // 1+5. kvn = LN(kv_feats_wt), qn = LN(query) — one launch
    ln_dual<<<dim3(2 * M_ROWS), blk, 0, stream>>>(
        kvwt, nkv_w, nkv_b, kvn_b, query, nq_w, nq_b, qn_b, 1024);

    // 2,6,7,9: all four projection GEMMs (independent)
    gemm_mfma<64,128,0,1><<<dim3(12, 32), blk, 0, stream>>>(kvn_b, wqkv_self_b, qkv_b, 1536, 1024, nullptr, 1024);
    gemm_mfma<64,64,0,1><<<dim3(8, 32), blk, 0, stream>>>(qn_b, wq_cross_b, q_c_b, 512, 1024, nullptr, 1024);
    gemm_mfma<64,128,0,1><<<dim3(8, 32), blk, 0, stream>>>(kvn_b, wkv_cross_b, kv_c_b, 1024, 1024, nullptr, 1024);
    gemm_mfma<64,128,0,1><<<dim3(12, 32), blk, 0, stream>>>(qn_b, wqkv_self_b, qkv_s_b, 1536, 1024, nullptr, 1024);

    // 3,8,10: three attentions in ONE launch (grid.z = 3 -> 3 blocks/CU)
    AttnPack ap;
    ap.Q[0] = qkv_b;    ap.K[0] = qkv_b + 512;    ap.V[0] = qkv_b + 1024;    ap.O[0] = wta_b;
    ap.qs[0] = 1536; ap.ks[0] = 1536; ap.vs[0] = 1536; ap.os[0] = 512; ap.ob[0] = 1;
    ap.Q[1] = q_c_b;    ap.K[1] = kv_c_b;         ap.V[1] = kv_c_b + 512;    ap.O[1] = cross_f;
    ap.qs[1] = 512;  ap.ks[1] = 1024; ap.vs[1] = 1024; ap.os[1] = 512; ap.ob[1] = 0;
    ap.Q[2] = qkv_s_b;  ap.K[2] = qkv_s_b + 512;  ap.V[2] = qkv_s_b + 1024;  ap.O[2] = self_f;
    ap.qs[2] = 1536; ap.ks[2] = 1536; ap.vs[2] = 1536; ap.os[2] = 512; ap.ob[2] = 0;
    attn_mfma<<<dim3(16, 16, 3), blk, 0, stream>>>(ap);

    // 4. wt_out = wt_attn @ w_out^T -> stack[1]
    gemm_mfma<64,128,0,0><<<dim3(8, 32), blk, 0, stream>>>(wta_b, w_out_b, wt_out, 1024, 512, nullptr, 512);
    // 11. son = LN(self; gn), con = LN(cross; gn) — one launch
    ln_dual<<<dim3(2 * M_ROWS), blk, 0, stream>>>(
        self_f, gn_w, gn_b, son_b, cross_f, gn_w, gn_b, con_b, 512);
    // 12. gq + fused gkv
    gemm_mfma<64,64,0,1><<<dim3(8, 32),  blk, 0, stream>>>(son_b, mha_in_b,           gq_b,  512,  512, nullptr, 512);
    gemm_mfma<64,128,0,1><<<dim3(8, 32), blk, 0, stream>>>(con_b, mha_in_b + 512*512, gkv_b, 1024, 512, nullptr, 512);
    // 13. gate attention (single problem, z=1)
    AttnPack gp;
    gp.Q[0] = gq_b; gp.K[0] = gkv_b; gp.V[0] = gkv_b + 512; gp.O[0] = gattn_b;
    gp.qs[0] = 512; gp.ks[0] = 1024; gp.vs[0] = 1024; gp.os[0] = 512; gp.ob[0] = 1;
    gp.Q[1] = gp.Q[0]; gp.K[1] = gp.K[0]; gp.V[1] = gp.V[0]; gp.O[1] = gp.O[0];
    gp.qs[1] = 512; gp.ks[1] = 1024; gp.vs[1] = 1024; gp.os[1] = 512; gp.ob[1] = 1;
    gp.Q[2] = gp.Q[0]; gp.K[2] = gp.K[0]; gp.V[2] = gp.V[0]; gp.O[2] = gp.O[0];
    gp.qs[2] = 512; gp.ks[2] = 1024; gp.vs[2] = 1024; gp.os[2] = 512; gp.ob[2] = 1;
    attn_mfma<<<dim3(16, 16, 1), blk, 0, stream>>>(gp);
    // 14. gate_ctx = gate_attn @ mha_out_w^T (f32 out)
    gemm_mfma<64,64,0,0><<<dim3(8, 32), blk, 0, stream>>>(gattn_b, mha_out_b, gctx_f, 512, 512, nullptr, 512);
    // 15. mixed = softmax-gate blend (bf16 out)
    mix_kernel<<<dim3(M_ROWS), blk, 0, stream>>>(gctx_f, mix_w, mix_b, self_f, cross_f, mixed_b);
    // 16. delta = mixed @ w_out^T -> stack[0] (f32)
    gemm_mfma<64,128,0,0><<<dim3(8, 32), blk, 0, stream>>>(mixed_b, w_out_b, delta_out, 1024, 512, nullptr, 512);
    // 17. ln_delta = LN(delta; ff_ln)
    ln_bf16<<<dim3(M_ROWS), blk, 0, stream>>>(delta_out, ff_ln_w, ff_ln_b, lnd_b, 1024);
    // 18. ffh = gelu(ln_delta @ ff_fc1^T)   128x128, grid 512 (2/CU), AI=64
    gemm_mfma<128,128,1,1><<<dim3(32, 16), blk, 0, stream>>>(lnd_b, ff_fc1_b, ffh_b, 4096, 1024, nullptr, 1024);
    // 19a. fc2 split-K=4 partials           128x128, grid 512
    gemm_mfma<128,128,0,0><<<dim3(8, 16, 4), blk, 0, stream>>>(ffh_b, ff_fc2_b, part_f, 1024, 4096, nullptr, 1024);
    // 19b. delta += gate * sum(partials)
    redk<<<dim3(2048), blk, 0, stream>>>(part_f, ff_gate, delta_out);
}

// Round 11
// 283.423 us; speedup vs baseline: 5.3092x; 1.0214x over previous
//
#include <hip/hip_runtime.h>
#include <math.h>

// ---------------------------------------------------------------------------
// GatedCrossAttention: B=2, NQ=NK=1024, QD=KVD=OD=1024, H=8, DH=64, INNER=512
// Round 11: concurrency model (per-block delivery latency-capped ~10 B/cyc;
// per-CU = blocks/CU x cap): fc1/fc2 back to 64x64 many-block configs;
// problem index interleaved into FAST dispatch bits (z was slowest -> no
// co-residency); 4 projection GEMMs batched (2304 blocks); gq/gk/gv batched.
// ---------------------------------------------------------------------------

#define M_ROWS 2048   // B*NQ
#define SEQ    1024

typedef unsigned short u16;
typedef __attribute__((ext_vector_type(8))) short short8;
typedef __attribute__((ext_vector_type(4))) float f32x4;

__device__ inline u16 f2b(float f) {
    unsigned u = __builtin_bit_cast(unsigned, f);
    u += 0x7FFFu + ((u >> 16) & 1u);   // round-to-nearest-even
    return (u16)(u >> 16);
}
__device__ inline float b2f(u16 h) {
    return __builtin_bit_cast(float, (unsigned)h << 16);
}

__device__ inline void gload16(const u16* g, u16* l) {
    __builtin_amdgcn_global_load_lds(
        (const __attribute__((address_space(1))) void*)g,
        (__attribute__((address_space(3))) void*)l, 16, 0, 0);
}

// ------------------- fused f32 -> bf16 weight convert -----------------------
struct CvtPack { const float* s[8]; u16* d[8]; };

__global__ __launch_bounds__(256)
void cvt8_kernel(CvtPack p)
{
    constexpr int pre[9] = {0, 1536, 2048, 3072, 3840, 4096, 4608, 8704, 12800};
    const int b = blockIdx.x;
    int seg = 0;
    #pragma unroll
    for (int i = 1; i < 8; ++i) seg += (b >= pre[i]);
    const int off = (b - pre[seg]) * 1024 + threadIdx.x * 4;
    const float4 v = *reinterpret_cast<const float4*>(p.s[seg] + off);
    ushort4 o;
    o.x = f2b(v.x); o.y = f2b(v.y); o.z = f2b(v.z); o.w = f2b(v.w);
    *reinterpret_cast<ushort4*>(p.d[seg] + off) = o;
}

// --------------------------- dual LayerNorm --------------------------------
__global__ __launch_bounds__(256)
void ln_dual(const float* __restrict__ x0, const float* __restrict__ w0,
             const float* __restrict__ b0, u16* __restrict__ out0,
             const float* __restrict__ x1, const float* __restrict__ w1,
             const float* __restrict__ b1, u16* __restrict__ out1, int D)
{
    const int r = blockIdx.x;
    const int sel = r >= M_ROWS;
    const size_t row = sel ? r - M_ROWS : r;
    const float* x = sel ? x1 : x0;
    const float* w = sel ? w1 : w0;
    const float* bias = sel ? b1 : b0;
    u16* out = sel ? out1 : out0;
    const float* xr = x + row * (size_t)D;
    const int c = threadIdx.x * 4;
    float4 v = make_float4(0.f, 0.f, 0.f, 0.f);
    if (c < D) v = *reinterpret_cast<const float4*>(&xr[c]);
    float sum = v.x + v.y + v.z + v.w;
    float sq  = v.x*v.x + v.y*v.y + v.z*v.z + v.w*v.w;
    #pragma unroll
    for (int off = 32; off > 0; off >>= 1) {
        sum += __shfl_down(sum, off);
        sq  += __shfl_down(sq,  off);
    }
    __shared__ float s1[4], s2[4];
    const int wid = threadIdx.x >> 6;
    if ((threadIdx.x & 63) == 0) { s1[wid] = sum; s2[wid] = sq; }
    __syncthreads();
    const float tsum = s1[0] + s1[1] + s1[2] + s1[3];
    const float tsq  = s2[0] + s2[1] + s2[2] + s2[3];
    const float mean = tsum / (float)D;
    const float var  = tsq / (float)D - mean * mean;
    const float rstd = rsqrtf(var + 1e-5f);
    if (c < D) {
        ushort4 o;
        o.x = f2b((v.x - mean) * rstd * w[c+0] + bias[c+0]);
        o.y = f2b((v.y - mean) * rstd * w[c+1] + bias[c+1]);
        o.z = f2b((v.z - mean) * rstd * w[c+2] + bias[c+2]);
        o.w = f2b((v.w - mean) * rstd * w[c+3] + bias[c+3]);
        *reinterpret_cast<ushort4*>(&out[row * (size_t)D + c]) = o;
    }
}

__global__ __launch_bounds__(256)
void ln_bf16(const float* __restrict__ x, const float* __restrict__ w,
             const float* __restrict__ bias, u16* __restrict__ out, int D)
{
    const size_t row = blockIdx.x;
    const float* xr = x + row * (size_t)D;
    const int c = threadIdx.x * 4;
    float4 v = make_float4(0.f, 0.f, 0.f, 0.f);
    if (c < D) v = *reinterpret_cast<const float4*>(&xr[c]);
    float sum = v.x + v.y + v.z + v.w;
    float sq  = v.x*v.x + v.y*v.y + v.z*v.z + v.w*v.w;
    #pragma unroll
    for (int off = 32; off > 0; off >>= 1) {
        sum += __shfl_down(sum, off);
        sq  += __shfl_down(sq,  off);
    }
    __shared__ float s1[4], s2[4];
    const int wid = threadIdx.x >> 6;
    if ((threadIdx.x & 63) == 0) { s1[wid] = sum; s2[wid] = sq; }
    __syncthreads();
    const float tsum = s1[0] + s1[1] + s1[2] + s1[3];
    const float tsq  = s2[0] + s2[1] + s2[2] + s2[3];
    const float mean = tsum / (float)D;
    const float var  = tsq / (float)D - mean * mean;
    const float rstd = rsqrtf(var + 1e-5f);
    if (c < D) {
        ushort4 o;
        o.x = f2b((v.x - mean) * rstd * w[c+0] + bias[c+0]);
        o.y = f2b((v.y - mean) * rstd * w[c+1] + bias[c+1]);
        o.z = f2b((v.z - mean) * rstd * w[c+2] + bias[c+2]);
        o.w = f2b((v.w - mean) * rstd * w[c+3] + bias[c+3]);
        *reinterpret_cast<ushort4*>(&out[row * (size_t)D + c]) = o;
    }
}

// --------------------- shared 64x64 GEMM core (device) ----------------------
// C[M,N] = A[M,K]*W[N,K]^T for one 64x64 tile at (m0,n0). bf16 in, f32 acc,
// bf16 out, no epilogue. PF=3 / ring-4 LDS (caller provides As/Ws[4][2048]).
// Counted vmcnt (never 0 in steady loop); chunk swizzle conflict-free.
__device__ __forceinline__ void gemm64_core(
    const u16* __restrict__ A, const u16* __restrict__ W, u16* __restrict__ C,
    int N, int K, int m0, int n0, u16* As, u16* Ws)
{
    constexpr int PF = 3, LPT = 2, RD = 4;
    const int tid  = threadIdx.x;
    const int lane = tid & 63;
    const int wave = tid >> 6;
    const int wr = wave >> 1, wc = wave & 1;

    const int srow = tid >> 2;
    const int scol = (((tid & 3) ^ ((srow >> 1) & 3))) * 8;
    const u16* Ag = A + (size_t)(m0 + srow) * K + scol;
    const u16* Wg = W + (size_t)(n0 + srow) * K + scol;

    const int fr = lane & 15;
    const int fq = lane >> 4;

    f32x4 acc[2][2] = {};

    auto stage = [&](int buf, int k0) {
        gload16(Ag + k0, &As[buf * 2048 + tid * 8]);
        gload16(Wg + k0, &Ws[buf * 2048 + tid * 8]);
    };
    auto compute = [&](int buf) {
        short8 a[2], b[2];
        #pragma unroll
        for (int m = 0; m < 2; ++m) {
            const int r = wr * 32 + m * 16 + fr;
            a[m] = *reinterpret_cast<const short8*>(
                &As[buf * 2048 + r * 32 + ((fq ^ ((r >> 1) & 3)) << 3)]);
        }
        #pragma unroll
        for (int n = 0; n < 2; ++n) {
            const int r = wc * 32 + n * 16 + fr;
            b[n] = *reinterpret_cast<const short8*>(
                &Ws[buf * 2048 + r * 32 + ((fq ^ ((r >> 1) & 3)) << 3)]);
        }
        #pragma unroll
        for (int m = 0; m < 2; ++m)
            #pragma unroll
            for (int n = 0; n < 2; ++n)
                acc[m][n] = __builtin_amdgcn_mfma_f32_16x16x32_bf16(
                    a[m], b[n], acc[m][n], 0, 0, 0);
    };

    const int nt = K / 32;
    #pragma unroll
    for (int i = 0; i < PF; ++i) stage(i, i * 32);

    int cbuf = 0, sbuf = PF;
    for (int t = 0; t <= nt - PF; ++t) {
        asm volatile("s_waitcnt vmcnt(%0)\n\ts_barrier"
                     :: "n"((PF - 1) * LPT) : "memory");
        if (t + PF < nt) {
            stage(sbuf, (t + PF) * 32);
            if (++sbuf == RD) sbuf = 0;
        }
        compute(cbuf);
        if (++cbuf == RD) cbuf = 0;
    }
    #pragma unroll
    for (int i = 1; i < PF; ++i) {
        asm volatile("s_waitcnt vmcnt(%0)\n\ts_barrier"
                     :: "n"((PF - 1 - i) * LPT) : "memory");
        compute(cbuf);
        if (++cbuf == RD) cbuf = 0;
    }

    #pragma unroll
    for (int m = 0; m < 2; ++m)
        #pragma unroll
        for (int j = 0; j < 4; ++j) {
            const size_t row = (size_t)(m0 + wr * 32 + m * 16 + fq * 4 + j);
            #pragma unroll
            for (int n = 0; n < 2; ++n)
                C[row * (size_t)N + (size_t)(n0 + wc * 32 + n * 16 + fr)] =
                    f2b(acc[m][n][j]);
        }
}

// ------------------------------ MFMA GEMM ----------------------------------
// General templated variant (used for wt_out, gctx, delta, fc1, fc2).
template<int BM, int BN, int EPI, int OB>
__global__ __launch_bounds__(256)
void gemm_mfma(const u16* __restrict__ A, const u16* __restrict__ W,
               void* __restrict__ Cv, int N, int K,
               const float* __restrict__ gatep, int kchunk)
{
    constexpr int MF  = BM / 32;
    constexpr int NF  = BN / 32;
    constexpr int LPT = BM / 64 + BN / 64;
    constexpr int PF  = 3;
    constexpr int RD  = 4;
    __shared__ __align__(16) u16 As[RD][BM * 32];
    __shared__ __align__(16) u16 Ws[RD][BN * 32];
    const int tid  = threadIdx.x;
    const int lane = tid & 63;
    const int wave = tid >> 6;
    const int wr = wave >> 1, wc = wave & 1;

    const int nwg = gridDim.x * gridDim.y;
    const int bid = blockIdx.y * gridDim.x + blockIdx.x;
    const int nid = (bid & 7) * (nwg >> 3) + (bid >> 3);
    const int by  = nid % gridDim.y;
    const int bx  = nid / gridDim.y;
    const int m0 = by * BM, n0 = bx * BN;
    const int kz = blockIdx.z * kchunk;

    const int srow = tid >> 2;
    const int scol = (((tid & 3) ^ ((srow >> 1) & 3))) * 8;
    const u16* Ag = A + (size_t)(m0 + srow) * K + scol + kz;
    const u16* Wg = W + (size_t)(n0 + srow) * K + scol + kz;

    const int fr = lane & 15;
    const int fq = lane >> 4;

    f32x4 acc[MF][NF] = {};

    auto stage = [&](int buf, int k0) {
        #pragma unroll
        for (int i = 0; i < BM / 64; ++i)
            gload16(Ag + k0 + (size_t)(i * 64) * K, &As[buf][tid * 8 + i * 2048]);
        #pragma unroll
        for (int i = 0; i < BN / 64; ++i)
            gload16(Wg + k0 + (size_t)(i * 64) * K, &Ws[buf][tid * 8 + i * 2048]);
    };
    auto compute = [&](int buf) {
        short8 a[MF], b[NF];
        #pragma unroll
        for (int m = 0; m < MF; ++m) {
            const int r = wr * (BM / 2) + m * 16 + fr;
            a[m] = *reinterpret_cast<const short8*>(
                &As[buf][r * 32 + ((fq ^ ((r >> 1) & 3)) << 3)]);
        }
        #pragma unroll
        for (int n = 0; n < NF; ++n) {
            const int r = wc * (BN / 2) + n * 16 + fr;
            b[n] = *reinterpret_cast<const short8*>(
                &Ws[buf][r * 32 + ((fq ^ ((r >> 1) & 3)) << 3)]);
        }
        #pragma unroll
        for (int m = 0; m < MF; ++m)
            #pragma unroll
            for (int n = 0; n < NF; ++n)
                acc[m][n] = __builtin_amdgcn_mfma_f32_16x16x32_bf16(
                    a[m], b[n], acc[m][n], 0, 0, 0);
    };

    const int nt = kchunk / 32;
    #pragma unroll
    for (int i = 0; i < PF; ++i) stage(i, i * 32);

    int cbuf = 0, sbuf = PF;
    for (int t = 0; t <= nt - PF; ++t) {
        asm volatile("s_waitcnt vmcnt(%0)\n\ts_barrier"
                     :: "n"((PF - 1) * LPT) : "memory");
        if (t + PF < nt) {
            stage(sbuf, (t + PF) * 32);
            if (++sbuf == RD) sbuf = 0;
        }
        compute(cbuf);
        if (++cbuf == RD) cbuf = 0;
    }
    #pragma unroll
    for (int i = 1; i < PF; ++i) {
        asm volatile("s_waitcnt vmcnt(%0)\n\ts_barrier"
                     :: "n"((PF - 1 - i) * LPT) : "memory");
        compute(cbuf);
        if (++cbuf == RD) cbuf = 0;
    }

    float* Cz = (float*)Cv + (size_t)blockIdx.z * M_ROWS * N;
    const float gate = (EPI == 2) ? gatep[0] : 0.f;
    #pragma unroll
    for (int m = 0; m < MF; ++m) {
        #pragma unroll
        for (int j = 0; j < 4; ++j) {
            const size_t row = (size_t)(m0 + wr * (BM / 2) + m * 16 + fq * 4 + j);
            #pragma unroll
            for (int n = 0; n < NF; ++n) {
                float v = acc[m][n][j];
                const size_t idx = row * (size_t)N + (size_t)(n0 + wc * (BN / 2) + n * 16 + fr);
                if (EPI == 1) v = 0.5f * v * (1.f + erff(v * 0.70710678118654752f));
                if (OB) {
                    ((u16*)Cv)[idx] = f2b(v);
                } else {
                    if (EPI == 2) Cz[idx] = Cz[idx] + gate * v;
                    else          Cz[idx] = v;
                }
            }
        }
    }
}

// ------------- batched projection GEMMs (4 problems, K=1024) ----------------
// grid 2304 blocks; prefix {0,768,1024,1536,2304} (64x64 tiles).
struct GemmPack4 { const u16* A[4]; const u16* W[4]; u16* C[4]; int N[4]; };

__global__ __launch_bounds__(256)
void gemm_bat4(GemmPack4 p)
{
    __shared__ __align__(16) u16 As[4][2048];
    __shared__ __align__(16) u16 Ws[4][2048];
    constexpr int pre[5] = {0, 768, 1024, 1536, 2304};
    const int nwg = gridDim.x * gridDim.y;           // 2304
    const int bid = blockIdx.y * gridDim.x + blockIdx.x;
    const int nid = (bid & 7) * (nwg >> 3) + (bid >> 3);
    int seg = 0;
    #pragma unroll
    for (int i = 1; i < 4; ++i) seg += (nid >= pre[i]);
    const int idx = nid - pre[seg];
    const int nx  = p.N[seg] >> 6;
    const int bx  = idx % nx;
    const int by  = idx / nx;
    gemm64_core(p.A[seg], p.W[seg], p.C[seg], p.N[seg], 1024,
                by * 64, bx * 64, &As[0][0], &Ws[0][0]);
}

// ------------- batched gate-path GEMMs (3 problems, N=512,K=512) ------------
struct GemmPack3 { const u16* A[3]; const u16* W[3]; u16* C[3]; };

__global__ __launch_bounds__(256)
void gemm_bat3(GemmPack3 p)
{
    __shared__ __align__(16) u16 As[4][2048];
    __shared__ __align__(16) u16 Ws[4][2048];
    const int nwg = gridDim.x * gridDim.y;           // 768
    const int bid = blockIdx.y * gridDim.x + blockIdx.x;
    const int nid = (bid & 7) * (nwg >> 3) + (bid >> 3);
    const int z = nid % 3;                           // problem fastest-varying
    const int r = nid / 3;                           // [0,256)
    const int bx = r & 7;
    const int by = r >> 3;
    gemm64_core(p.A[z], p.W[z], p.C[z], 512, 512,
                by * 64, bx * 64, &As[0][0], &Ws[0][0]);
}

// ---------------- split-K reduce: C += gate * (p0+p1+p2+p3) ----------------
__global__ __launch_bounds__(256)
void redk(const float* __restrict__ p, const float* __restrict__ gatep,
          float* __restrict__ C)
{
    const int i = (blockIdx.x * 256 + threadIdx.x) * 4;
    const float g = gatep[0];
    const float4 a = *reinterpret_cast<const float4*>(p + i);
    const float4 b = *reinterpret_cast<const float4*>(p + 2097152 + i);
    const float4 c = *reinterpret_cast<const float4*>(p + 4194304 + i);
    const float4 d = *reinterpret_cast<const float4*>(p + 6291456 + i);
    float4 o = *reinterpret_cast<float4*>(C + i);
    o.x += g * ((a.x + b.x) + (c.x + d.x));
    o.y += g * ((a.y + b.y) + (c.y + d.y));
    o.z += g * ((a.z + b.z) + (c.z + d.z));
    o.w += g * ((a.w + b.w) + (c.w + d.w));
    *reinterpret_cast<float4*>(C + i) = o;
}

// ------------------------- MFMA fused attention ----------------------------
// Batched with problem index in the FAST bits: grid (16*NP, 16); after the
// XCD chunk swizzle, z = nid % NP so consecutive blocks alternate problems
// (true co-residency; blockIdx.z was slowest-varying -> no overlap, r10).
struct AttnPack {
    const u16* Q[3]; const u16* K[3]; const u16* V[3]; void* O[3];
    int qs[3], ks[3], vs[3], os[3], ob[3];
};

__global__ __launch_bounds__(256)
void attn_mfma(AttnPack p, int NP)
{
    const int nwg = gridDim.x * gridDim.y;
    const int bid = blockIdx.y * gridDim.x + blockIdx.x;
    const int nid = (bid & 7) * (nwg >> 3) + (bid >> 3);
    const int z  = nid % NP;
    const int r_ = nid / NP;                 // [0,256)
    const int qt = r_ & 15;
    const int bh = r_ >> 4;

    const u16* __restrict__ Q = p.Q[z];
    const u16* __restrict__ K = p.K[z];
    const u16* __restrict__ V = p.V[z];
    void* __restrict__ Ov = p.O[z];
    const int qs = p.qs[z], ks = p.ks[z], vs = p.vs[z], os = p.os[z];
    const int ob = p.ob[z];

    __shared__ __align__(16) u16 Ks[2][64 * 72];   // [kv][d], pad 72
    __shared__ __align__(16) u16 Vt[2][64 * 72];   // [d][kv], pad 72
    __shared__ __align__(16) u16 Ps[4][16 * 72];   // per-wave P [q][kv]
    const int tid  = threadIdx.x;
    const int lane = tid & 63;
    const int wave = tid >> 6;
    const int fr = lane & 15;
    const int fq = lane >> 4;

    const int b   = bh >> 3;
    const int hc  = (bh & 7) * 64;
    const size_t qrow0 = (size_t)b * SEQ + (size_t)qt * 64;
    const size_t krow0 = (size_t)b * SEQ;

    short8 qf[2];
    {
        const u16* qp = Q + (qrow0 + wave * 16 + fr) * qs + hc + fq * 8;
        qf[0] = *reinterpret_cast<const short8*>(qp);
        qf[1] = *reinterpret_cast<const short8*>(qp + 32);
    }

    const int skr = tid >> 2;
    const int skc = (tid & 3) * 16;
    const int svk = (tid >> 4) * 4;
    const int svd = (tid & 15) * 4;

    short8 kreg0, kreg1;
    ushort4 vr0, vr1, vr2, vr3;
    auto load_tile = [&](int kt) {
        const u16* kp = K + (krow0 + kt * 64 + skr) * ks + hc + skc;
        kreg0 = *reinterpret_cast<const short8*>(kp);
        kreg1 = *reinterpret_cast<const short8*>(kp + 8);
        const u16* vp = V + (krow0 + kt * 64 + svk) * vs + hc + svd;
        vr0 = *reinterpret_cast<const ushort4*>(vp);
        vr1 = *reinterpret_cast<const ushort4*>(vp + vs);
        vr2 = *reinterpret_cast<const ushort4*>(vp + 2 * (size_t)vs);
        vr3 = *reinterpret_cast<const ushort4*>(vp + 3 * (size_t)vs);
    };
    auto write_tile = [&](int bf) {
        *reinterpret_cast<short8*>(&Ks[bf][skr * 72 + skc]) = kreg0;
        *reinterpret_cast<short8*>(&Ks[bf][skr * 72 + skc + 8]) = kreg1;
        uint2 w;
        w.x = (unsigned)vr0.x | ((unsigned)vr1.x << 16);
        w.y = (unsigned)vr2.x | ((unsigned)vr3.x << 16);
        *reinterpret_cast<uint2*>(&Vt[bf][(svd + 0) * 72 + svk]) = w;
        w.x = (unsigned)vr0.y | ((unsigned)vr1.y << 16);
        w.y = (unsigned)vr2.y | ((unsigned)vr3.y << 16);
        *reinterpret_cast<uint2*>(&Vt[bf][(svd + 1) * 72 + svk]) = w;
        w.x = (unsigned)vr0.z | ((unsigned)vr1.z << 16);
        w.y = (unsigned)vr2.z | ((unsigned)vr3.z << 16);
        *reinterpret_cast<uint2*>(&Vt[bf][(svd + 2) * 72 + svk]) = w;
        w.x = (unsigned)vr0.w | ((unsigned)vr1.w << 16);
        w.y = (unsigned)vr2.w | ((unsigned)vr3.w << 16);
        *reinterpret_cast<uint2*>(&Vt[bf][(svd + 3) * 72 + svk]) = w;
    };

    float m_run = -1e30f, l_run = 0.f;
    f32x4 acc[4] = {};

    load_tile(0);
    write_tile(0);
    __syncthreads();

    constexpr int NT = SEQ / 64;
    for (int kt = 0; kt < NT; ++kt) {
        const int bf = kt & 1;
        if (kt + 1 < NT) load_tile(kt + 1);

        f32x4 st[4] = {};
        #pragma unroll
        for (int kn = 0; kn < 4; ++kn) {
            const short8 ka0 = *reinterpret_cast<const short8*>(
                &Ks[bf][(kn * 16 + fr) * 72 + fq * 8]);
            const short8 ka1 = *reinterpret_cast<const short8*>(
                &Ks[bf][(kn * 16 + fr) * 72 + 32 + fq * 8]);
            st[kn] = __builtin_amdgcn_mfma_f32_16x16x32_bf16(ka0, qf[0], st[kn], 0, 0, 0);
            st[kn] = __builtin_amdgcn_mfma_f32_16x16x32_bf16(ka1, qf[1], st[kn], 0, 0, 0);
        }

        float mx = -1e30f;
        #pragma unroll
        for (int kn = 0; kn < 4; ++kn)
            #pragma unroll
            for (int r = 0; r < 4; ++r) {
                st[kn][r] *= 0.125f;
                mx = fmaxf(mx, st[kn][r]);
            }
        mx = fmaxf(mx, __shfl_xor(mx, 16, 64));
        mx = fmaxf(mx, __shfl_xor(mx, 32, 64));
        const float mnew = fmaxf(m_run, mx);
        const float corr = __expf(m_run - mnew);
        m_run = mnew;
        float psum = 0.f;
        #pragma unroll
        for (int kn = 0; kn < 4; ++kn) {
            const float p0 = __expf(st[kn][0] - mnew);
            const float p1 = __expf(st[kn][1] - mnew);
            const float p2 = __expf(st[kn][2] - mnew);
            const float p3 = __expf(st[kn][3] - mnew);
            psum += (p0 + p1) + (p2 + p3);
            uint2 w;
            w.x = (unsigned)f2b(p0) | ((unsigned)f2b(p1) << 16);
            w.y = (unsigned)f2b(p2) | ((unsigned)f2b(p3) << 16);
            *reinterpret_cast<uint2*>(&Ps[wave][fr * 72 + kn * 16 + fq * 4]) = w;
        }
        psum += __shfl_xor(psum, 16, 64);
        psum += __shfl_xor(psum, 32, 64);
        l_run = l_run * corr + psum;

        float cq[4];
        #pragma unroll
        for (int j = 0; j < 4; ++j) cq[j] = __shfl(corr, fq * 4 + j, 64);
        #pragma unroll
        for (int nd = 0; nd < 4; ++nd)
            #pragma unroll
            for (int j = 0; j < 4; ++j)
                acc[nd][j] *= cq[j];

        short8 pa0 = *reinterpret_cast<const short8*>(&Ps[wave][fr * 72 + fq * 8]);
        short8 pa1 = *reinterpret_cast<const short8*>(&Ps[wave][fr * 72 + 32 + fq * 8]);
        #pragma unroll
        for (int nd = 0; nd < 4; ++nd) {
            const short8 vb0 = *reinterpret_cast<const short8*>(
                &Vt[bf][(nd * 16 + fr) * 72 + fq * 8]);
            const short8 vb1 = *reinterpret_cast<const short8*>(
                &Vt[bf][(nd * 16 + fr) * 72 + 32 + fq * 8]);
            acc[nd] = __builtin_amdgcn_mfma_f32_16x16x32_bf16(pa0, vb0, acc[nd], 0, 0, 0);
            acc[nd] = __builtin_amdgcn_mfma_f32_16x16x32_bf16(pa1, vb1, acc[nd], 0, 0, 0);
        }

        if (kt + 1 < NT) write_tile(bf ^ 1);
        __syncthreads();
    }

    float iq[4];
    #pragma unroll
    for (int j = 0; j < 4; ++j) iq[j] = 1.f / __shfl(l_run, fq * 4 + j, 64);
    #pragma unroll
    for (int j = 0; j < 4; ++j) {
        const size_t orow = (qrow0 + wave * 16 + fq * 4 + j) * os + hc;
        #pragma unroll
        for (int nd = 0; nd < 4; ++nd) {
            const float v = acc[nd][j] * iq[j];
            if (ob) ((u16*)Ov)[orow + nd * 16 + fr] = f2b(v);
            else    ((float*)Ov)[orow + nd * 16 + fr] = v;
        }
    }
}

// -------------------- gate mix (dot, softmax-2, blend) ---------------------
__global__ __launch_bounds__(256)
void mix_kernel(const float* __restrict__ gctx, const float* __restrict__ mixw,
                const float* __restrict__ mixb, const float* __restrict__ so,
                const float* __restrict__ co, u16* __restrict__ mixed)
{
    const size_t row = blockIdx.x;
    const float* g = gctx + row * 512;
    float d0 = 0.f, d1 = 0.f;
    for (int c = threadIdx.x; c < 512; c += 256) {
        const float gv = g[c];
        d0 = fmaf(gv, mixw[c], d0);
        d1 = fmaf(gv, mixw[512 + c], d1);
    }
    #pragma unroll
    for (int off = 32; off > 0; off >>= 1) {
        d0 += __shfl_down(d0, off);
        d1 += __shfl_down(d1, off);
    }
    __shared__ float sA[4], sB[4];
    const int wid = threadIdx.x >> 6;
    if ((threadIdx.x & 63) == 0) { sA[wid] = d0; sB[wid] = d1; }
    __syncthreads();
    const float t0 = sA[0] + sA[1] + sA[2] + sA[3] + mixb[0];
    const float t1 = sB[0] + sB[1] + sB[2] + sB[3] + mixb[1];
    const float mx = fmaxf(t0, t1);
    const float e0 = __expf(t0 - mx), e1 = __expf(t1 - mx);
    const float inv = 1.f / (e0 + e1);
    const float w0 = e0 * inv, w1 = e1 * inv;
    for (int c = threadIdx.x; c < 512; c += 256)
        mixed[row * 512 + c] = f2b(w0 * so[row * 512 + c] + w1 * co[row * 512 + c]);
}

// ---------------------------------------------------------------------------
extern "C" void kernel_launch(void* const* d_in, const int* in_sizes, int n_in,
                              void* d_out, int out_size, void* d_ws, size_t ws_size,
                              hipStream_t stream)
{
    const float* query     = (const float*)d_in[0];
    const float* kvwt      = (const float*)d_in[1];
    const float* nq_w      = (const float*)d_in[2];
    const float* nq_b      = (const float*)d_in[3];
    const float* nkv_w     = (const float*)d_in[4];
    const float* nkv_b     = (const float*)d_in[5];
    const float* wq_cross  = (const float*)d_in[6];
    const float* wkv_cross = (const float*)d_in[7];
    const float* wqkv_self = (const float*)d_in[8];
    const float* gn_w      = (const float*)d_in[9];
    const float* gn_b      = (const float*)d_in[10];
    const float* mha_in_w  = (const float*)d_in[11];
    const float* mha_out_w = (const float*)d_in[12];
    const float* mix_w     = (const float*)d_in[13];
    const float* mix_b     = (const float*)d_in[14];
    const float* w_out     = (const float*)d_in[15];
    const float* ff_ln_w   = (const float*)d_in[16];
    const float* ff_ln_b   = (const float*)d_in[17];
    const float* ff_fc1    = (const float*)d_in[18];
    const float* ff_fc2    = (const float*)d_in[19];
    const float* ff_gate   = (const float*)d_in[20];

    float* delta_out = (float*)d_out;                          // stack[0]
    float* wt_out    = (float*)d_out + (size_t)M_ROWS * 1024;  // stack[1]

    // ---- workspace layout (byte offsets; high-water 66,060,288 B) ----
    char* wsb = (char*)d_ws;
    u16*   qkv_b   = (u16*)  (wsb + 0);          // bf16 [2048,1536]
    u16*   kv_c_b  = (u16*)  (wsb + 6291456);    // bf16 [2048,1024]
    u16*   q_c_b   = (u16*)  (wsb + 10485760);   // bf16 [2048,512]
    float* cross_f = (float*)(wsb + 12582912);   // f32  [2048,512]
    float* self_f  = (float*)(wsb + 16777216);   // f32  [2048,512]
    u16*   kvn_b   = (u16*)  (wsb + 20971520);   // bf16 [2048,1024]
    u16*   qn_b    = (u16*)  (wsb + 25165824);   // bf16 [2048,1024]
    u16*   wta_b   = (u16*)  (wsb + 29360128);   // bf16 [2048,512]
    u16*   con_b   = (u16*)  (wsb + 31457280);   // bf16 [2048,512]
    // aliases (liveness audited):
    u16*   gq_b    = qkv_b;                      // [2048,512]
    u16*   gk_b    = qkv_b + 1048576;            // [2048,512]
    u16*   gv_b    = qkv_b + 2097152;            // [2048,512]
    float* gctx_f  = (float*)kv_c_b;
    u16*   gattn_b = kvn_b;
    u16*   mixed_b = kvn_b + 1048576;
    u16*   lnd_b   = qn_b;
    u16*   son_b   = wta_b;
    u16*   ffh_b   = qkv_b;                      // [2048,4096] spans 0..16.78MB
    float* part_f  = (float*)(wsb + 16777216);   // 4x[2048,1024] f32 (step 19)
    u16*   qkv_s_b = (u16*)  (wsb + 59768832);   // bf16 [2048,1536] tail
    // bf16 weights:
    u16* wqkv_self_b = (u16*)(wsb + 33554432);
    u16* wq_cross_b  = (u16*)(wsb + 36700160);
    u16* wkv_cross_b = (u16*)(wsb + 37748736);
    u16* mha_in_b    = (u16*)(wsb + 39845888);
    u16* mha_out_b   = (u16*)(wsb + 41418752);
    u16* w_out_b     = (u16*)(wsb + 41943040);
    u16* ff_fc1_b    = (u16*)(wsb + 42991616);
    u16* ff_fc2_b    = (u16*)(wsb + 51380224);

    const dim3 blk(256);

    // 0. fused weight conversion
    CvtPack cp;
    cp.s[0] = wqkv_self; cp.d[0] = wqkv_self_b;
    cp.s[1] = wq_cross;  cp.d[1] = wq_cross_b;
    cp.s[2] = wkv_cross; cp.d[2] = wkv_cross_b;
    cp.s[3] = mha_in_w;  cp.d[3] = mha_in_b;
    cp.s[4] = mha_out_w; cp.d[4] = mha_out_b;
    cp.s[5] = w_out;     cp.d[5] = w_out_b;
    cp.s[6] = ff_fc1;    cp.d[6] = ff_fc1_b;
    cp.s[7] = ff_fc2;    cp.d[7] = ff_fc2_b;
    cvt8_kernel<<<dim3(12800), blk, 0, stream>>>(cp);

    // 1+5. kvn = LN(kv_feats_wt), qn = LN(query)
    ln_dual<<<dim3(2 * M_ROWS), blk, 0, stream>>>(
        kvwt, nkv_w, nkv_b, kvn_b, query, nq_w, nq_b, qn_b, 1024);

    // 2,6,7,9: four projection GEMMs in ONE batched launch (2304 blocks)
    GemmPack4 g4;
    g4.A[0] = kvn_b; g4.W[0] = wqkv_self_b; g4.C[0] = qkv_b;   g4.N[0] = 1536;
    g4.A[1] = qn_b;  g4.W[1] = wq_cross_b;  g4.C[1] = q_c_b;   g4.N[1] = 512;
    g4.A[2] = kvn_b; g4.W[2] = wkv_cross_b; g4.C[2] = kv_c_b;  g4.N[2] = 1024;
    g4.A[3] = qn_b;  g4.W[3] = wqkv_self_b; g4.C[3] = qkv_s_b; g4.N[3] = 1536;
    gemm_bat4<<<dim3(72, 32), blk, 0, stream>>>(g4);

    // 3,8,10: three attentions, problem index in fast bits (grid 48x16)
    AttnPack ap;
    ap.Q[0] = qkv_b;    ap.K[0] = qkv_b + 512;    ap.V[0] = qkv_b + 1024;    ap.O[0] = wta_b;
    ap.qs[0] = 1536; ap.ks[0] = 1536; ap.vs[0] = 1536; ap.os[0] = 512; ap.ob[0] = 1;
    ap.Q[1] = q_c_b;    ap.K[1] = kv_c_b;         ap.V[1] = kv_c_b + 512;    ap.O[1] = cross_f;
    ap.qs[1] = 512;  ap.ks[1] = 1024; ap.vs[1] = 1024; ap.os[1] = 512; ap.ob[1] = 0;
    ap.Q[2] = qkv_s_b;  ap.K[2] = qkv_s_b + 512;  ap.V[2] = qkv_s_b + 1024;  ap.O[2] = self_f;
    ap.qs[2] = 1536; ap.ks[2] = 1536; ap.vs[2] = 1536; ap.os[2] = 512; ap.ob[2] = 0;
    attn_mfma<<<dim3(48, 16), blk, 0, stream>>>(ap, 3);

    // 4. wt_out = wt_attn @ w_out^T -> stack[1]
    gemm_mfma<64,128,0,0><<<dim3(8, 32), blk, 0, stream>>>(wta_b, w_out_b, wt_out, 1024, 512, nullptr, 512);
    // 11. son = LN(self; gn), con = LN(cross; gn)
    ln_dual<<<dim3(2 * M_ROWS), blk, 0, stream>>>(
        self_f, gn_w, gn_b, son_b, cross_f, gn_w, gn_b, con_b, 512);
    // 12. gq/gk/gv in ONE batched launch (768 blocks, problem fastest)
    GemmPack3 g3;
    g3.A[0] = son_b; g3.W[0] = mha_in_b;            g3.C[0] = gq_b;
    g3.A[1] = con_b; g3.W[1] = mha_in_b + 512*512;  g3.C[1] = gk_b;
    g3.A[2] = con_b; g3.W[2] = mha_in_b + 1024*512; g3.C[2] = gv_b;
    gemm_bat3<<<dim3(24, 32), blk, 0, stream>>>(g3);
    // 13. gate attention (single problem)
    AttnPack gp;
    gp.Q[0] = gq_b; gp.K[0] = gk_b; gp.V[0] = gv_b; gp.O[0] = gattn_b;
    gp.qs[0] = 512; gp.ks[0] = 512; gp.vs[0] = 512; gp.os[0] = 512; gp.ob[0] = 1;
    gp.Q[1] = gp.Q[0]; gp.K[1] = gp.K[0]; gp.V[1] = gp.V[0]; gp.O[1] = gp.O[0];
    gp.qs[1] = 512; gp.ks[1] = 512; gp.vs[1] = 512; gp.os[1] = 512; gp.ob[1] = 1;
    gp.Q[2] = gp.Q[0]; gp.K[2] = gp.K[0]; gp.V[2] = gp.V[0]; gp.O[2] = gp.O[0];
    gp.qs[2] = 512; gp.ks[2] = 512; gp.vs[2] = 512; gp.os[2] = 512; gp.ob[2] = 1;
    attn_mfma<<<dim3(16, 16), blk, 0, stream>>>(gp, 1);
    // 14. gate_ctx = gate_attn @ mha_out_w^T (f32 out)
    gemm_mfma<64,64,0,0><<<dim3(8, 32), blk, 0, stream>>>(gattn_b, mha_out_b, gctx_f, 512, 512, nullptr, 512);
    // 15. mixed = softmax-gate blend (bf16 out)
    mix_kernel<<<dim3(M_ROWS), blk, 0, stream>>>(gctx_f, mix_w, mix_b, self_f, cross_f, mixed_b);
    // 16. delta = mixed @ w_out^T -> stack[0] (f32)
    gemm_mfma<64,128,0,0><<<dim3(8, 32), blk, 0, stream>>>(mixed_b, w_out_b, delta_out, 1024, 512, nullptr, 512);
    // 17. ln_delta = LN(delta; ff_ln)
    ln_bf16<<<dim3(M_ROWS), blk, 0, stream>>>(delta_out, ff_ln_w, ff_ln_b, lnd_b, 1024);
    // 18. ffh = gelu(ln_delta @ ff_fc1^T)   64x64, grid 2048 (5/CU)
    gemm_mfma<64,64,1,1><<<dim3(64, 32), blk, 0, stream>>>(lnd_b, ff_fc1_b, ffh_b, 4096, 1024, nullptr, 1024);
    // 19a. fc2 split-K=4 partials           64x64, grid 2048
    gemm_mfma<64,64,0,0><<<dim3(16, 32, 4), blk, 0, stream>>>(ffh_b, ff_fc2_b, part_f, 1024, 4096, nullptr, 1024);
    // 19b. delta += gate * sum(partials)
    redk<<<dim3(2048), blk, 0, stream>>>(part_f, ff_gate, delta_out);
}